// Round 20
// baseline (1696.127 us; speedup 1.0000x reference)
//
#include <hip/hip_runtime.h>
#include <cstdint>
#include <cstddef>

#define BB 2
#define TT 16385
#define NPAD 16640
#define DD 512
#define HH 8
#define DHH 64
#define MLAND 256
#define PADF 255
#define A3KC 26
#define A3CH 640

typedef __attribute__((ext_vector_type(8))) _Float16 f16x8;
typedef __attribute__((ext_vector_type(4))) float f32x4;

__device__ __forceinline__ float gelu_f(float v) {
  float c = 0.7978845608028654f * (v + 0.044715f * v * v * v);
  return 0.5f * v * (1.0f + tanhf(c));
}

__device__ __forceinline__ unsigned short f16_1(float a) {
  _Float16 h = (_Float16)a;
  return __builtin_bit_cast(unsigned short, h);
}
__device__ __forceinline__ float f16f(unsigned u) {
  return (float)__builtin_bit_cast(_Float16, (unsigned short)(u & 0xffffu));
}
__device__ __forceinline__ unsigned pk_f16(float a, float b) {
  return (unsigned)f16_1(a) | ((unsigned)f16_1(b) << 16);
}
// split a,b into f16 hi (packed) and f16 residual-lo (packed)
__device__ __forceinline__ void split2h(float a, float b, unsigned& hi, unsigned& lo) {
  _Float16 ah = (_Float16)a, bh = (_Float16)b;
  hi = (unsigned)__builtin_bit_cast(unsigned short, ah) |
       ((unsigned)__builtin_bit_cast(unsigned short, bh) << 16);
  lo = pk_f16(a - (float)ah, b - (float)bh);
}
__device__ __forceinline__ void store4h(float4 v, unsigned short* dh,
                                        unsigned short* dl) {
  unsigned h0, l0, h1, l1;
  split2h(v.x, v.y, h0, l0);
  split2h(v.z, v.w, h1, l1);
  *(uint2*)dh = make_uint2(h0, h1);
  *(uint2*)dl = make_uint2(l0, l1);
}

// async global->LDS 16B (wave-uniform LDS base + lane*16)
__device__ __forceinline__ void gload16(const unsigned short* g, short* l) {
  __builtin_amdgcn_global_load_lds(
      (const __attribute__((address_space(1))) void*)g,
      (__attribute__((address_space(3))) void*)l, 16, 0, 0);
}

// ---------------------------------------------------------------- cls rows
__global__ void k_set_cls(float* __restrict__ h, const float* __restrict__ cls) {
  h[(size_t)blockIdx.x * TT * DD + threadIdx.x] = cls[threadIdx.x];
}
__global__ void k_copy_cls(float* __restrict__ dst, const float* __restrict__ src) {
  size_t o = (size_t)blockIdx.x * TT * DD + threadIdx.x;
  dst[o] = src[o];
}

// ------------------------------------------------ W[K][N] -> Wt f16 [N][K]
__global__ __launch_bounds__(256) void k_cvt_wt(
    const float* __restrict__ W, unsigned short* __restrict__ Wth, int K, int N) {
  __shared__ float tile[32][33];
  int kb = blockIdx.x * 32, nb = blockIdx.y * 32;
  int t = threadIdx.x;
  int tr = t >> 3, tc4 = (t & 7) * 4;
  float4 v = *(const float4*)(W + (size_t)(kb + tr) * N + nb + tc4);
  tile[tr][tc4 + 0] = v.x;
  tile[tr][tc4 + 1] = v.y;
  tile[tr][tc4 + 2] = v.z;
  tile[tr][tc4 + 3] = v.w;
  __syncthreads();
  int n = nb + tr;
  ushort4 hs;
  hs.x = f16_1(tile[tc4 + 0][tr]);
  hs.y = f16_1(tile[tc4 + 1][tr]);
  hs.z = f16_1(tile[tc4 + 2][tr]);
  hs.w = f16_1(tile[tc4 + 3][tr]);
  *(ushort4*)(Wth + (size_t)n * K + kb + tc4) = hs;
}

// ---------------- fp32-via-2xf16 MFMA GEMM, 128x256 tile, 8 waves (512 thr)
// (kept for MODE 0 feat-gelu; qkv/proj use k_gemm_pipe)
template <int MODE>
__global__ __launch_bounds__(512) void k_gemm_mfma(
    const float* __restrict__ A, const unsigned short* __restrict__ Aph,
    const unsigned short* __restrict__ Apl, const unsigned short* __restrict__ Wth,
    const float* __restrict__ bias, void* __restrict__ Cv, int M, int K, int N,
    int lda) {
  __shared__ short Ash[128][44];
  __shared__ short Asl[128][44];
  __shared__ short Bsh[256][44];
  const int t = threadIdx.x;
  // bijective swizzle over (gridDim.x row-tiles) x (gridDim.y col-tiles)
  int nRow = gridDim.x, nCol = gridDim.y;
  int lin = blockIdx.x + blockIdx.y * nRow;
  int chunk = 8 * nCol;
  int group = lin / chunk;
  int rem = lin - group * chunk;
  int gbase = group * 8;
  int Geff = nRow - gbase;
  if (Geff > 8) Geff = 8;
  const int rb = (gbase + rem % Geff) * 128;
  const int cb = (rem / Geff) * 256;
  const float* Ab = A;
  float* Cf = (float*)Cv;
  unsigned short* Ch = (unsigned short*)Cv;
  if (MODE == 2) {
    int b = blockIdx.z;
    Ab = A + (size_t)b * NPAD * DD + (size_t)PADF * DD;
    Cf = (float*)Cv + (size_t)b * TT * DD;
  }
  const int lane = t & 63, wv = t >> 6;
  const int wr = wv >> 2, wc = wv & 3;
  const int fr = lane & 15, kg = lane >> 4;
  const int srow = t >> 2, skh = (t & 3) * 8;   // A: 8 shorts / thread / plane
  const int brow = t >> 1, bkh = (t & 1) * 16;  // B: 16 shorts / thread

  f32x4 acc[4][4];
  f32x4 zero4 = {0.f, 0.f, 0.f, 0.f};
#pragma unroll
  for (int i = 0; i < 4; ++i)
#pragma unroll
    for (int j = 0; j < 4; ++j) acc[i][j] = zero4;

  for (int k0 = 0; k0 < K; k0 += 32) {
    __syncthreads();
    if (MODE == 1) {
      const unsigned short* ph = Aph + (size_t)(rb + srow) * lda + k0 + skh;
      const unsigned short* pl = Apl + (size_t)(rb + srow) * lda + k0 + skh;
      *(uint4*)&Ash[srow][skh] = *(const uint4*)ph;
      *(uint4*)&Asl[srow][skh] = *(const uint4*)pl;
    } else {
      int grow = rb + srow;
      float4 f0 = {0, 0, 0, 0}, f1 = {0, 0, 0, 0};
      if (grow < M) {
        const float* p = Ab + (size_t)grow * lda + k0 + skh;
        f0 = *(const float4*)p;
        f1 = *(const float4*)(p + 4);
      }
      unsigned h0, h1, h2, h3, l0, l1, l2, l3;
      split2h(f0.x, f0.y, h0, l0);
      split2h(f0.z, f0.w, h1, l1);
      split2h(f1.x, f1.y, h2, l2);
      split2h(f1.z, f1.w, h3, l3);
      *(uint4*)&Ash[srow][skh] = make_uint4(h0, h1, h2, h3);
      *(uint4*)&Asl[srow][skh] = make_uint4(l0, l1, l2, l3);
    }
    {
      const unsigned short* ph = Wth + (size_t)(cb + brow) * K + k0 + bkh;
      *(uint4*)&Bsh[brow][bkh] = *(const uint4*)ph;
      *(uint4*)&Bsh[brow][bkh + 8] = *(const uint4*)(ph + 8);
    }
    __syncthreads();
    f16x8 ah[4], al[4];
#pragma unroll
    for (int mf = 0; mf < 4; ++mf) {
      ah[mf] = *(const f16x8*)&Ash[wr * 64 + mf * 16 + fr][kg * 8];
      al[mf] = *(const f16x8*)&Asl[wr * 64 + mf * 16 + fr][kg * 8];
    }
#pragma unroll
    for (int nf = 0; nf < 4; ++nf) {
      f16x8 bhf = *(const f16x8*)&Bsh[wc * 64 + nf * 16 + fr][kg * 8];
#pragma unroll
      for (int mf = 0; mf < 4; ++mf) {
        acc[mf][nf] =
            __builtin_amdgcn_mfma_f32_16x16x32_f16(ah[mf], bhf, acc[mf][nf], 0, 0, 0);
        acc[mf][nf] =
            __builtin_amdgcn_mfma_f32_16x16x32_f16(al[mf], bhf, acc[mf][nf], 0, 0, 0);
      }
    }
  }
#pragma unroll
  for (int mf = 0; mf < 4; ++mf) {
#pragma unroll
    for (int r = 0; r < 4; ++r) {
      int row = rb + wr * 64 + mf * 16 + kg * 4 + r;
      if (MODE == 2 && row >= M) continue;
      size_t orow = (MODE == 0) ? (size_t)(row + (row >> 14) + 1) : (size_t)row;
#pragma unroll
      for (int nf = 0; nf < 4; ++nf) {
        int col = cb + wc * 64 + nf * 16 + fr;
        float v = acc[mf][nf][r];
        if (MODE == 0) {
          Cf[orow * DD + col] = gelu_f(v + bias[col]);
        } else if (MODE == 1) {
          Ch[orow * (size_t)N + col] = f16_1(v);
        } else {
          float old = Cf[orow * DD + col];
          Cf[orow * DD + col] = old + v + bias[col];
        }
      }
    }
  }
}

// ---------------- pipelined f16-plane GEMM: gload_lds + counted vmcnt
// BK=32, dbuf LDS 64KB -> 2 blocks/CU, 2-deep prefetch, vmcnt(4),
// XOR slot-swizzle (64B rows, slot^=row&3, 2-way free). K=512 fixed.
// PM==1: qkv (C f16 at row*1536+col).  PM==2: proj (C fp32 += v + bias, row<TT).
template <int PM>
__global__ __launch_bounds__(512) void k_gemm_pipe(
    const unsigned short* __restrict__ Aph, const unsigned short* __restrict__ Apl,
    const unsigned short* __restrict__ Wth, void* __restrict__ Cv,
    const float* __restrict__ bias) {
  __shared__ __align__(16) short Ah[2][128][32];
  __shared__ __align__(16) short Al[2][128][32];
  __shared__ __align__(16) short Bs[2][256][32];
  const int t = threadIdx.x;
  // L2 block swizzle
  int nRow = gridDim.x, nCol = gridDim.y;
  int lin = blockIdx.x + blockIdx.y * nRow;
  int chunk = 8 * nCol;
  int group = lin / chunk;
  int rem = lin - group * chunk;
  int gbase = group * 8;
  int Geff = nRow - gbase;
  if (Geff > 8) Geff = 8;
  const int rb = (gbase + rem % Geff) * 128;
  const int cb = (rem / Geff) * 256;
  const int lane = t & 63, wv = t >> 6;
  const int wr = wv >> 2, wc = wv & 3;
  const int fr = lane & 15, kg = lane >> 4;
  const int lr4 = lane >> 2;                // row-in-16 within a gload
  const int ss = (lane & 3) ^ (lr4 & 3);    // pre-swizzled src slot (16B units)

  size_t arow0 = (size_t)rb;
  if (PM == 2) arow0 += (size_t)blockIdx.z * NPAD + PADF;

  f32x4 acc[4][4];
  f32x4 zero4 = {0.f, 0.f, 0.f, 0.f};
#pragma unroll
  for (int i = 0; i < 4; ++i)
#pragma unroll
    for (int j = 0; j < 4; ++j) acc[i][j] = zero4;

  // stage K-step kt (K=32) into buffer bf: 4 gloads/wave (A hi 1, A lo 1, B 2)
  auto STAGE = [&](int kt, int bf) {
    const int k0 = kt * 32;
    {
      int lr = wv * 16;
      gload16(Aph + (arow0 + lr + lr4) * DD + k0 + ss * 8, &Ah[bf][lr][0]);
      gload16(Apl + (arow0 + lr + lr4) * DD + k0 + ss * 8, &Al[bf][lr][0]);
    }
#pragma unroll
    for (int j = 0; j < 2; ++j) {
      int lr = wv * 32 + j * 16;
      gload16(Wth + (size_t)(cb + lr + lr4) * DD + k0 + ss * 8, &Bs[bf][lr][0]);
    }
  };

  STAGE(0, 0);
  STAGE(1, 1);
  const int sl = ((kg ^ (fr & 3))) * 8;  // swizzled read slot (shorts)
  for (int kt = 0; kt < 16; ++kt) {
    if (kt < 15) {
      asm volatile("s_waitcnt vmcnt(4)" ::: "memory");  // own tile-kt loads done
    } else {
      asm volatile("s_waitcnt vmcnt(0)" ::: "memory");  // final drain
    }
    __builtin_amdgcn_sched_barrier(0);
    __builtin_amdgcn_s_barrier();  // all waves' tile-kt data in LDS
    const int bf = kt & 1;
    f16x8 ah[4], al[4];
#pragma unroll
    for (int mf = 0; mf < 4; ++mf) {
      ah[mf] = *(const f16x8*)&Ah[bf][wr * 64 + mf * 16 + fr][sl];
      al[mf] = *(const f16x8*)&Al[bf][wr * 64 + mf * 16 + fr][sl];
    }
#pragma unroll
    for (int nf = 0; nf < 4; ++nf) {
      f16x8 bhf = *(const f16x8*)&Bs[bf][wc * 64 + nf * 16 + fr][sl];
#pragma unroll
      for (int mf = 0; mf < 4; ++mf) {
        acc[mf][nf] =
            __builtin_amdgcn_mfma_f32_16x16x32_f16(ah[mf], bhf, acc[mf][nf], 0, 0, 0);
        acc[mf][nf] =
            __builtin_amdgcn_mfma_f32_16x16x32_f16(al[mf], bhf, acc[mf][nf], 0, 0, 0);
      }
    }
    __builtin_amdgcn_s_barrier();  // all waves done reading buf bf
    if (kt + 2 < 16) STAGE(kt + 2, bf);
  }
  if (PM == 1) {
    unsigned short* Ch = (unsigned short*)Cv;
#pragma unroll
    for (int mf = 0; mf < 4; ++mf) {
#pragma unroll
      for (int r = 0; r < 4; ++r) {
        int row = rb + wr * 64 + mf * 16 + kg * 4 + r;
#pragma unroll
        for (int nf = 0; nf < 4; ++nf) {
          int col = cb + wc * 64 + nf * 16 + fr;
          Ch[(size_t)row * 1536 + col] = f16_1(acc[mf][nf][r]);
        }
      }
    }
  } else {
    float* Cf = (float*)Cv + (size_t)blockIdx.z * TT * DD;
#pragma unroll
    for (int mf = 0; mf < 4; ++mf) {
#pragma unroll
      for (int r = 0; r < 4; ++r) {
        int row = rb + wr * 64 + mf * 16 + kg * 4 + r;
        if (row >= TT) continue;
#pragma unroll
        for (int nf = 0; nf < 4; ++nf) {
          int col = cb + wc * 64 + nf * 16 + fr;
          float old = Cf[(size_t)row * DD + col];
          Cf[(size_t)row * DD + col] = old + acc[mf][nf][r] + bias[col];
        }
      }
    }
  }
}

// ------------------------- LN + pad -> writes f16 hi/lo planes (qkv A operand)
__global__ __launch_bounds__(256) void k_ln_pad(
    unsigned short* __restrict__ xph, unsigned short* __restrict__ xpl,
    const float* __restrict__ h, const float* __restrict__ gam,
    const float* __restrict__ bet) {
  int w = threadIdx.x >> 6, lane = threadIdx.x & 63;
  int row = blockIdx.x * 4 + w;
  if (row >= BB * TT) return;
  int b = row / TT, i = row - b * TT;
  const float* src = h + (size_t)row * DD;
  float4 x0 = *(const float4*)(src + lane * 4);
  float4 x1 = *(const float4*)(src + 256 + lane * 4);
  float s = x0.x + x0.y + x0.z + x0.w + x1.x + x1.y + x1.z + x1.w;
  for (int o = 32; o; o >>= 1) s += __shfl_xor(s, o);
  float mu = s * (1.f / 512.f);
  float q = (x0.x - mu) * (x0.x - mu) + (x0.y - mu) * (x0.y - mu) +
            (x0.z - mu) * (x0.z - mu) + (x0.w - mu) * (x0.w - mu) +
            (x1.x - mu) * (x1.x - mu) + (x1.y - mu) * (x1.y - mu) +
            (x1.z - mu) * (x1.z - mu) + (x1.w - mu) * (x1.w - mu);
  for (int o = 32; o; o >>= 1) q += __shfl_xor(q, o);
  float rs = rsqrtf(q * (1.f / 512.f) + 1e-5f);
  float4 g0 = *(const float4*)(gam + lane * 4);
  float4 g1 = *(const float4*)(gam + 256 + lane * 4);
  float4 b0 = *(const float4*)(bet + lane * 4);
  float4 b1 = *(const float4*)(bet + 256 + lane * 4);
  float4 o0, o1;
  o0.x = (x0.x - mu) * rs * g0.x + b0.x;
  o0.y = (x0.y - mu) * rs * g0.y + b0.y;
  o0.z = (x0.z - mu) * rs * g0.z + b0.z;
  o0.w = (x0.w - mu) * rs * g0.w + b0.w;
  o1.x = (x1.x - mu) * rs * g1.x + b1.x;
  o1.y = (x1.y - mu) * rs * g1.y + b1.y;
  o1.z = (x1.z - mu) * rs * g1.z + b1.z;
  o1.w = (x1.w - mu) * rs * g1.w + b1.w;
  size_t ro = ((size_t)b * NPAD + PADF + i) * DD;
  store4h(o0, xph + ro + lane * 4, xpl + ro + lane * 4);
  store4h(o1, xph + ro + 256 + lane * 4, xpl + ro + 256 + lane * 4);
}

__global__ void k_zero_pad(unsigned short* __restrict__ xph,
                           unsigned short* __restrict__ xpl) {
  int r = blockIdx.x;
  int b = r / PADF, j = r - b * PADF;
  size_t ro = ((size_t)b * NPAD + j) * DD;
  ((unsigned*)(xph + ro))[threadIdx.x] = 0u;
  ((unsigned*)(xpl + ro))[threadIdx.x] = 0u;
}

// ---------------------------------------------------------------- landmarks (f16 qkv)
__global__ __launch_bounds__(256) void k_landmarks(
    float* __restrict__ ql, float* __restrict__ kl,
    const unsigned short* __restrict__ qkv) {
  int t = threadIdx.x;
  int mi = t >> 6, d = t & 63;
  int blk = blockIdx.x;
  int bh = blk >> 6, mg = blk & 63;
  int b = bh >> 3, h = bh & 7;
  int m = mg * 4 + mi;
  const unsigned short* base = qkv + (size_t)b * NPAD * 1536 + h * 64 + d;
  float sq = 0.f, sk = 0.f;
  int t0 = m * 65;
  for (int j = 0; j < 65; ++j) {
    const unsigned short* p = base + (size_t)(t0 + j) * 1536;
    sq += f16f(p[0]);
    sk += f16f(p[512]);
  }
  ql[((size_t)bh * 256 + m) * 64 + d] = sq * (0.125f / 65.f);
  kl[((size_t)bh * 256 + m) * 64 + d] = sk * (1.f / 65.f);
}

// ---------------------------------------------------------------- sim2 = ql @ kl^T
__global__ __launch_bounds__(256) void k_sim2(
    float* __restrict__ sim, const float* __restrict__ ql, const float* __restrict__ kl) {
  __shared__ __align__(16) float Aq[64][68];
  __shared__ __align__(16) float Bk[64][68];
  int t = threadIdx.x;
  int tj = blockIdx.x, ti = blockIdx.y, bh = blockIdx.z;
  int r = t >> 2, cc = (t & 3) * 16;
  const float* ap = ql + ((size_t)bh * 256 + ti * 64 + r) * 64 + cc;
  const float* bp = kl + ((size_t)bh * 256 + tj * 64 + r) * 64 + cc;
#pragma unroll
  for (int i = 0; i < 16; i += 4) {
    *(float4*)&Aq[r][cc + i] = *(const float4*)(ap + i);
    *(float4*)&Bk[r][cc + i] = *(const float4*)(bp + i);
  }
  __syncthreads();
  int tx = t & 15, ty = t >> 4;
  float acc[4][4];
#pragma unroll
  for (int i = 0; i < 4; ++i)
#pragma unroll
    for (int j = 0; j < 4; ++j) acc[i][j] = 0.f;
  for (int d = 0; d < 64; d += 4) {
    float4 a4[4], b4[4];
#pragma unroll
    for (int ii = 0; ii < 4; ++ii) a4[ii] = *(float4*)&Aq[ty * 4 + ii][d];
#pragma unroll
    for (int jj = 0; jj < 4; ++jj) b4[jj] = *(float4*)&Bk[tx * 4 + jj][d];
#pragma unroll
    for (int ii = 0; ii < 4; ++ii)
#pragma unroll
      for (int jj = 0; jj < 4; ++jj)
        acc[ii][jj] += a4[ii].x * b4[jj].x + a4[ii].y * b4[jj].y + a4[ii].z * b4[jj].z +
                       a4[ii].w * b4[jj].w;
  }
#pragma unroll
  for (int ii = 0; ii < 4; ++ii)
#pragma unroll
    for (int jj = 0; jj < 4; ++jj)
      sim[((size_t)bh * 256 + ti * 64 + ty * 4 + ii) * 256 + tj * 64 + tx * 4 + jj] =
          acc[ii][jj];
}

// ---------------------------------------------------------------- row softmax (len 256)
__global__ __launch_bounds__(256) void k_softmax256(float* __restrict__ a) {
  int w = threadIdx.x >> 6, lane = threadIdx.x & 63;
  size_t row = (size_t)blockIdx.x * 4 + w;
  float* p = a + row * 256 + lane * 4;
  float4 v = *(float4*)p;
  float m = fmaxf(fmaxf(v.x, v.y), fmaxf(v.z, v.w));
  for (int o = 32; o; o >>= 1) m = fmaxf(m, __shfl_xor(m, o));
  v.x = expf(v.x - m); v.y = expf(v.y - m);
  v.z = expf(v.z - m); v.w = expf(v.w - m);
  float s = v.x + v.y + v.z + v.w;
  for (int o = 32; o; o >>= 1) s += __shfl_xor(s, o);
  float inv = 1.f / s;
  v.x *= inv; v.y *= inv; v.z *= inv; v.w *= inv;
  *(float4*)p = v;
}

// ---------------------------------------------------------------- pinv helpers
__global__ void k_pinv_sums(float* __restrict__ red, const float* __restrict__ a2) {
  int bh = blockIdx.x, t = threadIdx.x;
  const float* Ab = a2 + (size_t)bh * 65536;
  float s = 0.f;
  for (int i = 0; i < 256; ++i) s += fabsf(Ab[(size_t)i * 256 + t]);
  red[bh * 256 + t] = s;
  float c = 0.f;
  const float* rp = Ab + (size_t)t * 256;
  for (int j = 0; j < 256; j += 4) {
    float4 v = *(const float4*)(rp + j);
    c += fabsf(v.x) + fabsf(v.y) + fabsf(v.z) + fabsf(v.w);
  }
  red[4096 + bh * 256 + t] = c;
}

__global__ void k_pinv_scale(float* __restrict__ red) {
  __shared__ float sm[8];
  int t = threadIdx.x;
  float m1 = 0.f, m2 = 0.f;
  for (int k = t; k < 4096; k += 256) {
    m1 = fmaxf(m1, red[k]);
    m2 = fmaxf(m2, red[4096 + k]);
  }
  for (int o = 32; o; o >>= 1) {
    m1 = fmaxf(m1, __shfl_xor(m1, o));
    m2 = fmaxf(m2, __shfl_xor(m2, o));
  }
  int w = t >> 6;
  if ((t & 63) == 0) { sm[w] = m1; sm[4 + w] = m2; }
  __syncthreads();
  if (t == 0) {
    float a = fmaxf(fmaxf(sm[0], sm[1]), fmaxf(sm[2], sm[3]));
    float b = fmaxf(fmaxf(sm[4], sm[5]), fmaxf(sm[6], sm[7]));
    red[8192] = 1.0f / (a * b);
  }
}

__global__ void k_zinit(float* __restrict__ z, const float* __restrict__ a2,
                        const float* __restrict__ red) {
  float s = red[8192];
  int i = blockIdx.x, bh = blockIdx.y, j = threadIdx.x;
  z[((size_t)bh * 256 + i) * 256 + j] = a2[((size_t)bh * 256 + j) * 256 + i] * s;
}

// ---- shared BK=128 f16 3-term matmul core: acc += A[i0..i0+64) @ B (256xN)
__device__ __forceinline__ void bmm_core(
    short (*Ash)[136], short (*Asl)[136], short (*Bsh)[136], short (*Bsl)[136],
    const float* __restrict__ Ab, const float* __restrict__ Bb, int i0, int j0, int N,
    int t, f32x4 (&acc)[4]) {
  const int lane = t & 63, w = t >> 6;
  const int fr = lane & 15, kg = lane >> 4;
  const int ar = t >> 2, akseg = (t & 3) * 32;  // A: 32 floats / thread
  for (int k0 = 0; k0 < 256; k0 += 128) {
    __syncthreads();
    {  // stage A rows (f16 split): 64 rows x 128 k
      const float* p = Ab + (size_t)(i0 + ar) * 256 + k0 + akseg;
#pragma unroll
      for (int q = 0; q < 4; ++q) {
        float4 f0 = *(const float4*)(p + q * 8);
        float4 f1 = *(const float4*)(p + q * 8 + 4);
        unsigned h0, h1, h2, h3, l0, l1, l2, l3;
        split2h(f0.x, f0.y, h0, l0);
        split2h(f0.z, f0.w, h1, l1);
        split2h(f1.x, f1.y, h2, l2);
        split2h(f1.z, f1.w, h3, l3);
        *(uint4*)&Ash[ar][akseg + q * 8] = make_uint4(h0, h1, h2, h3);
        *(uint4*)&Asl[ar][akseg + q * 8] = make_uint4(l0, l1, l2, l3);
      }
    }
    {  // stage B transposed (f16 split): Bsh[j_local][k_local], 128 k-rows x 64 j
#pragma unroll
      for (int pass = 0; pass < 8; ++pass) {
        int kr = pass * 16 + (t >> 4);
        int jseg = (t & 15) * 4;
        const float* p = Bb + (size_t)(k0 + kr) * N + j0 + jseg;
        float4 f = *(const float4*)p;
        float fv[4] = {f.x, f.y, f.z, f.w};
#pragma unroll
        for (int c = 0; c < 4; ++c) {
          _Float16 hh = (_Float16)fv[c];
          float lo = fv[c] - (float)hh;
          Bsh[jseg + c][kr] = (short)__builtin_bit_cast(unsigned short, hh);
          Bsl[jseg + c][kr] = (short)f16_1(lo);
        }
      }
    }
    __syncthreads();
#pragma unroll
    for (int kw = 0; kw < 4; ++kw) {
      f16x8 bhf = *(const f16x8*)&Bsh[w * 16 + fr][kw * 32 + kg * 8];
      f16x8 blf = *(const f16x8*)&Bsl[w * 16 + fr][kw * 32 + kg * 8];
#pragma unroll
      for (int mf = 0; mf < 4; ++mf) {
        f16x8 ah = *(const f16x8*)&Ash[mf * 16 + fr][kw * 32 + kg * 8];
        f16x8 al = *(const f16x8*)&Asl[mf * 16 + fr][kw * 32 + kg * 8];
        acc[mf] = __builtin_amdgcn_mfma_f32_16x16x32_f16(ah, bhf, acc[mf], 0, 0, 0);
        acc[mf] = __builtin_amdgcn_mfma_f32_16x16x32_f16(al, bhf, acc[mf], 0, 0, 0);
        acc[mf] = __builtin_amdgcn_mfma_f32_16x16x32_f16(ah, blf, acc[mf], 0, 0, 0);
      }
    }
  }
}

// ------- batched 256x256 @ 256xN; C = a1*(A@B) + d1*I + e1*E (E optional)
__global__ __launch_bounds__(256) void k_bmm_poly(
    const float* __restrict__ A, const float* __restrict__ Bm,
    const float* __restrict__ E, float* __restrict__ C, float a1, float d1, float e1,
    int N) {
  __shared__ short Ash[64][136];
  __shared__ short Asl[64][136];
  __shared__ short Bsh[64][136];
  __shared__ short Bsl[64][136];
  const int t = threadIdx.x;
  const int bh = blockIdx.z;
  const int i0 = blockIdx.y * 64, j0 = blockIdx.x * 64;
  const int lane = t & 63, w = t >> 6;
  const int fr = lane & 15, kg = lane >> 4;
  f32x4 acc[4];
  f32x4 zero4 = {0.f, 0.f, 0.f, 0.f};
#pragma unroll
  for (int i = 0; i < 4; ++i) acc[i] = zero4;
  bmm_core(Ash, Asl, Bsh, Bsl, A + (size_t)bh * 65536, Bm + (size_t)bh * 256 * N, i0,
           j0, N, t, acc);
  int j = j0 + w * 16 + fr;
#pragma unroll
  for (int mf = 0; mf < 4; ++mf) {
#pragma unroll
    for (int rr = 0; rr < 4; ++rr) {
      int i = i0 + mf * 16 + kg * 4 + rr;
      float v = acc[mf][rr];
      size_t off = (size_t)bh * 256 * N + (size_t)i * N + j;
      float out = a1 * v + ((i == j) ? d1 : 0.f);
      if (E) out += e1 * E[off];
      C[off] = out;
    }
  }
}

// ------- dual batched: z<16: C0 = s*(A0@B); z>=16: C1 = s*(A1@B)   (N=256)
__global__ __launch_bounds__(256) void k_bmm_dual(
    const float* __restrict__ A0, const float* __restrict__ A1,
    const float* __restrict__ Bm, float* __restrict__ C0, float* __restrict__ C1,
    float s) {
  __shared__ short Ash[64][136];
  __shared__ short Asl[64][136];
  __shared__ short Bsh[64][136];
  __shared__ short Bsl[64][136];
  const int t = threadIdx.x;
  const int z = blockIdx.z;
  const int bh = z & 15;
  const int sel = z >> 4;
  const float* A = sel ? A1 : A0;
  float* C = sel ? C1 : C0;
  const int i0 = blockIdx.y * 64, j0 = blockIdx.x * 64;
  const int lane = t & 63, w = t >> 6;
  const int fr = lane & 15, kg = lane >> 4;
  f32x4 acc[4];
  f32x4 zero4 = {0.f, 0.f, 0.f, 0.f};
#pragma unroll
  for (int i = 0; i < 4; ++i) acc[i] = zero4;
  bmm_core(Ash, Asl, Bsh, Bsl, A + (size_t)bh * 65536, Bm + (size_t)bh * 65536, i0, j0,
           256, t, acc);
  int j = j0 + w * 16 + fr;
#pragma unroll
  for (int mf = 0; mf < 4; ++mf) {
#pragma unroll
    for (int rr = 0; rr < 4; ++rr) {
      int i = i0 + mf * 16 + kg * 4 + rr;
      size_t off = (size_t)bh * 65536 + (size_t)i * 256 + j;
      C[off] = s * acc[mf][rr];
    }
  }
}

// -------------------------- a3 @ v : MFMA flash (f16 qkv, no-max, split-K chunks)
__global__ __launch_bounds__(256, 2) void k_a3v_mfma(
    float* __restrict__ pacc, float* __restrict__ pL,
    const float* __restrict__ ql, const unsigned short* __restrict__ qkv) {
  __shared__ short Ks[64][72];
  __shared__ short Vt[64][72];
  __shared__ short Ps[4][64][72];
  const int t = threadIdx.x;
  const int bh = blockIdx.x;
  const int kc = blockIdx.y;
  const int b = bh >> 3, h = bh & 7;
  const int lane = t & 63, w = t >> 6;
  const int fr = lane & 15, kg = lane >> 4;

  f16x8 qf[4][2];
#pragma unroll
  for (int nf = 0; nf < 4; ++nf) {
    const float* qp = ql + ((size_t)bh * 256 + w * 64 + nf * 16 + fr) * 64 + kg * 8;
#pragma unroll
    for (int kw = 0; kw < 2; ++kw) {
      float4 a = *(const float4*)(qp + kw * 32);
      float4 c = *(const float4*)(qp + kw * 32 + 4);
      uint4 uu = make_uint4(pk_f16(a.x, a.y), pk_f16(a.z, a.w), pk_f16(c.x, c.y),
                            pk_f16(c.z, c.w));
      qf[nf][kw] = *(f16x8*)&uu;
    }
  }
  f32x4 oacc[4][4];
  f32x4 zero4 = {0.f, 0.f, 0.f, 0.f};
#pragma unroll
  for (int i = 0; i < 4; ++i)
#pragma unroll
    for (int j = 0; j < 4; ++j) oacc[i][j] = zero4;
  float Lp[4] = {0.f, 0.f, 0.f, 0.f};

  const int skey = t >> 2, sd = (t & 3) * 16;
  const unsigned short* kbase = qkv + (size_t)b * NPAD * 1536 + 512 + h * 64 + sd;

  for (int it = 0; it < A3CH / 64; ++it) {
    int nt = kc * A3CH + it * 64;
    __syncthreads();
    {
      const unsigned short* kp = kbase + (size_t)(nt + skey) * 1536;
      *(uint4*)&Ks[skey][sd] = *(const uint4*)kp;
      *(uint4*)&Ks[skey][sd + 8] = *(const uint4*)(kp + 8);
      const unsigned short* vp = kp + 512;
      uint4 v01 = *(const uint4*)vp;
      uint4 v23 = *(const uint4*)(vp + 8);
      Vt[sd + 0][skey] = (short)v01.x;
      Vt[sd + 1][skey] = (short)(v01.x >> 16);
      Vt[sd + 2][skey] = (short)v01.y;
      Vt[sd + 3][skey] = (short)(v01.y >> 16);
      Vt[sd + 4][skey] = (short)v01.z;
      Vt[sd + 5][skey] = (short)(v01.z >> 16);
      Vt[sd + 6][skey] = (short)v01.w;
      Vt[sd + 7][skey] = (short)(v01.w >> 16);
      Vt[sd + 8][skey] = (short)v23.x;
      Vt[sd + 9][skey] = (short)(v23.x >> 16);
      Vt[sd + 10][skey] = (short)v23.y;
      Vt[sd + 11][skey] = (short)(v23.y >> 16);
      Vt[sd + 12][skey] = (short)v23.z;
      Vt[sd + 13][skey] = (short)(v23.z >> 16);
      Vt[sd + 14][skey] = (short)v23.w;
      Vt[sd + 15][skey] = (short)(v23.w >> 16);
    }
    __syncthreads();
    f32x4 sacc[4][4];
#pragma unroll
    for (int i = 0; i < 4; ++i)
#pragma unroll
      for (int j = 0; j < 4; ++j) sacc[i][j] = zero4;
#pragma unroll
    for (int kw = 0; kw < 2; ++kw) {
      f16x8 kf[4];
#pragma unroll
      for (int mf = 0; mf < 4; ++mf)
        kf[mf] = *(const f16x8*)&Ks[mf * 16 + fr][kw * 32 + kg * 8];
#pragma unroll
      for (int mf = 0; mf < 4; ++mf)
#pragma unroll
        for (int nf = 0; nf < 4; ++nf)
          sacc[mf][nf] = __builtin_amdgcn_mfma_f32_16x16x32_f16(kf[mf], qf[nf][kw],
                                                                sacc[mf][nf], 0, 0, 0);
    }
#pragma unroll
    for (int mf = 0; mf < 4; ++mf)
#pragma unroll
      for (int nf = 0; nf < 4; ++nf) {
        f32x4 s = sacc[mf][nf];
        float p0 = __expf(s[0]);
        float p1 = __expf(s[1]);
        float p2 = __expf(s[2]);
        float p3 = __expf(s[3]);
        Lp[nf] += (p0 + p1) + (p2 + p3);
        uint2 pw = make_uint2(pk_f16(p0, p1), pk_f16(p2, p3));
        *(uint2*)&Ps[w][nf * 16 + fr][mf * 16 + kg * 4] = pw;
      }
    __syncthreads();
#pragma unroll
    for (int kw = 0; kw < 2; ++kw) {
      f16x8 vf[4], pf[4];
#pragma unroll
      for (int mf = 0; mf < 4; ++mf)
        vf[mf] = *(const f16x8*)&Vt[mf * 16 + fr][kw * 32 + kg * 8];
#pragma unroll
      for (int nf = 0; nf < 4; ++nf)
        pf[nf] = *(const f16x8*)&Ps[w][nf * 16 + fr][kw * 32 + kg * 8];
#pragma unroll
      for (int mf = 0; mf < 4; ++mf)
#pragma unroll
        for (int nf = 0; nf < 4; ++nf)
          oacc[mf][nf] = __builtin_amdgcn_mfma_f32_16x16x32_f16(vf[mf], pf[nf],
                                                                oacc[mf][nf], 0, 0, 0);
    }
  }
  size_t obase = ((size_t)kc * 16 + bh) * 256;
#pragma unroll
  for (int mf = 0; mf < 4; ++mf)
#pragma unroll
    for (int nf = 0; nf < 4; ++nf) {
      int lm = w * 64 + nf * 16 + fr;
      *(f32x4*)(pacc + (obase + lm) * 64 + mf * 16 + kg * 4) = oacc[mf][nf];
    }
#pragma unroll
  for (int nf = 0; nf < 4; ++nf) {
    Lp[nf] += __shfl_xor(Lp[nf], 16);
    Lp[nf] += __shfl_xor(Lp[nf], 32);
  }
  if (lane < 16) {
#pragma unroll
    for (int nf = 0; nf < 4; ++nf)
      pL[obase + w * 64 + nf * 16 + lane] = Lp[nf];
  }
}

__global__ __launch_bounds__(64) void k_a3v_red(
    float* __restrict__ bv, const float* __restrict__ pacc,
    const float* __restrict__ pL) {
  int row = blockIdx.x;
  int d = threadIdx.x;
  float A = 0.f, L = 0.f;
#pragma unroll
  for (int c = 0; c < A3KC; ++c) {
    size_t pr = (size_t)c * 4096 + row;
    A += pacc[pr * 64 + d];
    L += pL[pr];
  }
  bv[(size_t)row * 64 + d] = A / L;
}

// ------------- fused sim1: softmax(q @ (0.125*kl)^T) @ w2 -> f16 hi/lo planes
__global__ __launch_bounds__(256, 2) void k_att1(
    unsigned short* __restrict__ xph, unsigned short* __restrict__ xpl,
    const unsigned short* __restrict__ qkv, const float* __restrict__ kl,
    const float* __restrict__ w2) {
  __shared__ short KLs[64][72];
  __shared__ short W2t[64][72];
  __shared__ short Ps[4][64][72];
  const int t = threadIdx.x;
  const int tile = blockIdx.x, bh = blockIdx.y;
  const int b = bh >> 3, h = bh & 7;
  const int lane = t & 63, w = t >> 6;
  const int fr = lane & 15, kg = lane >> 4;
  const int n0 = tile * 256;

  f16x8 qf[4][2];
#pragma unroll
  for (int nf = 0; nf < 4; ++nf) {
    const unsigned short* qp =
        qkv + ((size_t)b * NPAD + n0 + w * 64 + nf * 16 + fr) * 1536 + h * 64 + kg * 8;
    qf[nf][0] = *(const f16x8*)qp;
    qf[nf][1] = *(const f16x8*)(qp + 32);
  }
  f32x4 oacc[4][4];
  f32x4 zero4 = {0.f, 0.f, 0.f, 0.f};
#pragma unroll
  for (int i = 0; i < 4; ++i)
#pragma unroll
    for (int j = 0; j < 4; ++j) oacc[i][j] = zero4;
  float Lp[4] = {0.f, 0.f, 0.f, 0.f};

  const int sr = t >> 2, sc = (t & 3) * 16;
  for (int cb = 0; cb < 4; ++cb) {
    __syncthreads();
    {
      const float* kp = kl + ((size_t)bh * 256 + cb * 64 + sr) * 64 + sc;
      float4 k0 = *(const float4*)kp;
      float4 k1 = *(const float4*)(kp + 4);
      float4 k2 = *(const float4*)(kp + 8);
      float4 k3 = *(const float4*)(kp + 12);
      *(uint4*)&KLs[sr][sc] =
          make_uint4(pk_f16(k0.x * 0.125f, k0.y * 0.125f),
                     pk_f16(k0.z * 0.125f, k0.w * 0.125f),
                     pk_f16(k1.x * 0.125f, k1.y * 0.125f),
                     pk_f16(k1.z * 0.125f, k1.w * 0.125f));
      *(uint4*)&KLs[sr][sc + 8] =
          make_uint4(pk_f16(k2.x * 0.125f, k2.y * 0.125f),
                     pk_f16(k2.z * 0.125f, k2.w * 0.125f),
                     pk_f16(k3.x * 0.125f, k3.y * 0.125f),
                     pk_f16(k3.z * 0.125f, k3.w * 0.125f));
      const float* wp = w2 + ((size_t)bh * 256 + cb * 64 + sr) * 64 + sc;
      float4 v0 = *(const float4*)wp;
      float4 v1 = *(const float4*)(wp + 4);
      float4 v2 = *(const float4*)(wp + 8);
      float4 v3 = *(const float4*)(wp + 12);
      W2t[sc + 0][sr] = (short)f16_1(v0.x);
      W2t[sc + 1][sr] = (short)f16_1(v0.y);
      W2t[sc + 2][sr] = (short)f16_1(v0.z);
      W2t[sc + 3][sr] = (short)f16_1(v0.w);
      W2t[sc + 4][sr] = (short)f16_1(v1.x);
      W2t[sc + 5][sr] = (short)f16_1(v1.y);
      W2t[sc + 6][sr] = (short)f16_1(v1.z);
      W2t[sc + 7][sr] = (short)f16_1(v1.w);
      W2t[sc + 8][sr] = (short)f16_1(v2.x);
      W2t[sc + 9][sr] = (short)f16_1(v2.y);
      W2t[sc + 10][sr] = (short)f16_1(v2.z);
      W2t[sc + 11][sr] = (short)f16_1(v2.w);
      W2t[sc + 12][sr] = (short)f16_1(v3.x);
      W2t[sc + 13][sr] = (short)f16_1(v3.y);
      W2t[sc + 14][sr] = (short)f16_1(v3.z);
      W2t[sc + 15][sr] = (short)f16_1(v3.w);
    }
    __syncthreads();
    f32x4 sacc[4][4];
#pragma unroll
    for (int i = 0; i < 4; ++i)
#pragma unroll
      for (int j = 0; j < 4; ++j) sacc[i][j] = zero4;
#pragma unroll
    for (int kw = 0; kw < 2; ++kw) {
      f16x8 kf[4];
#pragma unroll
      for (int mf = 0; mf < 4; ++mf)
        kf[mf] = *(const f16x8*)&KLs[mf * 16 + fr][kw * 32 + kg * 8];
#pragma unroll
      for (int mf = 0; mf < 4; ++mf)
#pragma unroll
        for (int nf = 0; nf < 4; ++nf)
          sacc[mf][nf] = __builtin_amdgcn_mfma_f32_16x16x32_f16(kf[mf], qf[nf][kw],
                                                                sacc[mf][nf], 0, 0, 0);
    }
#pragma unroll
    for (int mf = 0; mf < 4; ++mf)
#pragma unroll
      for (int nf = 0; nf < 4; ++nf) {
        f32x4 s = sacc[mf][nf];
        float p0 = __expf(s[0]);
        float p1 = __expf(s[1]);
        float p2 = __expf(s[2]);
        float p3 = __expf(s[3]);
        Lp[nf] += (p0 + p1) + (p2 + p3);
        uint2 pw = make_uint2(pk_f16(p0, p1), pk_f16(p2, p3));
        *(uint2*)&Ps[w][nf * 16 + fr][mf * 16 + kg * 4] = pw;
      }
    __syncthreads();
#pragma unroll
    for (int kw = 0; kw < 2; ++kw) {
      f16x8 vf[4], pf[4];
#pragma unroll
      for (int mf = 0; mf < 4; ++mf)
        vf[mf] = *(const f16x8*)&W2t[mf * 16 + fr][kw * 32 + kg * 8];
#pragma unroll
      for (int nf = 0; nf < 4; ++nf)
        pf[nf] = *(const f16x8*)&Ps[w][nf * 16 + fr][kw * 32 + kg * 8];
#pragma unroll
      for (int mf = 0; mf < 4; ++mf)
#pragma unroll
        for (int nf = 0; nf < 4; ++nf)
          oacc[mf][nf] = __builtin_amdgcn_mfma_f32_16x16x32_f16(vf[mf], pf[nf],
                                                                oacc[mf][nf], 0, 0, 0);
    }
  }
#pragma unroll
  for (int nf = 0; nf < 4; ++nf) {
    Lp[nf] += __shfl_xor(Lp[nf], 16);
    Lp[nf] += __shfl_xor(Lp[nf], 32);
  }
#pragma unroll
  for (int nf = 0; nf < 4; ++nf) {
    float inv = 1.0f / Lp[nf];
    int tok = n0 + w * 64 + nf * 16 + fr;
#pragma unroll
    for (int mf = 0; mf < 4; ++mf) {
      f32x4 o = oacc[mf][nf];
      float4 ov = make_float4(o[0] * inv, o[1] * inv, o[2] * inv, o[3] * inv);
      size_t ro = ((size_t)b * NPAD + tok) * DD + h * 64 + mf * 16 + kg * 4;
      store4h(ov, xph + ro, xpl + ro);
    }
  }
}

// ---------------- planes += depthwise33(v); grid (NPAD/64, 16 bh); v is f16
__global__ __launch_bounds__(256) void k_convres(
    unsigned short* __restrict__ xph, unsigned short* __restrict__ xpl,
    const unsigned short* __restrict__ qkv, const float* __restrict__ resw) {
  __shared__ float vS[96][68];
  __shared__ float w33[33];
  int t = threadIdx.x;
  int tb = blockIdx.x, bh = blockIdx.y;
  int b = bh >> 3, h = bh & 7;
  int n0 = tb * 64;
  if (t < 33) w33[t] = resw[h * 33 + t];
  int sc = (t & 3) * 16;
#pragma unroll
  for (int pass = 0; pass < 2; ++pass) {
    int r = (t >> 2) + pass * 64;
    if (r < 96) {
      int seq = n0 - 16 + r;
      if (seq >= 0 && seq < NPAD) {
        const unsigned short* p =
            qkv + ((size_t)b * NPAD + seq) * 1536 + 1024 + h * 64 + sc;
        uint4 u0 = *(const uint4*)p;
        uint4 u1 = *(const uint4*)(p + 8);
        vS[r][sc + 0] = f16f(u0.x); vS[r][sc + 1] = f16f(u0.x >> 16);
        vS[r][sc + 2] = f16f(u0.y); vS[r][sc + 3] = f16f(u0.y >> 16);
        vS[r][sc + 4] = f16f(u0.z); vS[r][sc + 5] = f16f(u0.z >> 16);
        vS[r][sc + 6] = f16f(u0.w); vS[r][sc + 7] = f16f(u0.w >> 16);
        vS[r][sc + 8] = f16f(u1.x); vS[r][sc + 9] = f16f(u1.x >> 16);
        vS[r][sc + 10] = f16f(u1.y); vS[r][sc + 11] = f16f(u1.y >> 16);
        vS[r][sc + 12] = f16f(u1.z); vS[r][sc + 13] = f16f(u1.z >> 16);
        vS[r][sc + 14] = f16f(u1.w); vS[r][sc + 15] = f16f(u1.w >> 16);
      } else {
#pragma unroll
        for (int i = 0; i < 16; ++i) vS[r][sc + i] = 0.f;
      }
    }
  }
  __syncthreads();
  int tg = t >> 5;
  int d2 = (t & 31) * 2;
#pragma unroll
  for (int tk = 0; tk < 8; ++tk) {
    int tokL = tg * 8 + tk;
    float ax = 0.f, ay = 0.f;
    for (int k = 0; k < 33; ++k) {
      float2 v = *(float2*)&vS[tokL + k][d2];
      ax += w33[k] * v.x;
      ay += w33[k] * v.y;
    }
    size_t off = ((size_t)b * NPAD + n0 + tokL) * DD + h * 64 + d2;
    unsigned hv = *(unsigned*)(xph + off);
    unsigned lv = *(unsigned*)(xpl + off);
    float x0 = f16f(hv) + f16f(lv) + ax;
    float x1 = f16f(hv >> 16) + f16f(lv >> 16) + ay;
    unsigned nh, nl;
    split2h(x0, x1, nh, nl);
    *(unsigned*)(xph + off) = nh;
    *(unsigned*)(xpl + off) = nl;
  }
}

// ---------------------------------------------------------------- PPEG (combined 7x7)
__global__ __launch_bounds__(128) void k_ppeg(
    float* __restrict__ hB, const float* __restrict__ hA,
    const float* __restrict__ w7, const float* __restrict__ b7,
    const float* __restrict__ w5, const float* __restrict__ b5,
    const float* __restrict__ w3, const float* __restrict__ b3) {
  __shared__ float cw[49][128];
  int t = threadIdx.x;
  int i = blockIdx.x >> 2;
  int j0 = (blockIdx.x & 3) * 32;
  int cg = blockIdx.y, b = blockIdx.z;
  int c = cg * 128 + t;
#pragma unroll
  for (int k = 0; k < 49; ++k) cw[k][t] = w7[c * 49 + k];
#pragma unroll
  for (int di = 0; di < 5; ++di)
#pragma unroll
    for (int dj = 0; dj < 5; ++dj)
      cw[(di + 1) * 7 + dj + 1][t] += w5[c * 25 + di * 5 + dj];
#pragma unroll
  for (int di = 0; di < 3; ++di)
#pragma unroll
    for (int dj = 0; dj < 3; ++dj)
      cw[(di + 2) * 7 + dj + 2][t] += w3[c * 9 + di * 3 + dj];
  cw[24][t] += 1.0f;
  float bias = b7[c] + b5[c] + b3[c];
  const float* base = hA + (size_t)b * TT * DD + DD + c;
  float* obase = hB + (size_t)b * TT * DD + DD + c;
  float acc[32];
#pragma unroll
  for (int j = 0; j < 32; ++j) acc[j] = bias;
  for (int di = 0; di < 7; ++di) {
    int ii = i + di - 3;
    if ((unsigned)ii >= 128u) continue;
    float win[38];
#pragma unroll
    for (int w = 0; w < 38; ++w) {
      int col = j0 - 3 + w;
      win[w] = ((unsigned)col < 128u) ? base[(size_t)(ii * 128 + col) * DD] : 0.f;
    }
#pragma unroll
    for (int dj = 0; dj < 7; ++dj) {
      float wv = cw[di * 7 + dj][t];
#pragma unroll
      for (int j = 0; j < 32; ++j) acc[j] += win[j + dj] * wv;
    }
  }
#pragma unroll
  for (int j = 0; j < 32; ++j) obase[(size_t)(i * 128 + j0 + j) * DD] = acc[j];
}

// ---------------------------------------------------------------- final head
__global__ __launch_bounds__(512) void k_final(
    float* __restrict__ out, const float* __restrict__ h,
    const float* __restrict__ g, const float* __restrict__ be,
    const float* __restrict__ cw, const float* __restrict__ cbias) {
  __shared__ float sm[16];
  int t = threadIdx.x;
  for (int b = 0; b < 2; ++b) {
    const float* row = h + (size_t)b * TT * DD;
    float x = row[t];
    float s = x;
    for (int o = 32; o; o >>= 1) s += __shfl_xor(s, o);
    if ((t & 63) == 0) sm[t >> 6] = s;
    __syncthreads();
    float mu = 0.f;
    for (int i = 0; i < 8; ++i) mu += sm[i];
    mu *= (1.f / 512.f);
    __syncthreads();
    float d = x - mu;
    s = d * d;
    for (int o = 32; o; o >>= 1) s += __shfl_xor(s, o);
    if ((t & 63) == 0) sm[t >> 6] = s;
    __syncthreads();
    float var = 0.f;
    for (int i = 0; i < 8; ++i) var += sm[i];
    var *= (1.f / 512.f);
    float rs = rsqrtf(var + 1e-5f);
    __syncthreads();
    float f = d * rs * g[t] + be[t];
    float p0 = f * cw[2 * t], p1 = f * cw[2 * t + 1];
    for (int o = 32; o; o >>= 1) {
      p0 += __shfl_xor(p0, o);
      p1 += __shfl_xor(p1, o);
    }
    if ((t & 63) == 0) {
      sm[t >> 6] = p0;
      sm[8 + (t >> 6)] = p1;
    }
    __syncthreads();
    if (t == 0) {
      float q0 = 0.f, q1 = 0.f;
      for (int i = 0; i < 8; ++i) {
        q0 += sm[i];
        q1 += sm[8 + i];
      }
      out[b * 2 + 0] = q0 + cbias[0];
      out[b * 2 + 1] = q1 + cbias[1];
    }
    __syncthreads();
  }
}

// ---------------------------------------------------------------- host side
static void run_attn(float* h, const float* lng, const float* lnb,
                     const float* wqkv, const float* wout, const float* bout,
                     const float* resw, float* xp, unsigned short* qkvh, float* ql,
                     float* kl, float* a2, float* z0, float* z1, float* xz, float* xz2,
                     float* yB, float* yC, float* bv, float* w2, float* red,
                     float* Sbuf, unsigned short* wth, hipStream_t stream) {
  // xp region holds f16 hi/lo planes: LN output, later attention output
  unsigned short* xph = (unsigned short*)xp;
  unsigned short* xpl = xph + (size_t)BB * NPAD * DD;
  k_zero_pad<<<BB * PADF, 256, 0, stream>>>(xph, xpl);
  k_ln_pad<<<(BB * TT + 3) / 4, 256, 0, stream>>>(xph, xpl, h, lng, lnb);
  k_cvt_wt<<<dim3(DD / 32, 1536 / 32), 256, 0, stream>>>(wqkv, wth, DD, 1536);
  k_gemm_pipe<1><<<dim3(BB * NPAD / 128, 1536 / 256), 512, 0, stream>>>(xph, xpl, wth,
                                                                        qkvh, nullptr);
  k_landmarks<<<1024, 256, 0, stream>>>(ql, kl, qkvh);
  float* pacc = Sbuf;
  float* pL = Sbuf + (size_t)A3KC * 4096 * 64;
  k_a3v_mfma<<<dim3(16, A3KC), 256, 0, stream>>>(pacc, pL, ql, qkvh);
  k_a3v_red<<<4096, 64, 0, stream>>>(bv, pacc, pL);
  k_sim2<<<dim3(4, 4, 16), 256, 0, stream>>>(a2, ql, kl);
  k_softmax256<<<1024, 256, 0, stream>>>(a2);
  k_pinv_sums<<<16, 256, 0, stream>>>(red, a2);
  k_pinv_scale<<<1, 256, 0, stream>>>(red);
  k_zinit<<<dim3(256, 16), 256, 0, stream>>>(z0, a2, red);
  // Newton-Schulz: 3 matmuls/iter via P = a2@z carried forward
  float* zc = z0;
  float* zn = z1;
  float* P = xz;
  float* Pn = xz2;
  // P0 = a2 @ z0
  k_bmm_poly<<<dim3(4, 4, 16), 256, 0, stream>>>(a2, zc, nullptr, P, 1.f, 0.f, 0.f, 256);
  for (int it = 0; it < 6; ++it) {
    // yB = P@P + 15I - 7P   (== 15I - P@(7I - P))
    k_bmm_poly<<<dim3(4, 4, 16), 256, 0, stream>>>(P, P, P, yB, 1.f, 15.f, -7.f, 256);
    // yC = 13I - P@yB
    k_bmm_poly<<<dim3(4, 4, 16), 256, 0, stream>>>(P, yB, nullptr, yC, -1.f, 13.f, 0.f, 256);
    // zn = 0.25 zc@yC ; Pn = 0.25 P@yC  (batched)
    k_bmm_dual<<<dim3(4, 4, 32), 256, 0, stream>>>(zc, P, yC, zn, Pn, 0.25f);
    float* tmp = zc; zc = zn; zn = tmp;
    tmp = P; P = Pn; Pn = tmp;
  }
  k_bmm_poly<<<dim3(1, 4, 16), 256, 0, stream>>>(zc, bv, nullptr, w2, 1.f, 0.f, 0.f, 64);
  k_att1<<<dim3(NPAD / 256, 16), 256, 0, stream>>>(xph, xpl, qkvh, kl, w2);
  k_convres<<<dim3(NPAD / 64, 16), 256, 0, stream>>>(xph, xpl, qkvh, resw);
  k_cvt_wt<<<dim3(DD / 32, DD / 32), 256, 0, stream>>>(wout, wth, DD, DD);
  k_gemm_pipe<2><<<dim3(129, 2, BB), 512, 0, stream>>>(xph, xpl, wth, h, bout);
}

extern "C" void kernel_launch(void* const* d_in, const int* in_sizes, int n_in,
                              void* d_out, int out_size, void* d_ws, size_t ws_size,
                              hipStream_t stream) {
  const float* x        = (const float*)d_in[0];
  const float* w_feat   = (const float*)d_in[1];
  const float* b_feat   = (const float*)d_in[2];
  const float* cls_tok  = (const float*)d_in[3];
  const float* ln1_g    = (const float*)d_in[4];
  const float* ln1_b    = (const float*)d_in[5];
  const float* qkv1     = (const float*)d_in[6];
  const float* out1_w   = (const float*)d_in[7];
  const float* out1_b   = (const float*)d_in[8];
  const float* res1_w   = (const float*)d_in[9];
  const float* ppeg_w7  = (const float*)d_in[10];
  const float* ppeg_b7  = (const float*)d_in[11];
  const float* ppeg_w5  = (const float*)d_in[12];
  const float* ppeg_b5  = (const float*)d_in[13];
  const float* ppeg_w3  = (const float*)d_in[14];
  const float* ppeg_b3  = (const float*)d_in[15];
  const float* ln2_g    = (const float*)d_in[16];
  const float* ln2_b    = (const float*)d_in[17];
  const float* qkv2     = (const float*)d_in[18];
  const float* out2_w   = (const float*)d_in[19];
  const float* out2_b   = (const float*)d_in[20];
  const float* res2_w   = (const float*)d_in[21];
  const float* lnf_g    = (const float*)d_in[22];
  const float* lnf_b    = (const float*)d_in[23];
  const float* cls_w    = (const float*)d_in[24];
  const float* cls_b    = (const float*)d_in[25];

  float* ws = (float*)d_ws;
  size_t off = 0;
  float* hA  = ws + off; off += (size_t)BB * TT * DD;
  float* hB  = ws + off; off += (size_t)BB * TT * DD;
  float* xp  = ws + off; off += (size_t)BB * NPAD * DD;
  float* qkvf = ws + off; off += (size_t)BB * NPAD * 3 * DD;  // used as f16 (half)
  unsigned short* qkvh = (unsigned short*)qkvf;
  float* ql  = ws + off; off += (size_t)BB * HH * 256 * 64;
  float* kl  = ws + off; off += (size_t)BB * HH * 256 * 64;
  float* a2  = ws + off; off += (size_t)16 * 65536;
  float* z0  = ws + off; off += (size_t)16 * 65536;
  float* z1  = ws + off; off += (size_t)16 * 65536;
  float* xz  = ws + off; off += (size_t)16 * 65536;
  float* xz2 = ws + off; off += (size_t)16 * 65536;
  float* yB  = ws + off; off += (size_t)16 * 65536;
  float* yC  = ws + off; off += (size_t)16 * 65536;
  float* bv  = ws + off; off += (size_t)BB * HH * 256 * 64;
  float* w2  = ws + off; off += (size_t)BB * HH * 256 * 64;
  float* red = ws + off; off += 8448;
  unsigned short* wth = (unsigned short*)(ws + off); off += 393216;

  // Stage 1: h = gelu(x @ w_feat + b_feat), prepend cls token
  k_set_cls<<<2, 512, 0, stream>>>(hA, cls_tok);
  k_cvt_wt<<<dim3(1024 / 32, DD / 32), 256, 0, stream>>>(w_feat, wth, 1024, DD);
  k_gemm_mfma<0><<<dim3(32768 / 128, DD / 256), 512, 0, stream>>>(
      x, nullptr, nullptr, wth, b_feat, hA, 32768, 1024, DD, 1024);
  // Attention 1 (residual in-place on hA; hB is dead -> scratch)
  run_attn(hA, ln1_g, ln1_b, qkv1, out1_w, out1_b, res1_w, xp, qkvh, ql, kl, a2, z0, z1,
           xz, xz2, yB, yC, bv, w2, red, hB, wth, stream);
  // PPEG: hB = ppeg(hA)
  k_copy_cls<<<2, 512, 0, stream>>>(hB, hA);
  k_ppeg<<<dim3(512, 4, 2), 128, 0, stream>>>(hB, hA, ppeg_w7, ppeg_b7, ppeg_w5, ppeg_b5,
                                              ppeg_w3, ppeg_b3);
  // Attention 2 (residual in-place on hB; hA is dead -> scratch)
  run_attn(hB, ln2_g, ln2_b, qkv2, out2_w, out2_b, res2_w, xp, qkvh, ql, kl, a2, z0, z1,
           xz, xz2, yB, yC, bv, w2, red, hA, wth, stream);
  // Final: LN(cls) @ cls_w + cls_b
  k_final<<<1, 512, 0, stream>>>((float*)d_out, hB, lnf_g, lnf_b, cls_w, cls_b);
}

// Round 21
// 1539.941 us; speedup vs baseline: 1.1014x; 1.1014x over previous
//
#include <hip/hip_runtime.h>
#include <cstdint>
#include <cstddef>

#define BB 2
#define TT 16385
#define NPAD 16640
#define DD 512
#define HH 8
#define DHH 64
#define MLAND 256
#define PADF 255
#define A3KC 26
#define A3CH 640

typedef __attribute__((ext_vector_type(8))) _Float16 f16x8;
typedef __attribute__((ext_vector_type(4))) float f32x4;

__device__ __forceinline__ float gelu_f(float v) {
  float c = 0.7978845608028654f * (v + 0.044715f * v * v * v);
  return 0.5f * v * (1.0f + tanhf(c));
}

__device__ __forceinline__ unsigned short f16_1(float a) {
  _Float16 h = (_Float16)a;
  return __builtin_bit_cast(unsigned short, h);
}
__device__ __forceinline__ float f16f(unsigned u) {
  return (float)__builtin_bit_cast(_Float16, (unsigned short)(u & 0xffffu));
}
__device__ __forceinline__ unsigned pk_f16(float a, float b) {
  return (unsigned)f16_1(a) | ((unsigned)f16_1(b) << 16);
}
// split a,b into f16 hi (packed) and f16 residual-lo (packed)
__device__ __forceinline__ void split2h(float a, float b, unsigned& hi, unsigned& lo) {
  _Float16 ah = (_Float16)a, bh = (_Float16)b;
  hi = (unsigned)__builtin_bit_cast(unsigned short, ah) |
       ((unsigned)__builtin_bit_cast(unsigned short, bh) << 16);
  lo = pk_f16(a - (float)ah, b - (float)bh);
}
__device__ __forceinline__ void store4h(float4 v, unsigned short* dh,
                                        unsigned short* dl) {
  unsigned h0, l0, h1, l1;
  split2h(v.x, v.y, h0, l0);
  split2h(v.z, v.w, h1, l1);
  *(uint2*)dh = make_uint2(h0, h1);
  *(uint2*)dl = make_uint2(l0, l1);
}

// async global->LDS 16B (wave-uniform LDS base + lane*16)
__device__ __forceinline__ void gload16(const unsigned short* g, short* l) {
  __builtin_amdgcn_global_load_lds(
      (const __attribute__((address_space(1))) void*)g,
      (__attribute__((address_space(3))) void*)l, 16, 0, 0);
}

// ---------------------------------------------------------------- cls rows
__global__ void k_set_cls(float* __restrict__ h, const float* __restrict__ cls) {
  h[(size_t)blockIdx.x * TT * DD + threadIdx.x] = cls[threadIdx.x];
}
__global__ void k_copy_cls(float* __restrict__ dst, const float* __restrict__ src) {
  size_t o = (size_t)blockIdx.x * TT * DD + threadIdx.x;
  dst[o] = src[o];
}

// ------------------------------------------------ W[K][N] -> Wt f16 [N][K]
__global__ __launch_bounds__(256) void k_cvt_wt(
    const float* __restrict__ W, unsigned short* __restrict__ Wth, int K, int N) {
  __shared__ float tile[32][33];
  int kb = blockIdx.x * 32, nb = blockIdx.y * 32;
  int t = threadIdx.x;
  int tr = t >> 3, tc4 = (t & 7) * 4;
  float4 v = *(const float4*)(W + (size_t)(kb + tr) * N + nb + tc4);
  tile[tr][tc4 + 0] = v.x;
  tile[tr][tc4 + 1] = v.y;
  tile[tr][tc4 + 2] = v.z;
  tile[tr][tc4 + 3] = v.w;
  __syncthreads();
  int n = nb + tr;
  ushort4 hs;
  hs.x = f16_1(tile[tc4 + 0][tr]);
  hs.y = f16_1(tile[tc4 + 1][tr]);
  hs.z = f16_1(tile[tc4 + 2][tr]);
  hs.w = f16_1(tile[tc4 + 3][tr]);
  *(ushort4*)(Wth + (size_t)n * K + kb + tc4) = hs;
}

// ---------------- fp32-via-2xf16 MFMA GEMM, 128x256 tile, 8 waves (512 thr)
// (MODE 0 feat-gelu and MODE 2 proj-residual; qkv uses k_gemm_qkv8)
template <int MODE>
__global__ __launch_bounds__(512) void k_gemm_mfma(
    const float* __restrict__ A, const unsigned short* __restrict__ Aph,
    const unsigned short* __restrict__ Apl, const unsigned short* __restrict__ Wth,
    const float* __restrict__ bias, void* __restrict__ Cv, int M, int K, int N,
    int lda) {
  __shared__ short Ash[128][44];
  __shared__ short Asl[128][44];
  __shared__ short Bsh[256][44];
  const int t = threadIdx.x;
  // bijective swizzle over (gridDim.x row-tiles) x (gridDim.y col-tiles)
  int nRow = gridDim.x, nCol = gridDim.y;
  int lin = blockIdx.x + blockIdx.y * nRow;
  int chunk = 8 * nCol;
  int group = lin / chunk;
  int rem = lin - group * chunk;
  int gbase = group * 8;
  int Geff = nRow - gbase;
  if (Geff > 8) Geff = 8;
  const int rb = (gbase + rem % Geff) * 128;
  const int cb = (rem / Geff) * 256;
  const float* Ab = A;
  float* Cf = (float*)Cv;
  unsigned short* Ch = (unsigned short*)Cv;
  if (MODE == 2) {
    int b = blockIdx.z;
    Ab = A + (size_t)b * NPAD * DD + (size_t)PADF * DD;
    Cf = (float*)Cv + (size_t)b * TT * DD;
  }
  const int lane = t & 63, wv = t >> 6;
  const int wr = wv >> 2, wc = wv & 3;
  const int fr = lane & 15, kg = lane >> 4;
  const int srow = t >> 2, skh = (t & 3) * 8;   // A: 8 shorts / thread / plane
  const int brow = t >> 1, bkh = (t & 1) * 16;  // B: 16 shorts / thread

  f32x4 acc[4][4];
  f32x4 zero4 = {0.f, 0.f, 0.f, 0.f};
#pragma unroll
  for (int i = 0; i < 4; ++i)
#pragma unroll
    for (int j = 0; j < 4; ++j) acc[i][j] = zero4;

  for (int k0 = 0; k0 < K; k0 += 32) {
    __syncthreads();
    if (MODE == 1) {
      const unsigned short* ph = Aph + (size_t)(rb + srow) * lda + k0 + skh;
      const unsigned short* pl = Apl + (size_t)(rb + srow) * lda + k0 + skh;
      *(uint4*)&Ash[srow][skh] = *(const uint4*)ph;
      *(uint4*)&Asl[srow][skh] = *(const uint4*)pl;
    } else {
      int grow = rb + srow;
      float4 f0 = {0, 0, 0, 0}, f1 = {0, 0, 0, 0};
      if (grow < M) {
        const float* p = Ab + (size_t)grow * lda + k0 + skh;
        f0 = *(const float4*)p;
        f1 = *(const float4*)(p + 4);
      }
      unsigned h0, h1, h2, h3, l0, l1, l2, l3;
      split2h(f0.x, f0.y, h0, l0);
      split2h(f0.z, f0.w, h1, l1);
      split2h(f1.x, f1.y, h2, l2);
      split2h(f1.z, f1.w, h3, l3);
      *(uint4*)&Ash[srow][skh] = make_uint4(h0, h1, h2, h3);
      *(uint4*)&Asl[srow][skh] = make_uint4(l0, l1, l2, l3);
    }
    {
      const unsigned short* ph = Wth + (size_t)(cb + brow) * K + k0 + bkh;
      *(uint4*)&Bsh[brow][bkh] = *(const uint4*)ph;
      *(uint4*)&Bsh[brow][bkh + 8] = *(const uint4*)(ph + 8);
    }
    __syncthreads();
    f16x8 ah[4], al[4];
#pragma unroll
    for (int mf = 0; mf < 4; ++mf) {
      ah[mf] = *(const f16x8*)&Ash[wr * 64 + mf * 16 + fr][kg * 8];
      al[mf] = *(const f16x8*)&Asl[wr * 64 + mf * 16 + fr][kg * 8];
    }
#pragma unroll
    for (int nf = 0; nf < 4; ++nf) {
      f16x8 bhf = *(const f16x8*)&Bsh[wc * 64 + nf * 16 + fr][kg * 8];
#pragma unroll
      for (int mf = 0; mf < 4; ++mf) {
        acc[mf][nf] =
            __builtin_amdgcn_mfma_f32_16x16x32_f16(ah[mf], bhf, acc[mf][nf], 0, 0, 0);
        acc[mf][nf] =
            __builtin_amdgcn_mfma_f32_16x16x32_f16(al[mf], bhf, acc[mf][nf], 0, 0, 0);
      }
    }
  }
#pragma unroll
  for (int mf = 0; mf < 4; ++mf) {
#pragma unroll
    for (int r = 0; r < 4; ++r) {
      int row = rb + wr * 64 + mf * 16 + kg * 4 + r;
      if (MODE == 2 && row >= M) continue;
      size_t orow = (MODE == 0) ? (size_t)(row + (row >> 14) + 1) : (size_t)row;
#pragma unroll
      for (int nf = 0; nf < 4; ++nf) {
        int col = cb + wc * 64 + nf * 16 + fr;
        float v = acc[mf][nf][r];
        if (MODE == 0) {
          Cf[orow * DD + col] = gelu_f(v + bias[col]);
        } else if (MODE == 1) {
          Ch[orow * (size_t)N + col] = f16_1(v);
        } else {
          float old = Cf[orow * DD + col];
          Cf[orow * DD + col] = old + v + bias[col];
        }
      }
    }
  }
}

// ---------------- qkv GEMM (MODE-1 specialized): gload_lds + counted vmcnt
// BK=32, dbuf LDS 64KB -> 2 blocks/CU (cross-block MFMA||LDS overlap),
// 2-deep prefetch, vmcnt(4), XOR slot-swizzle (64B rows, slot^=row&3, 2-way free).
__global__ __launch_bounds__(512) void k_gemm_qkv8(
    const unsigned short* __restrict__ Aph, const unsigned short* __restrict__ Apl,
    const unsigned short* __restrict__ Wth, unsigned short* __restrict__ Ch) {
  __shared__ __align__(16) short Ah[2][128][32];
  __shared__ __align__(16) short Al[2][128][32];
  __shared__ __align__(16) short Bs[2][256][32];
  const int t = threadIdx.x;
  // L2 block swizzle (same as k_gemm_mfma)
  int nRow = gridDim.x, nCol = gridDim.y;
  int lin = blockIdx.x + blockIdx.y * nRow;
  int chunk = 8 * nCol;
  int group = lin / chunk;
  int rem = lin - group * chunk;
  int gbase = group * 8;
  int Geff = nRow - gbase;
  if (Geff > 8) Geff = 8;
  const int rb = (gbase + rem % Geff) * 128;
  const int cb = (rem / Geff) * 256;
  const int lane = t & 63, wv = t >> 6;
  const int wr = wv >> 2, wc = wv & 3;
  const int fr = lane & 15, kg = lane >> 4;
  const int lr4 = lane >> 2;                       // row-in-16 within a gload
  const int ss = (lane & 3) ^ (lr4 & 3);           // pre-swizzled src slot (16B)

  f32x4 acc[4][4];
  f32x4 zero4 = {0.f, 0.f, 0.f, 0.f};
#pragma unroll
  for (int i = 0; i < 4; ++i)
#pragma unroll
    for (int j = 0; j < 4; ++j) acc[i][j] = zero4;

  // stage K-step kt (K=32) into buffer bf: 4 gloads/wave (A hi 1, A lo 1, B 2)
  auto STAGE = [&](int kt, int bf) {
    const int k0 = kt * 32;
    {
      int lr = wv * 16;
      gload16(Aph + (size_t)(rb + lr + lr4) * DD + k0 + ss * 8, &Ah[bf][lr][0]);
      gload16(Apl + (size_t)(rb + lr + lr4) * DD + k0 + ss * 8, &Al[bf][lr][0]);
    }
#pragma unroll
    for (int j = 0; j < 2; ++j) {
      int lr = wv * 32 + j * 16;
      gload16(Wth + (size_t)(cb + lr + lr4) * DD + k0 + ss * 8, &Bs[bf][lr][0]);
    }
  };

  STAGE(0, 0);
  STAGE(1, 1);
  const int sl = ((kg ^ (fr & 3))) * 8;  // swizzled read slot (shorts)
  for (int kt = 0; kt < 16; ++kt) {
    if (kt < 15) {
      asm volatile("s_waitcnt vmcnt(4)" ::: "memory");  // own tile-kt loads done
    } else {
      asm volatile("s_waitcnt vmcnt(0)" ::: "memory");  // final drain
    }
    __builtin_amdgcn_sched_barrier(0);
    __builtin_amdgcn_s_barrier();  // all waves' tile-kt data in LDS
    const int bf = kt & 1;
    f16x8 ah[4], al[4];
#pragma unroll
    for (int mf = 0; mf < 4; ++mf) {
      ah[mf] = *(const f16x8*)&Ah[bf][wr * 64 + mf * 16 + fr][sl];
      al[mf] = *(const f16x8*)&Al[bf][wr * 64 + mf * 16 + fr][sl];
    }
#pragma unroll
    for (int nf = 0; nf < 4; ++nf) {
      f16x8 bhf = *(const f16x8*)&Bs[bf][wc * 64 + nf * 16 + fr][sl];
#pragma unroll
      for (int mf = 0; mf < 4; ++mf) {
        acc[mf][nf] =
            __builtin_amdgcn_mfma_f32_16x16x32_f16(ah[mf], bhf, acc[mf][nf], 0, 0, 0);
        acc[mf][nf] =
            __builtin_amdgcn_mfma_f32_16x16x32_f16(al[mf], bhf, acc[mf][nf], 0, 0, 0);
      }
    }
    __builtin_amdgcn_s_barrier();  // all waves done reading buf bf
    if (kt + 2 < 16) STAGE(kt + 2, bf);
  }
#pragma unroll
  for (int mf = 0; mf < 4; ++mf) {
#pragma unroll
    for (int r = 0; r < 4; ++r) {
      int row = rb + wr * 64 + mf * 16 + kg * 4 + r;
#pragma unroll
      for (int nf = 0; nf < 4; ++nf) {
        int col = cb + wc * 64 + nf * 16 + fr;
        Ch[(size_t)row * 1536 + col] = f16_1(acc[mf][nf][r]);
      }
    }
  }
}

// ------------------------- LN + pad -> writes f16 hi/lo planes (qkv A operand)
__global__ __launch_bounds__(256) void k_ln_pad(
    unsigned short* __restrict__ xph, unsigned short* __restrict__ xpl,
    const float* __restrict__ h, const float* __restrict__ gam,
    const float* __restrict__ bet) {
  int w = threadIdx.x >> 6, lane = threadIdx.x & 63;
  int row = blockIdx.x * 4 + w;
  if (row >= BB * TT) return;
  int b = row / TT, i = row - b * TT;
  const float* src = h + (size_t)row * DD;
  float4 x0 = *(const float4*)(src + lane * 4);
  float4 x1 = *(const float4*)(src + 256 + lane * 4);
  float s = x0.x + x0.y + x0.z + x0.w + x1.x + x1.y + x1.z + x1.w;
  for (int o = 32; o; o >>= 1) s += __shfl_xor(s, o);
  float mu = s * (1.f / 512.f);
  float q = (x0.x - mu) * (x0.x - mu) + (x0.y - mu) * (x0.y - mu) +
            (x0.z - mu) * (x0.z - mu) + (x0.w - mu) * (x0.w - mu) +
            (x1.x - mu) * (x1.x - mu) + (x1.y - mu) * (x1.y - mu) +
            (x1.z - mu) * (x1.z - mu) + (x1.w - mu) * (x1.w - mu);
  for (int o = 32; o; o >>= 1) q += __shfl_xor(q, o);
  float rs = rsqrtf(q * (1.f / 512.f) + 1e-5f);
  float4 g0 = *(const float4*)(gam + lane * 4);
  float4 g1 = *(const float4*)(gam + 256 + lane * 4);
  float4 b0 = *(const float4*)(bet + lane * 4);
  float4 b1 = *(const float4*)(bet + 256 + lane * 4);
  float4 o0, o1;
  o0.x = (x0.x - mu) * rs * g0.x + b0.x;
  o0.y = (x0.y - mu) * rs * g0.y + b0.y;
  o0.z = (x0.z - mu) * rs * g0.z + b0.z;
  o0.w = (x0.w - mu) * rs * g0.w + b0.w;
  o1.x = (x1.x - mu) * rs * g1.x + b1.x;
  o1.y = (x1.y - mu) * rs * g1.y + b1.y;
  o1.z = (x1.z - mu) * rs * g1.z + b1.z;
  o1.w = (x1.w - mu) * rs * g1.w + b1.w;
  size_t ro = ((size_t)b * NPAD + PADF + i) * DD;
  store4h(o0, xph + ro + lane * 4, xpl + ro + lane * 4);
  store4h(o1, xph + ro + 256 + lane * 4, xpl + ro + 256 + lane * 4);
}

__global__ void k_zero_pad(unsigned short* __restrict__ xph,
                           unsigned short* __restrict__ xpl) {
  int r = blockIdx.x;
  int b = r / PADF, j = r - b * PADF;
  size_t ro = ((size_t)b * NPAD + j) * DD;
  ((unsigned*)(xph + ro))[threadIdx.x] = 0u;
  ((unsigned*)(xpl + ro))[threadIdx.x] = 0u;
}

// ---------------------------------------------------------------- landmarks (f16 qkv)
__global__ __launch_bounds__(256) void k_landmarks(
    float* __restrict__ ql, float* __restrict__ kl,
    const unsigned short* __restrict__ qkv) {
  int t = threadIdx.x;
  int mi = t >> 6, d = t & 63;
  int blk = blockIdx.x;
  int bh = blk >> 6, mg = blk & 63;
  int b = bh >> 3, h = bh & 7;
  int m = mg * 4 + mi;
  const unsigned short* base = qkv + (size_t)b * NPAD * 1536 + h * 64 + d;
  float sq = 0.f, sk = 0.f;
  int t0 = m * 65;
  for (int j = 0; j < 65; ++j) {
    const unsigned short* p = base + (size_t)(t0 + j) * 1536;
    sq += f16f(p[0]);
    sk += f16f(p[512]);
  }
  ql[((size_t)bh * 256 + m) * 64 + d] = sq * (0.125f / 65.f);
  kl[((size_t)bh * 256 + m) * 64 + d] = sk * (1.f / 65.f);
}

// ---------------------------------------------------------------- sim2 = ql @ kl^T
__global__ __launch_bounds__(256) void k_sim2(
    float* __restrict__ sim, const float* __restrict__ ql, const float* __restrict__ kl) {
  __shared__ __align__(16) float Aq[64][68];
  __shared__ __align__(16) float Bk[64][68];
  int t = threadIdx.x;
  int tj = blockIdx.x, ti = blockIdx.y, bh = blockIdx.z;
  int r = t >> 2, cc = (t & 3) * 16;
  const float* ap = ql + ((size_t)bh * 256 + ti * 64 + r) * 64 + cc;
  const float* bp = kl + ((size_t)bh * 256 + tj * 64 + r) * 64 + cc;
#pragma unroll
  for (int i = 0; i < 16; i += 4) {
    *(float4*)&Aq[r][cc + i] = *(const float4*)(ap + i);
    *(float4*)&Bk[r][cc + i] = *(const float4*)(bp + i);
  }
  __syncthreads();
  int tx = t & 15, ty = t >> 4;
  float acc[4][4];
#pragma unroll
  for (int i = 0; i < 4; ++i)
#pragma unroll
    for (int j = 0; j < 4; ++j) acc[i][j] = 0.f;
  for (int d = 0; d < 64; d += 4) {
    float4 a4[4], b4[4];
#pragma unroll
    for (int ii = 0; ii < 4; ++ii) a4[ii] = *(float4*)&Aq[ty * 4 + ii][d];
#pragma unroll
    for (int jj = 0; jj < 4; ++jj) b4[jj] = *(float4*)&Bk[tx * 4 + jj][d];
#pragma unroll
    for (int ii = 0; ii < 4; ++ii)
#pragma unroll
      for (int jj = 0; jj < 4; ++jj)
        acc[ii][jj] += a4[ii].x * b4[jj].x + a4[ii].y * b4[jj].y + a4[ii].z * b4[jj].z +
                       a4[ii].w * b4[jj].w;
  }
#pragma unroll
  for (int ii = 0; ii < 4; ++ii)
#pragma unroll
    for (int jj = 0; jj < 4; ++jj)
      sim[((size_t)bh * 256 + ti * 64 + ty * 4 + ii) * 256 + tj * 64 + tx * 4 + jj] =
          acc[ii][jj];
}

// ---------------------------------------------------------------- row softmax (len 256)
__global__ __launch_bounds__(256) void k_softmax256(float* __restrict__ a) {
  int w = threadIdx.x >> 6, lane = threadIdx.x & 63;
  size_t row = (size_t)blockIdx.x * 4 + w;
  float* p = a + row * 256 + lane * 4;
  float4 v = *(float4*)p;
  float m = fmaxf(fmaxf(v.x, v.y), fmaxf(v.z, v.w));
  for (int o = 32; o; o >>= 1) m = fmaxf(m, __shfl_xor(m, o));
  v.x = expf(v.x - m); v.y = expf(v.y - m);
  v.z = expf(v.z - m); v.w = expf(v.w - m);
  float s = v.x + v.y + v.z + v.w;
  for (int o = 32; o; o >>= 1) s += __shfl_xor(s, o);
  float inv = 1.f / s;
  v.x *= inv; v.y *= inv; v.z *= inv; v.w *= inv;
  *(float4*)p = v;
}

// ---------------------------------------------------------------- pinv helpers
__global__ void k_pinv_sums(float* __restrict__ red, const float* __restrict__ a2) {
  int bh = blockIdx.x, t = threadIdx.x;
  const float* Ab = a2 + (size_t)bh * 65536;
  float s = 0.f;
  for (int i = 0; i < 256; ++i) s += fabsf(Ab[(size_t)i * 256 + t]);
  red[bh * 256 + t] = s;
  float c = 0.f;
  const float* rp = Ab + (size_t)t * 256;
  for (int j = 0; j < 256; j += 4) {
    float4 v = *(const float4*)(rp + j);
    c += fabsf(v.x) + fabsf(v.y) + fabsf(v.z) + fabsf(v.w);
  }
  red[4096 + bh * 256 + t] = c;
}

__global__ void k_pinv_scale(float* __restrict__ red) {
  __shared__ float sm[8];
  int t = threadIdx.x;
  float m1 = 0.f, m2 = 0.f;
  for (int k = t; k < 4096; k += 256) {
    m1 = fmaxf(m1, red[k]);
    m2 = fmaxf(m2, red[4096 + k]);
  }
  for (int o = 32; o; o >>= 1) {
    m1 = fmaxf(m1, __shfl_xor(m1, o));
    m2 = fmaxf(m2, __shfl_xor(m2, o));
  }
  int w = t >> 6;
  if ((t & 63) == 0) { sm[w] = m1; sm[4 + w] = m2; }
  __syncthreads();
  if (t == 0) {
    float a = fmaxf(fmaxf(sm[0], sm[1]), fmaxf(sm[2], sm[3]));
    float b = fmaxf(fmaxf(sm[4], sm[5]), fmaxf(sm[6], sm[7]));
    red[8192] = 1.0f / (a * b);
  }
}

__global__ void k_zinit(float* __restrict__ z, const float* __restrict__ a2,
                        const float* __restrict__ red) {
  float s = red[8192];
  int i = blockIdx.x, bh = blockIdx.y, j = threadIdx.x;
  z[((size_t)bh * 256 + i) * 256 + j] = a2[((size_t)bh * 256 + j) * 256 + i] * s;
}

// ---- shared BK=128 f16 3-term matmul core: acc += A[i0..i0+64) @ B (256xN)
__device__ __forceinline__ void bmm_core(
    short (*Ash)[136], short (*Asl)[136], short (*Bsh)[136], short (*Bsl)[136],
    const float* __restrict__ Ab, const float* __restrict__ Bb, int i0, int j0, int N,
    int t, f32x4 (&acc)[4]) {
  const int lane = t & 63, w = t >> 6;
  const int fr = lane & 15, kg = lane >> 4;
  const int ar = t >> 2, akseg = (t & 3) * 32;  // A: 32 floats / thread
  for (int k0 = 0; k0 < 256; k0 += 128) {
    __syncthreads();
    {  // stage A rows (f16 split): 64 rows x 128 k
      const float* p = Ab + (size_t)(i0 + ar) * 256 + k0 + akseg;
#pragma unroll
      for (int q = 0; q < 4; ++q) {
        float4 f0 = *(const float4*)(p + q * 8);
        float4 f1 = *(const float4*)(p + q * 8 + 4);
        unsigned h0, h1, h2, h3, l0, l1, l2, l3;
        split2h(f0.x, f0.y, h0, l0);
        split2h(f0.z, f0.w, h1, l1);
        split2h(f1.x, f1.y, h2, l2);
        split2h(f1.z, f1.w, h3, l3);
        *(uint4*)&Ash[ar][akseg + q * 8] = make_uint4(h0, h1, h2, h3);
        *(uint4*)&Asl[ar][akseg + q * 8] = make_uint4(l0, l1, l2, l3);
      }
    }
    {  // stage B transposed (f16 split): Bsh[j_local][k_local], 128 k-rows x 64 j
#pragma unroll
      for (int pass = 0; pass < 8; ++pass) {
        int kr = pass * 16 + (t >> 4);
        int jseg = (t & 15) * 4;
        const float* p = Bb + (size_t)(k0 + kr) * N + j0 + jseg;
        float4 f = *(const float4*)p;
        float fv[4] = {f.x, f.y, f.z, f.w};
#pragma unroll
        for (int c = 0; c < 4; ++c) {
          _Float16 hh = (_Float16)fv[c];
          float lo = fv[c] - (float)hh;
          Bsh[jseg + c][kr] = (short)__builtin_bit_cast(unsigned short, hh);
          Bsl[jseg + c][kr] = (short)f16_1(lo);
        }
      }
    }
    __syncthreads();
#pragma unroll
    for (int kw = 0; kw < 4; ++kw) {
      f16x8 bhf = *(const f16x8*)&Bsh[w * 16 + fr][kw * 32 + kg * 8];
      f16x8 blf = *(const f16x8*)&Bsl[w * 16 + fr][kw * 32 + kg * 8];
#pragma unroll
      for (int mf = 0; mf < 4; ++mf) {
        f16x8 ah = *(const f16x8*)&Ash[mf * 16 + fr][kw * 32 + kg * 8];
        f16x8 al = *(const f16x8*)&Asl[mf * 16 + fr][kw * 32 + kg * 8];
        acc[mf] = __builtin_amdgcn_mfma_f32_16x16x32_f16(ah, bhf, acc[mf], 0, 0, 0);
        acc[mf] = __builtin_amdgcn_mfma_f32_16x16x32_f16(al, bhf, acc[mf], 0, 0, 0);
        acc[mf] = __builtin_amdgcn_mfma_f32_16x16x32_f16(ah, blf, acc[mf], 0, 0, 0);
      }
    }
  }
}

// ------- batched 256x256 @ 256xN; C = a1*(A@B) + d1*I + e1*E (E optional)
__global__ __launch_bounds__(256) void k_bmm_poly(
    const float* __restrict__ A, const float* __restrict__ Bm,
    const float* __restrict__ E, float* __restrict__ C, float a1, float d1, float e1,
    int N) {
  __shared__ short Ash[64][136];
  __shared__ short Asl[64][136];
  __shared__ short Bsh[64][136];
  __shared__ short Bsl[64][136];
  const int t = threadIdx.x;
  const int bh = blockIdx.z;
  const int i0 = blockIdx.y * 64, j0 = blockIdx.x * 64;
  const int lane = t & 63, w = t >> 6;
  const int fr = lane & 15, kg = lane >> 4;
  f32x4 acc[4];
  f32x4 zero4 = {0.f, 0.f, 0.f, 0.f};
#pragma unroll
  for (int i = 0; i < 4; ++i) acc[i] = zero4;
  bmm_core(Ash, Asl, Bsh, Bsl, A + (size_t)bh * 65536, Bm + (size_t)bh * 256 * N, i0,
           j0, N, t, acc);
  int j = j0 + w * 16 + fr;
#pragma unroll
  for (int mf = 0; mf < 4; ++mf) {
#pragma unroll
    for (int rr = 0; rr < 4; ++rr) {
      int i = i0 + mf * 16 + kg * 4 + rr;
      float v = acc[mf][rr];
      size_t off = (size_t)bh * 256 * N + (size_t)i * N + j;
      float out = a1 * v + ((i == j) ? d1 : 0.f);
      if (E) out += e1 * E[off];
      C[off] = out;
    }
  }
}

// ------- dual batched: z<16: C0 = s*(A0@B); z>=16: C1 = s*(A1@B)   (N=256)
__global__ __launch_bounds__(256) void k_bmm_dual(
    const float* __restrict__ A0, const float* __restrict__ A1,
    const float* __restrict__ Bm, float* __restrict__ C0, float* __restrict__ C1,
    float s) {
  __shared__ short Ash[64][136];
  __shared__ short Asl[64][136];
  __shared__ short Bsh[64][136];
  __shared__ short Bsl[64][136];
  const int t = threadIdx.x;
  const int z = blockIdx.z;
  const int bh = z & 15;
  const int sel = z >> 4;
  const float* A = sel ? A1 : A0;
  float* C = sel ? C1 : C0;
  const int i0 = blockIdx.y * 64, j0 = blockIdx.x * 64;
  const int lane = t & 63, w = t >> 6;
  const int fr = lane & 15, kg = lane >> 4;
  f32x4 acc[4];
  f32x4 zero4 = {0.f, 0.f, 0.f, 0.f};
#pragma unroll
  for (int i = 0; i < 4; ++i) acc[i] = zero4;
  bmm_core(Ash, Asl, Bsh, Bsl, A + (size_t)bh * 65536, Bm + (size_t)bh * 65536, i0, j0,
           256, t, acc);
  int j = j0 + w * 16 + fr;
#pragma unroll
  for (int mf = 0; mf < 4; ++mf) {
#pragma unroll
    for (int rr = 0; rr < 4; ++rr) {
      int i = i0 + mf * 16 + kg * 4 + rr;
      size_t off = (size_t)bh * 65536 + (size_t)i * 256 + j;
      C[off] = s * acc[mf][rr];
    }
  }
}

// -------------------------- a3 @ v : MFMA flash (f16 qkv, no-max, split-K chunks)
__global__ __launch_bounds__(256, 2) void k_a3v_mfma(
    float* __restrict__ pacc, float* __restrict__ pL,
    const float* __restrict__ ql, const unsigned short* __restrict__ qkv) {
  __shared__ short Ks[64][72];
  __shared__ short Vt[64][72];
  __shared__ short Ps[4][64][72];
  const int t = threadIdx.x;
  const int bh = blockIdx.x;
  const int kc = blockIdx.y;
  const int b = bh >> 3, h = bh & 7;
  const int lane = t & 63, w = t >> 6;
  const int fr = lane & 15, kg = lane >> 4;

  f16x8 qf[4][2];
#pragma unroll
  for (int nf = 0; nf < 4; ++nf) {
    const float* qp = ql + ((size_t)bh * 256 + w * 64 + nf * 16 + fr) * 64 + kg * 8;
#pragma unroll
    for (int kw = 0; kw < 2; ++kw) {
      float4 a = *(const float4*)(qp + kw * 32);
      float4 c = *(const float4*)(qp + kw * 32 + 4);
      uint4 uu = make_uint4(pk_f16(a.x, a.y), pk_f16(a.z, a.w), pk_f16(c.x, c.y),
                            pk_f16(c.z, c.w));
      qf[nf][kw] = *(f16x8*)&uu;
    }
  }
  f32x4 oacc[4][4];
  f32x4 zero4 = {0.f, 0.f, 0.f, 0.f};
#pragma unroll
  for (int i = 0; i < 4; ++i)
#pragma unroll
    for (int j = 0; j < 4; ++j) oacc[i][j] = zero4;
  float Lp[4] = {0.f, 0.f, 0.f, 0.f};

  const int skey = t >> 2, sd = (t & 3) * 16;
  const unsigned short* kbase = qkv + (size_t)b * NPAD * 1536 + 512 + h * 64 + sd;

  for (int it = 0; it < A3CH / 64; ++it) {
    int nt = kc * A3CH + it * 64;
    __syncthreads();
    {
      const unsigned short* kp = kbase + (size_t)(nt + skey) * 1536;
      *(uint4*)&Ks[skey][sd] = *(const uint4*)kp;
      *(uint4*)&Ks[skey][sd + 8] = *(const uint4*)(kp + 8);
      const unsigned short* vp = kp + 512;
      uint4 v01 = *(const uint4*)vp;
      uint4 v23 = *(const uint4*)(vp + 8);
      Vt[sd + 0][skey] = (short)v01.x;
      Vt[sd + 1][skey] = (short)(v01.x >> 16);
      Vt[sd + 2][skey] = (short)v01.y;
      Vt[sd + 3][skey] = (short)(v01.y >> 16);
      Vt[sd + 4][skey] = (short)v01.z;
      Vt[sd + 5][skey] = (short)(v01.z >> 16);
      Vt[sd + 6][skey] = (short)v01.w;
      Vt[sd + 7][skey] = (short)(v01.w >> 16);
      Vt[sd + 8][skey] = (short)v23.x;
      Vt[sd + 9][skey] = (short)(v23.x >> 16);
      Vt[sd + 10][skey] = (short)v23.y;
      Vt[sd + 11][skey] = (short)(v23.y >> 16);
      Vt[sd + 12][skey] = (short)v23.z;
      Vt[sd + 13][skey] = (short)(v23.z >> 16);
      Vt[sd + 14][skey] = (short)v23.w;
      Vt[sd + 15][skey] = (short)(v23.w >> 16);
    }
    __syncthreads();
    f32x4 sacc[4][4];
#pragma unroll
    for (int i = 0; i < 4; ++i)
#pragma unroll
      for (int j = 0; j < 4; ++j) sacc[i][j] = zero4;
#pragma unroll
    for (int kw = 0; kw < 2; ++kw) {
      f16x8 kf[4];
#pragma unroll
      for (int mf = 0; mf < 4; ++mf)
        kf[mf] = *(const f16x8*)&Ks[mf * 16 + fr][kw * 32 + kg * 8];
#pragma unroll
      for (int mf = 0; mf < 4; ++mf)
#pragma unroll
        for (int nf = 0; nf < 4; ++nf)
          sacc[mf][nf] = __builtin_amdgcn_mfma_f32_16x16x32_f16(kf[mf], qf[nf][kw],
                                                                sacc[mf][nf], 0, 0, 0);
    }
#pragma unroll
    for (int mf = 0; mf < 4; ++mf)
#pragma unroll
      for (int nf = 0; nf < 4; ++nf) {
        f32x4 s = sacc[mf][nf];
        float p0 = __expf(s[0]);
        float p1 = __expf(s[1]);
        float p2 = __expf(s[2]);
        float p3 = __expf(s[3]);
        Lp[nf] += (p0 + p1) + (p2 + p3);
        uint2 pw = make_uint2(pk_f16(p0, p1), pk_f16(p2, p3));
        *(uint2*)&Ps[w][nf * 16 + fr][mf * 16 + kg * 4] = pw;
      }
    __syncthreads();
#pragma unroll
    for (int kw = 0; kw < 2; ++kw) {
      f16x8 vf[4], pf[4];
#pragma unroll
      for (int mf = 0; mf < 4; ++mf)
        vf[mf] = *(const f16x8*)&Vt[mf * 16 + fr][kw * 32 + kg * 8];
#pragma unroll
      for (int nf = 0; nf < 4; ++nf)
        pf[nf] = *(const f16x8*)&Ps[w][nf * 16 + fr][kw * 32 + kg * 8];
#pragma unroll
      for (int mf = 0; mf < 4; ++mf)
#pragma unroll
        for (int nf = 0; nf < 4; ++nf)
          oacc[mf][nf] = __builtin_amdgcn_mfma_f32_16x16x32_f16(vf[mf], pf[nf],
                                                                oacc[mf][nf], 0, 0, 0);
    }
  }
  size_t obase = ((size_t)kc * 16 + bh) * 256;
#pragma unroll
  for (int mf = 0; mf < 4; ++mf)
#pragma unroll
    for (int nf = 0; nf < 4; ++nf) {
      int lm = w * 64 + nf * 16 + fr;
      *(f32x4*)(pacc + (obase + lm) * 64 + mf * 16 + kg * 4) = oacc[mf][nf];
    }
#pragma unroll
  for (int nf = 0; nf < 4; ++nf) {
    Lp[nf] += __shfl_xor(Lp[nf], 16);
    Lp[nf] += __shfl_xor(Lp[nf], 32);
  }
  if (lane < 16) {
#pragma unroll
    for (int nf = 0; nf < 4; ++nf)
      pL[obase + w * 64 + nf * 16 + lane] = Lp[nf];
  }
}

__global__ __launch_bounds__(64) void k_a3v_red(
    float* __restrict__ bv, const float* __restrict__ pacc,
    const float* __restrict__ pL) {
  int row = blockIdx.x;
  int d = threadIdx.x;
  float A = 0.f, L = 0.f;
#pragma unroll
  for (int c = 0; c < A3KC; ++c) {
    size_t pr = (size_t)c * 4096 + row;
    A += pacc[pr * 64 + d];
    L += pL[pr];
  }
  bv[(size_t)row * 64 + d] = A / L;
}

// ------------- fused sim1: attout = softmax(q @ (0.125*kl)^T) @ w2 (f16, no-max)
__global__ __launch_bounds__(256, 2) void k_att1(
    float* __restrict__ attout, const unsigned short* __restrict__ qkv,
    const float* __restrict__ kl, const float* __restrict__ w2) {
  __shared__ short KLs[64][72];
  __shared__ short W2t[64][72];
  __shared__ short Ps[4][64][72];
  const int t = threadIdx.x;
  const int tile = blockIdx.x, bh = blockIdx.y;
  const int b = bh >> 3, h = bh & 7;
  const int lane = t & 63, w = t >> 6;
  const int fr = lane & 15, kg = lane >> 4;
  const int n0 = tile * 256;

  f16x8 qf[4][2];
#pragma unroll
  for (int nf = 0; nf < 4; ++nf) {
    const unsigned short* qp =
        qkv + ((size_t)b * NPAD + n0 + w * 64 + nf * 16 + fr) * 1536 + h * 64 + kg * 8;
    qf[nf][0] = *(const f16x8*)qp;
    qf[nf][1] = *(const f16x8*)(qp + 32);
  }
  f32x4 oacc[4][4];
  f32x4 zero4 = {0.f, 0.f, 0.f, 0.f};
#pragma unroll
  for (int i = 0; i < 4; ++i)
#pragma unroll
    for (int j = 0; j < 4; ++j) oacc[i][j] = zero4;
  float Lp[4] = {0.f, 0.f, 0.f, 0.f};

  const int sr = t >> 2, sc = (t & 3) * 16;
  for (int cb = 0; cb < 4; ++cb) {
    __syncthreads();
    {
      const float* kp = kl + ((size_t)bh * 256 + cb * 64 + sr) * 64 + sc;
      float4 k0 = *(const float4*)kp;
      float4 k1 = *(const float4*)(kp + 4);
      float4 k2 = *(const float4*)(kp + 8);
      float4 k3 = *(const float4*)(kp + 12);
      *(uint4*)&KLs[sr][sc] =
          make_uint4(pk_f16(k0.x * 0.125f, k0.y * 0.125f),
                     pk_f16(k0.z * 0.125f, k0.w * 0.125f),
                     pk_f16(k1.x * 0.125f, k1.y * 0.125f),
                     pk_f16(k1.z * 0.125f, k1.w * 0.125f));
      *(uint4*)&KLs[sr][sc + 8] =
          make_uint4(pk_f16(k2.x * 0.125f, k2.y * 0.125f),
                     pk_f16(k2.z * 0.125f, k2.w * 0.125f),
                     pk_f16(k3.x * 0.125f, k3.y * 0.125f),
                     pk_f16(k3.z * 0.125f, k3.w * 0.125f));
      const float* wp = w2 + ((size_t)bh * 256 + cb * 64 + sr) * 64 + sc;
      float4 v0 = *(const float4*)wp;
      float4 v1 = *(const float4*)(wp + 4);
      float4 v2 = *(const float4*)(wp + 8);
      float4 v3 = *(const float4*)(wp + 12);
      W2t[sc + 0][sr] = (short)f16_1(v0.x);
      W2t[sc + 1][sr] = (short)f16_1(v0.y);
      W2t[sc + 2][sr] = (short)f16_1(v0.z);
      W2t[sc + 3][sr] = (short)f16_1(v0.w);
      W2t[sc + 4][sr] = (short)f16_1(v1.x);
      W2t[sc + 5][sr] = (short)f16_1(v1.y);
      W2t[sc + 6][sr] = (short)f16_1(v1.z);
      W2t[sc + 7][sr] = (short)f16_1(v1.w);
      W2t[sc + 8][sr] = (short)f16_1(v2.x);
      W2t[sc + 9][sr] = (short)f16_1(v2.y);
      W2t[sc + 10][sr] = (short)f16_1(v2.z);
      W2t[sc + 11][sr] = (short)f16_1(v2.w);
      W2t[sc + 12][sr] = (short)f16_1(v3.x);
      W2t[sc + 13][sr] = (short)f16_1(v3.y);
      W2t[sc + 14][sr] = (short)f16_1(v3.z);
      W2t[sc + 15][sr] = (short)f16_1(v3.w);
    }
    __syncthreads();
    f32x4 sacc[4][4];
#pragma unroll
    for (int i = 0; i < 4; ++i)
#pragma unroll
      for (int j = 0; j < 4; ++j) sacc[i][j] = zero4;
#pragma unroll
    for (int kw = 0; kw < 2; ++kw) {
      f16x8 kf[4];
#pragma unroll
      for (int mf = 0; mf < 4; ++mf)
        kf[mf] = *(const f16x8*)&KLs[mf * 16 + fr][kw * 32 + kg * 8];
#pragma unroll
      for (int mf = 0; mf < 4; ++mf)
#pragma unroll
        for (int nf = 0; nf < 4; ++nf)
          sacc[mf][nf] = __builtin_amdgcn_mfma_f32_16x16x32_f16(kf[mf], qf[nf][kw],
                                                                sacc[mf][nf], 0, 0, 0);
    }
#pragma unroll
    for (int mf = 0; mf < 4; ++mf)
#pragma unroll
      for (int nf = 0; nf < 4; ++nf) {
        f32x4 s = sacc[mf][nf];
        float p0 = __expf(s[0]);
        float p1 = __expf(s[1]);
        float p2 = __expf(s[2]);
        float p3 = __expf(s[3]);
        Lp[nf] += (p0 + p1) + (p2 + p3);
        uint2 pw = make_uint2(pk_f16(p0, p1), pk_f16(p2, p3));
        *(uint2*)&Ps[w][nf * 16 + fr][mf * 16 + kg * 4] = pw;
      }
    __syncthreads();
#pragma unroll
    for (int kw = 0; kw < 2; ++kw) {
      f16x8 vf[4], pf[4];
#pragma unroll
      for (int mf = 0; mf < 4; ++mf)
        vf[mf] = *(const f16x8*)&W2t[mf * 16 + fr][kw * 32 + kg * 8];
#pragma unroll
      for (int nf = 0; nf < 4; ++nf)
        pf[nf] = *(const f16x8*)&Ps[w][nf * 16 + fr][kw * 32 + kg * 8];
#pragma unroll
      for (int mf = 0; mf < 4; ++mf)
#pragma unroll
        for (int nf = 0; nf < 4; ++nf)
          oacc[mf][nf] = __builtin_amdgcn_mfma_f32_16x16x32_f16(vf[mf], pf[nf],
                                                                oacc[mf][nf], 0, 0, 0);
    }
  }
#pragma unroll
  for (int nf = 0; nf < 4; ++nf) {
    Lp[nf] += __shfl_xor(Lp[nf], 16);
    Lp[nf] += __shfl_xor(Lp[nf], 32);
  }
#pragma unroll
  for (int nf = 0; nf < 4; ++nf) {
    float inv = 1.0f / Lp[nf];
    int tok = n0 + w * 64 + nf * 16 + fr;
#pragma unroll
    for (int mf = 0; mf < 4; ++mf) {
      f32x4 o = oacc[mf][nf];
      o[0] *= inv; o[1] *= inv; o[2] *= inv; o[3] *= inv;
      *(f32x4*)(attout + ((size_t)b * NPAD + tok) * DD + h * 64 + mf * 16 + kg * 4) = o;
    }
  }
}

// ---------------- attout += depthwise33(v); sliding-window (40 LDS loads/thread,
// was 264); accumulation order per output identical (k ascending) -> bitwise-same
__global__ __launch_bounds__(256) void k_convres(
    float* __restrict__ attout, const unsigned short* __restrict__ qkv,
    const float* __restrict__ resw) {
  __shared__ float vS[96][68];
  __shared__ float w33[33];
  int t = threadIdx.x;
  int tb = blockIdx.x, bh = blockIdx.y;
  int b = bh >> 3, h = bh & 7;
  int n0 = tb * 64;
  if (t < 33) w33[t] = resw[h * 33 + t];
  int sc = (t & 3) * 16;
#pragma unroll
  for (int pass = 0; pass < 2; ++pass) {
    int r = (t >> 2) + pass * 64;
    if (r < 96) {
      int seq = n0 - 16 + r;
      if (seq >= 0 && seq < NPAD) {
        const unsigned short* p =
            qkv + ((size_t)b * NPAD + seq) * 1536 + 1024 + h * 64 + sc;
        uint4 u0 = *(const uint4*)p;
        uint4 u1 = *(const uint4*)(p + 8);
        float4 f0 = make_float4(f16f(u0.x), f16f(u0.x >> 16), f16f(u0.y),
                                f16f(u0.y >> 16));
        float4 f1 = make_float4(f16f(u0.z), f16f(u0.z >> 16), f16f(u0.w),
                                f16f(u0.w >> 16));
        float4 f2 = make_float4(f16f(u1.x), f16f(u1.x >> 16), f16f(u1.y),
                                f16f(u1.y >> 16));
        float4 f3 = make_float4(f16f(u1.z), f16f(u1.z >> 16), f16f(u1.w),
                                f16f(u1.w >> 16));
        *(float4*)&vS[r][sc + 0] = f0;
        *(float4*)&vS[r][sc + 4] = f1;
        *(float4*)&vS[r][sc + 8] = f2;
        *(float4*)&vS[r][sc + 12] = f3;
      } else {
        float4 z = make_float4(0.f, 0.f, 0.f, 0.f);
        *(float4*)&vS[r][sc + 0] = z;
        *(float4*)&vS[r][sc + 4] = z;
        *(float4*)&vS[r][sc + 8] = z;
        *(float4*)&vS[r][sc + 12] = z;
      }
    }
  }
  __syncthreads();
  int tg = t >> 5;
  int d2 = (t & 31) * 2;
  float ax[8], ay[8];
#pragma unroll
  for (int j = 0; j < 8; ++j) { ax[j] = 0.f; ay[j] = 0.f; }
  // rows tg*8 .. tg*8+39 cover taps k=0..32 for the 8 tokens tg*8+j
#pragma unroll
  for (int rr = 0; rr < 40; ++rr) {
    float2 v = *(float2*)&vS[tg * 8 + rr][d2];
#pragma unroll
    for (int j = 0; j < 8; ++j) {
      int k = rr - j;
      if (k >= 0 && k < 33) {
        ax[j] += w33[k] * v.x;
        ay[j] += w33[k] * v.y;
      }
    }
  }
#pragma unroll
  for (int j = 0; j < 8; ++j) {
    float* dst = attout + ((size_t)b * NPAD + n0 + tg * 8 + j) * DD + h * 64 + d2;
    float2 o = *(float2*)dst;
    o.x += ax[j];
    o.y += ay[j];
    *(float2*)dst = o;
  }
}

// ---------------------------------------------------------------- PPEG (combined 7x7)
__global__ __launch_bounds__(128) void k_ppeg(
    float* __restrict__ hB, const float* __restrict__ hA,
    const float* __restrict__ w7, const float* __restrict__ b7,
    const float* __restrict__ w5, const float* __restrict__ b5,
    const float* __restrict__ w3, const float* __restrict__ b3) {
  __shared__ float cw[49][128];
  int t = threadIdx.x;
  int i = blockIdx.x >> 2;
  int j0 = (blockIdx.x & 3) * 32;
  int cg = blockIdx.y, b = blockIdx.z;
  int c = cg * 128 + t;
#pragma unroll
  for (int k = 0; k < 49; ++k) cw[k][t] = w7[c * 49 + k];
#pragma unroll
  for (int di = 0; di < 5; ++di)
#pragma unroll
    for (int dj = 0; dj < 5; ++dj)
      cw[(di + 1) * 7 + dj + 1][t] += w5[c * 25 + di * 5 + dj];
#pragma unroll
  for (int di = 0; di < 3; ++di)
#pragma unroll
    for (int dj = 0; dj < 3; ++dj)
      cw[(di + 2) * 7 + dj + 2][t] += w3[c * 9 + di * 3 + dj];
  cw[24][t] += 1.0f;
  float bias = b7[c] + b5[c] + b3[c];
  const float* base = hA + (size_t)b * TT * DD + DD + c;
  float* obase = hB + (size_t)b * TT * DD + DD + c;
  float acc[32];
#pragma unroll
  for (int j = 0; j < 32; ++j) acc[j] = bias;
  for (int di = 0; di < 7; ++di) {
    int ii = i + di - 3;
    if ((unsigned)ii >= 128u) continue;
    float win[38];
#pragma unroll
    for (int w = 0; w < 38; ++w) {
      int col = j0 - 3 + w;
      win[w] = ((unsigned)col < 128u) ? base[(size_t)(ii * 128 + col) * DD] : 0.f;
    }
#pragma unroll
    for (int dj = 0; dj < 7; ++dj) {
      float wv = cw[di * 7 + dj][t];
#pragma unroll
      for (int j = 0; j < 32; ++j) acc[j] += win[j + dj] * wv;
    }
  }
#pragma unroll
  for (int j = 0; j < 32; ++j) obase[(size_t)(i * 128 + j0 + j) * DD] = acc[j];
}

// ---------------------------------------------------------------- final head
__global__ __launch_bounds__(512) void k_final(
    float* __restrict__ out, const float* __restrict__ h,
    const float* __restrict__ g, const float* __restrict__ be,
    const float* __restrict__ cw, const float* __restrict__ cbias) {
  __shared__ float sm[16];
  int t = threadIdx.x;
  for (int b = 0; b < 2; ++b) {
    const float* row = h + (size_t)b * TT * DD;
    float x = row[t];
    float s = x;
    for (int o = 32; o; o >>= 1) s += __shfl_xor(s, o);
    if ((t & 63) == 0) sm[t >> 6] = s;
    __syncthreads();
    float mu = 0.f;
    for (int i = 0; i < 8; ++i) mu += sm[i];
    mu *= (1.f / 512.f);
    __syncthreads();
    float d = x - mu;
    s = d * d;
    for (int o = 32; o; o >>= 1) s += __shfl_xor(s, o);
    if ((t & 63) == 0) sm[t >> 6] = s;
    __syncthreads();
    float var = 0.f;
    for (int i = 0; i < 8; ++i) var += sm[i];
    var *= (1.f / 512.f);
    float rs = rsqrtf(var + 1e-5f);
    __syncthreads();
    float f = d * rs * g[t] + be[t];
    float p0 = f * cw[2 * t], p1 = f * cw[2 * t + 1];
    for (int o = 32; o; o >>= 1) {
      p0 += __shfl_xor(p0, o);
      p1 += __shfl_xor(p1, o);
    }
    if ((t & 63) == 0) {
      sm[t >> 6] = p0;
      sm[8 + (t >> 6)] = p1;
    }
    __syncthreads();
    if (t == 0) {
      float q0 = 0.f, q1 = 0.f;
      for (int i = 0; i < 8; ++i) {
        q0 += sm[i];
        q1 += sm[8 + i];
      }
      out[b * 2 + 0] = q0 + cbias[0];
      out[b * 2 + 1] = q1 + cbias[1];
    }
    __syncthreads();
  }
}

// ---------------------------------------------------------------- host side
static void run_attn(float* h, const float* lng, const float* lnb,
                     const float* wqkv, const float* wout, const float* bout,
                     const float* resw, float* xp, unsigned short* qkvh, float* ql,
                     float* kl, float* a2, float* z0, float* z1, float* xz, float* xz2,
                     float* yB, float* yC, float* bv, float* w2, float* red,
                     float* Sbuf, unsigned short* wth, hipStream_t stream) {
  // xp region doubles as: [f16 hi/lo planes for LN output] then [fp32 attout]
  unsigned short* xph = (unsigned short*)xp;
  unsigned short* xpl = xph + (size_t)BB * NPAD * DD;
  k_zero_pad<<<BB * PADF, 256, 0, stream>>>(xph, xpl);
  k_ln_pad<<<(BB * TT + 3) / 4, 256, 0, stream>>>(xph, xpl, h, lng, lnb);
  k_cvt_wt<<<dim3(DD / 32, 1536 / 32), 256, 0, stream>>>(wqkv, wth, DD, 1536);
  k_gemm_qkv8<<<dim3(BB * NPAD / 128, 1536 / 256), 512, 0, stream>>>(xph, xpl, wth,
                                                                     qkvh);
  k_landmarks<<<1024, 256, 0, stream>>>(ql, kl, qkvh);
  float* pacc = Sbuf;
  float* pL = Sbuf + (size_t)A3KC * 4096 * 64;
  k_a3v_mfma<<<dim3(16, A3KC), 256, 0, stream>>>(pacc, pL, ql, qkvh);
  k_a3v_red<<<4096, 64, 0, stream>>>(bv, pacc, pL);
  k_sim2<<<dim3(4, 4, 16), 256, 0, stream>>>(a2, ql, kl);
  k_softmax256<<<1024, 256, 0, stream>>>(a2);
  k_pinv_sums<<<16, 256, 0, stream>>>(red, a2);
  k_pinv_scale<<<1, 256, 0, stream>>>(red);
  k_zinit<<<dim3(256, 16), 256, 0, stream>>>(z0, a2, red);
  // Newton-Schulz: 3 matmuls/iter via P = a2@z carried forward
  float* zc = z0;
  float* zn = z1;
  float* P = xz;
  float* Pn = xz2;
  // P0 = a2 @ z0
  k_bmm_poly<<<dim3(4, 4, 16), 256, 0, stream>>>(a2, zc, nullptr, P, 1.f, 0.f, 0.f, 256);
  for (int it = 0; it < 6; ++it) {
    // yB = P@P + 15I - 7P   (== 15I - P@(7I - P))
    k_bmm_poly<<<dim3(4, 4, 16), 256, 0, stream>>>(P, P, P, yB, 1.f, 15.f, -7.f, 256);
    // yC = 13I - P@yB
    k_bmm_poly<<<dim3(4, 4, 16), 256, 0, stream>>>(P, yB, nullptr, yC, -1.f, 13.f, 0.f, 256);
    // zn = 0.25 zc@yC ; Pn = 0.25 P@yC  (batched)
    k_bmm_dual<<<dim3(4, 4, 32), 256, 0, stream>>>(zc, P, yC, zn, Pn, 0.25f);
    float* tmp = zc; zc = zn; zn = tmp;
    tmp = P; P = Pn; Pn = tmp;
  }
  k_bmm_poly<<<dim3(1, 4, 16), 256, 0, stream>>>(zc, bv, nullptr, w2, 1.f, 0.f, 0.f, 64);
  k_att1<<<dim3(NPAD / 256, 16), 256, 0, stream>>>(xp, qkvh, kl, w2);
  k_convres<<<dim3(NPAD / 64, 16), 256, 0, stream>>>(xp, qkvh, resw);
  k_cvt_wt<<<dim3(DD / 32, DD / 32), 256, 0, stream>>>(wout, wth, DD, DD);
  k_gemm_mfma<2><<<dim3(129, 2, BB), 512, 0, stream>>>(xp, nullptr, nullptr, wth, bout,
                                                       h, TT, DD, DD, DD);
}

extern "C" void kernel_launch(void* const* d_in, const int* in_sizes, int n_in,
                              void* d_out, int out_size, void* d_ws, size_t ws_size,
                              hipStream_t stream) {
  const float* x        = (const float*)d_in[0];
  const float* w_feat   = (const float*)d_in[1];
  const float* b_feat   = (const float*)d_in[2];
  const float* cls_tok  = (const float*)d_in[3];
  const float* ln1_g    = (const float*)d_in[4];
  const float* ln1_b    = (const float*)d_in[5];
  const float* qkv1     = (const float*)d_in[6];
  const float* out1_w   = (const float*)d_in[7];
  const float* out1_b   = (const float*)d_in[8];
  const float* res1_w   = (const float*)d_in[9];
  const float* ppeg_w7  = (const float*)d_in[10];
  const float* ppeg_b7  = (const float*)d_in[11];
  const float* ppeg_w5  = (const float*)d_in[12];
  const float* ppeg_b5  = (const float*)d_in[13];
  const float* ppeg_w3  = (const float*)d_in[14];
  const float* ppeg_b3  = (const float*)d_in[15];
  const float* ln2_g    = (const float*)d_in[16];
  const float* ln2_b    = (const float*)d_in[17];
  const float* qkv2     = (const float*)d_in[18];
  const float* out2_w   = (const float*)d_in[19];
  const float* out2_b   = (const float*)d_in[20];
  const float* res2_w   = (const float*)d_in[21];
  const float* lnf_g    = (const float*)d_in[22];
  const float* lnf_b    = (const float*)d_in[23];
  const float* cls_w    = (const float*)d_in[24];
  const float* cls_b    = (const float*)d_in[25];

  float* ws = (float*)d_ws;
  size_t off = 0;
  float* hA  = ws + off; off += (size_t)BB * TT * DD;
  float* hB  = ws + off; off += (size_t)BB * TT * DD;
  float* xp  = ws + off; off += (size_t)BB * NPAD * DD;
  float* qkvf = ws + off; off += (size_t)BB * NPAD * 3 * DD;  // used as f16 (half)
  unsigned short* qkvh = (unsigned short*)qkvf;
  float* ql  = ws + off; off += (size_t)BB * HH * 256 * 64;
  float* kl  = ws + off; off += (size_t)BB * HH * 256 * 64;
  float* a2  = ws + off; off += (size_t)16 * 65536;
  float* z0  = ws + off; off += (size_t)16 * 65536;
  float* z1  = ws + off; off += (size_t)16 * 65536;
  float* xz  = ws + off; off += (size_t)16 * 65536;
  float* xz2 = ws + off; off += (size_t)16 * 65536;
  float* yB  = ws + off; off += (size_t)16 * 65536;
  float* yC  = ws + off; off += (size_t)16 * 65536;
  float* bv  = ws + off; off += (size_t)BB * HH * 256 * 64;
  float* w2  = ws + off; off += (size_t)BB * HH * 256 * 64;
  float* red = ws + off; off += 8448;
  unsigned short* wth = (unsigned short*)(ws + off); off += 393216;

  // Stage 1: h = gelu(x @ w_feat + b_feat), prepend cls token
  k_set_cls<<<2, 512, 0, stream>>>(hA, cls_tok);
  k_cvt_wt<<<dim3(1024 / 32, DD / 32), 256, 0, stream>>>(w_feat, wth, 1024, DD);
  k_gemm_mfma<0><<<dim3(32768 / 128, DD / 256), 512, 0, stream>>>(
      x, nullptr, nullptr, wth, b_feat, hA, 32768, 1024, DD, 1024);
  // Attention 1 (residual in-place on hA; hB is dead -> scratch)
  run_attn(hA, ln1_g, ln1_b, qkv1, out1_w, out1_b, res1_w, xp, qkvh, ql, kl, a2, z0, z1,
           xz, xz2, yB, yC, bv, w2, red, hB, wth, stream);
  // PPEG: hB = ppeg(hA)
  k_copy_cls<<<2, 512, 0, stream>>>(hB, hA);
  k_ppeg<<<dim3(512, 4, 2), 128, 0, stream>>>(hB, hA, ppeg_w7, ppeg_b7, ppeg_w5, ppeg_b5,
                                              ppeg_w3, ppeg_b3);
  // Attention 2 (residual in-place on hB; hA is dead -> scratch)
  run_attn(hB, ln2_g, ln2_b, qkv2, out2_w, out2_b, res2_w, xp, qkvh, ql, kl, a2, z0, z1,
           xz, xz2, yB, yC, bv, w2, red, hA, wth, stream);
  // Final: LN(cls) @ cls_w + cls_b
  k_final<<<1, 512, 0, stream>>>((float*)d_out, hB, lnf_g, lnf_b, cls_w, cls_b);
}

// Round 22
// 1451.068 us; speedup vs baseline: 1.1689x; 1.0612x over previous
//
#include <hip/hip_runtime.h>
#include <cstdint>
#include <cstddef>

#define BB 2
#define TT 16385
#define NPAD 16640
#define DD 512
#define HH 8
#define DHH 64
#define MLAND 256
#define PADF 255
#define A3KC 26
#define A3CH 640

typedef __attribute__((ext_vector_type(8))) _Float16 f16x8;
typedef __attribute__((ext_vector_type(4))) float f32x4;

__device__ __forceinline__ float gelu_f(float v) {
  float c = 0.7978845608028654f * (v + 0.044715f * v * v * v);
  return 0.5f * v * (1.0f + tanhf(c));
}

__device__ __forceinline__ unsigned short f16_1(float a) {
  _Float16 h = (_Float16)a;
  return __builtin_bit_cast(unsigned short, h);
}
__device__ __forceinline__ float f16f(unsigned u) {
  return (float)__builtin_bit_cast(_Float16, (unsigned short)(u & 0xffffu));
}
__device__ __forceinline__ unsigned pk_f16(float a, float b) {
  return (unsigned)f16_1(a) | ((unsigned)f16_1(b) << 16);
}
// split a,b into f16 hi (packed) and f16 residual-lo (packed)
__device__ __forceinline__ void split2h(float a, float b, unsigned& hi, unsigned& lo) {
  _Float16 ah = (_Float16)a, bh = (_Float16)b;
  hi = (unsigned)__builtin_bit_cast(unsigned short, ah) |
       ((unsigned)__builtin_bit_cast(unsigned short, bh) << 16);
  lo = pk_f16(a - (float)ah, b - (float)bh);
}
__device__ __forceinline__ void store4h(float4 v, unsigned short* dh,
                                        unsigned short* dl) {
  unsigned h0, l0, h1, l1;
  split2h(v.x, v.y, h0, l0);
  split2h(v.z, v.w, h1, l1);
  *(uint2*)dh = make_uint2(h0, h1);
  *(uint2*)dl = make_uint2(l0, l1);
}

// async global->LDS 16B (wave-uniform LDS base + lane*16)
__device__ __forceinline__ void gload16(const unsigned short* g, short* l) {
  __builtin_amdgcn_global_load_lds(
      (const __attribute__((address_space(1))) void*)g,
      (__attribute__((address_space(3))) void*)l, 16, 0, 0);
}

// ---------------------------------------------------------------- cls rows
__global__ void k_set_cls(float* __restrict__ h, const float* __restrict__ cls) {
  h[(size_t)blockIdx.x * TT * DD + threadIdx.x] = cls[threadIdx.x];
}
__global__ void k_copy_cls(float* __restrict__ dst, const float* __restrict__ src) {
  size_t o = (size_t)blockIdx.x * TT * DD + threadIdx.x;
  dst[o] = src[o];
}

// ------------------------------------------------ W[K][N] -> Wt f16 [N][K]
__global__ __launch_bounds__(256) void k_cvt_wt(
    const float* __restrict__ W, unsigned short* __restrict__ Wth, int K, int N) {
  __shared__ float tile[32][33];
  int kb = blockIdx.x * 32, nb = blockIdx.y * 32;
  int t = threadIdx.x;
  int tr = t >> 3, tc4 = (t & 7) * 4;
  float4 v = *(const float4*)(W + (size_t)(kb + tr) * N + nb + tc4);
  tile[tr][tc4 + 0] = v.x;
  tile[tr][tc4 + 1] = v.y;
  tile[tr][tc4 + 2] = v.z;
  tile[tr][tc4 + 3] = v.w;
  __syncthreads();
  int n = nb + tr;
  ushort4 hs;
  hs.x = f16_1(tile[tc4 + 0][tr]);
  hs.y = f16_1(tile[tc4 + 1][tr]);
  hs.z = f16_1(tile[tc4 + 2][tr]);
  hs.w = f16_1(tile[tc4 + 3][tr]);
  *(ushort4*)(Wth + (size_t)n * K + kb + tc4) = hs;
}

// ---------------- fp32-via-2xf16 MFMA GEMM, 128x256 tile, 8 waves (512 thr)
// (MODE 0 feat-gelu only; qkv uses k_gemm_qkv8, proj uses k_gemm_proj)
template <int MODE>
__global__ __launch_bounds__(512) void k_gemm_mfma(
    const float* __restrict__ A, const unsigned short* __restrict__ Aph,
    const unsigned short* __restrict__ Apl, const unsigned short* __restrict__ Wth,
    const float* __restrict__ bias, void* __restrict__ Cv, int M, int K, int N,
    int lda) {
  __shared__ short Ash[128][44];
  __shared__ short Asl[128][44];
  __shared__ short Bsh[256][44];
  const int t = threadIdx.x;
  // bijective swizzle over (gridDim.x row-tiles) x (gridDim.y col-tiles)
  int nRow = gridDim.x, nCol = gridDim.y;
  int lin = blockIdx.x + blockIdx.y * nRow;
  int chunk = 8 * nCol;
  int group = lin / chunk;
  int rem = lin - group * chunk;
  int gbase = group * 8;
  int Geff = nRow - gbase;
  if (Geff > 8) Geff = 8;
  const int rb = (gbase + rem % Geff) * 128;
  const int cb = (rem / Geff) * 256;
  const float* Ab = A;
  float* Cf = (float*)Cv;
  unsigned short* Ch = (unsigned short*)Cv;
  if (MODE == 2) {
    int b = blockIdx.z;
    Ab = A + (size_t)b * NPAD * DD + (size_t)PADF * DD;
    Cf = (float*)Cv + (size_t)b * TT * DD;
  }
  const int lane = t & 63, wv = t >> 6;
  const int wr = wv >> 2, wc = wv & 3;
  const int fr = lane & 15, kg = lane >> 4;
  const int srow = t >> 2, skh = (t & 3) * 8;   // A: 8 shorts / thread / plane
  const int brow = t >> 1, bkh = (t & 1) * 16;  // B: 16 shorts / thread

  f32x4 acc[4][4];
  f32x4 zero4 = {0.f, 0.f, 0.f, 0.f};
#pragma unroll
  for (int i = 0; i < 4; ++i)
#pragma unroll
    for (int j = 0; j < 4; ++j) acc[i][j] = zero4;

  for (int k0 = 0; k0 < K; k0 += 32) {
    __syncthreads();
    if (MODE == 1) {
      const unsigned short* ph = Aph + (size_t)(rb + srow) * lda + k0 + skh;
      const unsigned short* pl = Apl + (size_t)(rb + srow) * lda + k0 + skh;
      *(uint4*)&Ash[srow][skh] = *(const uint4*)ph;
      *(uint4*)&Asl[srow][skh] = *(const uint4*)pl;
    } else {
      int grow = rb + srow;
      float4 f0 = {0, 0, 0, 0}, f1 = {0, 0, 0, 0};
      if (grow < M) {
        const float* p = Ab + (size_t)grow * lda + k0 + skh;
        f0 = *(const float4*)p;
        f1 = *(const float4*)(p + 4);
      }
      unsigned h0, h1, h2, h3, l0, l1, l2, l3;
      split2h(f0.x, f0.y, h0, l0);
      split2h(f0.z, f0.w, h1, l1);
      split2h(f1.x, f1.y, h2, l2);
      split2h(f1.z, f1.w, h3, l3);
      *(uint4*)&Ash[srow][skh] = make_uint4(h0, h1, h2, h3);
      *(uint4*)&Asl[srow][skh] = make_uint4(l0, l1, l2, l3);
    }
    {
      const unsigned short* ph = Wth + (size_t)(cb + brow) * K + k0 + bkh;
      *(uint4*)&Bsh[brow][bkh] = *(const uint4*)ph;
      *(uint4*)&Bsh[brow][bkh + 8] = *(const uint4*)(ph + 8);
    }
    __syncthreads();
    f16x8 ah[4], al[4];
#pragma unroll
    for (int mf = 0; mf < 4; ++mf) {
      ah[mf] = *(const f16x8*)&Ash[wr * 64 + mf * 16 + fr][kg * 8];
      al[mf] = *(const f16x8*)&Asl[wr * 64 + mf * 16 + fr][kg * 8];
    }
#pragma unroll
    for (int nf = 0; nf < 4; ++nf) {
      f16x8 bhf = *(const f16x8*)&Bsh[wc * 64 + nf * 16 + fr][kg * 8];
#pragma unroll
      for (int mf = 0; mf < 4; ++mf) {
        acc[mf][nf] =
            __builtin_amdgcn_mfma_f32_16x16x32_f16(ah[mf], bhf, acc[mf][nf], 0, 0, 0);
        acc[mf][nf] =
            __builtin_amdgcn_mfma_f32_16x16x32_f16(al[mf], bhf, acc[mf][nf], 0, 0, 0);
      }
    }
  }
#pragma unroll
  for (int mf = 0; mf < 4; ++mf) {
#pragma unroll
    for (int r = 0; r < 4; ++r) {
      int row = rb + wr * 64 + mf * 16 + kg * 4 + r;
      if (MODE == 2 && row >= M) continue;
      size_t orow = (MODE == 0) ? (size_t)(row + (row >> 14) + 1) : (size_t)row;
#pragma unroll
      for (int nf = 0; nf < 4; ++nf) {
        int col = cb + wc * 64 + nf * 16 + fr;
        float v = acc[mf][nf][r];
        if (MODE == 0) {
          Cf[orow * DD + col] = gelu_f(v + bias[col]);
        } else if (MODE == 1) {
          Ch[orow * (size_t)N + col] = f16_1(v);
        } else {
          float old = Cf[orow * DD + col];
          Cf[orow * DD + col] = old + v + bias[col];
        }
      }
    }
  }
}

// ---------------- qkv GEMM (MODE-1 specialized): gload_lds + counted vmcnt
// BK=32, dbuf LDS 64KB -> 2 blocks/CU, 2-deep prefetch, vmcnt(4),
// XOR slot-swizzle (64B rows, slot^=row&3, 2-way free).
__global__ __launch_bounds__(512) void k_gemm_qkv8(
    const unsigned short* __restrict__ Aph, const unsigned short* __restrict__ Apl,
    const unsigned short* __restrict__ Wth, unsigned short* __restrict__ Ch) {
  __shared__ __align__(16) short Ah[2][128][32];
  __shared__ __align__(16) short Al[2][128][32];
  __shared__ __align__(16) short Bs[2][256][32];
  const int t = threadIdx.x;
  // L2 block swizzle (same as k_gemm_mfma)
  int nRow = gridDim.x, nCol = gridDim.y;
  int lin = blockIdx.x + blockIdx.y * nRow;
  int chunk = 8 * nCol;
  int group = lin / chunk;
  int rem = lin - group * chunk;
  int gbase = group * 8;
  int Geff = nRow - gbase;
  if (Geff > 8) Geff = 8;
  const int rb = (gbase + rem % Geff) * 128;
  const int cb = (rem / Geff) * 256;
  const int lane = t & 63, wv = t >> 6;
  const int wr = wv >> 2, wc = wv & 3;
  const int fr = lane & 15, kg = lane >> 4;
  const int lr4 = lane >> 2;                       // row-in-16 within a gload
  const int ss = (lane & 3) ^ (lr4 & 3);           // pre-swizzled src slot (16B)

  f32x4 acc[4][4];
  f32x4 zero4 = {0.f, 0.f, 0.f, 0.f};
#pragma unroll
  for (int i = 0; i < 4; ++i)
#pragma unroll
    for (int j = 0; j < 4; ++j) acc[i][j] = zero4;

  // stage K-step kt (K=32) into buffer bf: 4 gloads/wave (A hi 1, A lo 1, B 2)
  auto STAGE = [&](int kt, int bf) {
    const int k0 = kt * 32;
    {
      int lr = wv * 16;
      gload16(Aph + (size_t)(rb + lr + lr4) * DD + k0 + ss * 8, &Ah[bf][lr][0]);
      gload16(Apl + (size_t)(rb + lr + lr4) * DD + k0 + ss * 8, &Al[bf][lr][0]);
    }
#pragma unroll
    for (int j = 0; j < 2; ++j) {
      int lr = wv * 32 + j * 16;
      gload16(Wth + (size_t)(cb + lr + lr4) * DD + k0 + ss * 8, &Bs[bf][lr][0]);
    }
  };

  STAGE(0, 0);
  STAGE(1, 1);
  const int sl = ((kg ^ (fr & 3))) * 8;  // swizzled read slot (shorts)
  for (int kt = 0; kt < 16; ++kt) {
    if (kt < 15) {
      asm volatile("s_waitcnt vmcnt(4)" ::: "memory");  // own tile-kt loads done
    } else {
      asm volatile("s_waitcnt vmcnt(0)" ::: "memory");  // final drain
    }
    __builtin_amdgcn_sched_barrier(0);
    __builtin_amdgcn_s_barrier();  // all waves' tile-kt data in LDS
    const int bf = kt & 1;
    f16x8 ah[4], al[4];
#pragma unroll
    for (int mf = 0; mf < 4; ++mf) {
      ah[mf] = *(const f16x8*)&Ah[bf][wr * 64 + mf * 16 + fr][sl];
      al[mf] = *(const f16x8*)&Al[bf][wr * 64 + mf * 16 + fr][sl];
    }
#pragma unroll
    for (int nf = 0; nf < 4; ++nf) {
      f16x8 bhf = *(const f16x8*)&Bs[bf][wc * 64 + nf * 16 + fr][sl];
#pragma unroll
      for (int mf = 0; mf < 4; ++mf) {
        acc[mf][nf] =
            __builtin_amdgcn_mfma_f32_16x16x32_f16(ah[mf], bhf, acc[mf][nf], 0, 0, 0);
        acc[mf][nf] =
            __builtin_amdgcn_mfma_f32_16x16x32_f16(al[mf], bhf, acc[mf][nf], 0, 0, 0);
      }
    }
    __builtin_amdgcn_s_barrier();  // all waves done reading buf bf
    if (kt + 2 < 16) STAGE(kt + 2, bf);
  }
#pragma unroll
  for (int mf = 0; mf < 4; ++mf) {
#pragma unroll
    for (int r = 0; r < 4; ++r) {
      int row = rb + wr * 64 + mf * 16 + kg * 4 + r;
#pragma unroll
      for (int nf = 0; nf < 4; ++nf) {
        int col = cb + wc * 64 + nf * 16 + fr;
        Ch[(size_t)row * 1536 + col] = f16_1(acc[mf][nf][r]);
      }
    }
  }
}

// ---------------- proj GEMM: pipelined, single-f16 A (attf), fp32 residual out
// BK=32, dbuf LDS 48KB -> 3 blocks/CU, 2-deep prefetch, vmcnt(3), XOR swizzle.
__global__ __launch_bounds__(512) void k_gemm_proj(
    const unsigned short* __restrict__ Af, const unsigned short* __restrict__ Wth,
    float* __restrict__ Cb, const float* __restrict__ bias) {
  __shared__ __align__(16) short Ah[2][128][32];
  __shared__ __align__(16) short Bs[2][256][32];
  const int t = threadIdx.x;
  int nRow = gridDim.x, nCol = gridDim.y;
  int lin = blockIdx.x + blockIdx.y * nRow;
  int chunk = 8 * nCol;
  int group = lin / chunk;
  int rem = lin - group * chunk;
  int gbase = group * 8;
  int Geff = nRow - gbase;
  if (Geff > 8) Geff = 8;
  const int rb = (gbase + rem % Geff) * 128;
  const int cb = (rem / Geff) * 256;
  const int lane = t & 63, wv = t >> 6;
  const int wr = wv >> 2, wc = wv & 3;
  const int fr = lane & 15, kg = lane >> 4;
  const int lr4 = lane >> 2;
  const int ss = (lane & 3) ^ (lr4 & 3);
  const size_t arow0 = (size_t)blockIdx.z * NPAD + PADF + rb;

  f32x4 acc[4][4];
  f32x4 zero4 = {0.f, 0.f, 0.f, 0.f};
#pragma unroll
  for (int i = 0; i < 4; ++i)
#pragma unroll
    for (int j = 0; j < 4; ++j) acc[i][j] = zero4;

  // stage K-step kt (K=32) into buffer bf: 3 gloads/wave (A 1, B 2)
  auto STAGE = [&](int kt, int bf) {
    const int k0 = kt * 32;
    {
      int lr = wv * 16;
      gload16(Af + (arow0 + lr + lr4) * DD + k0 + ss * 8, &Ah[bf][lr][0]);
    }
#pragma unroll
    for (int j = 0; j < 2; ++j) {
      int lr = wv * 32 + j * 16;
      gload16(Wth + (size_t)(cb + lr + lr4) * DD + k0 + ss * 8, &Bs[bf][lr][0]);
    }
  };

  STAGE(0, 0);
  STAGE(1, 1);
  const int sl = ((kg ^ (fr & 3))) * 8;
  for (int kt = 0; kt < 16; ++kt) {
    if (kt < 15) {
      asm volatile("s_waitcnt vmcnt(3)" ::: "memory");
    } else {
      asm volatile("s_waitcnt vmcnt(0)" ::: "memory");
    }
    __builtin_amdgcn_sched_barrier(0);
    __builtin_amdgcn_s_barrier();
    const int bf = kt & 1;
    f16x8 ah[4];
#pragma unroll
    for (int mf = 0; mf < 4; ++mf)
      ah[mf] = *(const f16x8*)&Ah[bf][wr * 64 + mf * 16 + fr][sl];
#pragma unroll
    for (int nf = 0; nf < 4; ++nf) {
      f16x8 bhf = *(const f16x8*)&Bs[bf][wc * 64 + nf * 16 + fr][sl];
#pragma unroll
      for (int mf = 0; mf < 4; ++mf)
        acc[mf][nf] =
            __builtin_amdgcn_mfma_f32_16x16x32_f16(ah[mf], bhf, acc[mf][nf], 0, 0, 0);
    }
    __builtin_amdgcn_s_barrier();
    if (kt + 2 < 16) STAGE(kt + 2, bf);
  }
  float* Cf = Cb + (size_t)blockIdx.z * TT * DD;
#pragma unroll
  for (int mf = 0; mf < 4; ++mf) {
#pragma unroll
    for (int r = 0; r < 4; ++r) {
      int row = rb + wr * 64 + mf * 16 + kg * 4 + r;
      if (row >= TT) continue;
#pragma unroll
      for (int nf = 0; nf < 4; ++nf) {
        int col = cb + wc * 64 + nf * 16 + fr;
        float old = Cf[(size_t)row * DD + col];
        Cf[(size_t)row * DD + col] = old + acc[mf][nf][r] + bias[col];
      }
    }
  }
}

// ------------------------- LN + pad -> writes f16 hi/lo planes (qkv A operand)
__global__ __launch_bounds__(256) void k_ln_pad(
    unsigned short* __restrict__ xph, unsigned short* __restrict__ xpl,
    const float* __restrict__ h, const float* __restrict__ gam,
    const float* __restrict__ bet) {
  int w = threadIdx.x >> 6, lane = threadIdx.x & 63;
  int row = blockIdx.x * 4 + w;
  if (row >= BB * TT) return;
  int b = row / TT, i = row - b * TT;
  const float* src = h + (size_t)row * DD;
  float4 x0 = *(const float4*)(src + lane * 4);
  float4 x1 = *(const float4*)(src + 256 + lane * 4);
  float s = x0.x + x0.y + x0.z + x0.w + x1.x + x1.y + x1.z + x1.w;
  for (int o = 32; o; o >>= 1) s += __shfl_xor(s, o);
  float mu = s * (1.f / 512.f);
  float q = (x0.x - mu) * (x0.x - mu) + (x0.y - mu) * (x0.y - mu) +
            (x0.z - mu) * (x0.z - mu) + (x0.w - mu) * (x0.w - mu) +
            (x1.x - mu) * (x1.x - mu) + (x1.y - mu) * (x1.y - mu) +
            (x1.z - mu) * (x1.z - mu) + (x1.w - mu) * (x1.w - mu);
  for (int o = 32; o; o >>= 1) q += __shfl_xor(q, o);
  float rs = rsqrtf(q * (1.f / 512.f) + 1e-5f);
  float4 g0 = *(const float4*)(gam + lane * 4);
  float4 g1 = *(const float4*)(gam + 256 + lane * 4);
  float4 b0 = *(const float4*)(bet + lane * 4);
  float4 b1 = *(const float4*)(bet + 256 + lane * 4);
  float4 o0, o1;
  o0.x = (x0.x - mu) * rs * g0.x + b0.x;
  o0.y = (x0.y - mu) * rs * g0.y + b0.y;
  o0.z = (x0.z - mu) * rs * g0.z + b0.z;
  o0.w = (x0.w - mu) * rs * g0.w + b0.w;
  o1.x = (x1.x - mu) * rs * g1.x + b1.x;
  o1.y = (x1.y - mu) * rs * g1.y + b1.y;
  o1.z = (x1.z - mu) * rs * g1.z + b1.z;
  o1.w = (x1.w - mu) * rs * g1.w + b1.w;
  size_t ro = ((size_t)b * NPAD + PADF + i) * DD;
  store4h(o0, xph + ro + lane * 4, xpl + ro + lane * 4);
  store4h(o1, xph + ro + 256 + lane * 4, xpl + ro + 256 + lane * 4);
}

__global__ void k_zero_pad(unsigned short* __restrict__ xph,
                           unsigned short* __restrict__ xpl) {
  int r = blockIdx.x;
  int b = r / PADF, j = r - b * PADF;
  size_t ro = ((size_t)b * NPAD + j) * DD;
  ((unsigned*)(xph + ro))[threadIdx.x] = 0u;
  ((unsigned*)(xpl + ro))[threadIdx.x] = 0u;
}

// ---------------------------------------------------------------- landmarks (f16 qkv)
__global__ __launch_bounds__(256) void k_landmarks(
    float* __restrict__ ql, float* __restrict__ kl,
    const unsigned short* __restrict__ qkv) {
  int t = threadIdx.x;
  int mi = t >> 6, d = t & 63;
  int blk = blockIdx.x;
  int bh = blk >> 6, mg = blk & 63;
  int b = bh >> 3, h = bh & 7;
  int m = mg * 4 + mi;
  const unsigned short* base = qkv + (size_t)b * NPAD * 1536 + h * 64 + d;
  float sq = 0.f, sk = 0.f;
  int t0 = m * 65;
  for (int j = 0; j < 65; ++j) {
    const unsigned short* p = base + (size_t)(t0 + j) * 1536;
    sq += f16f(p[0]);
    sk += f16f(p[512]);
  }
  ql[((size_t)bh * 256 + m) * 64 + d] = sq * (0.125f / 65.f);
  kl[((size_t)bh * 256 + m) * 64 + d] = sk * (1.f / 65.f);
}

// ---------------------------------------------------------------- sim2 = ql @ kl^T
__global__ __launch_bounds__(256) void k_sim2(
    float* __restrict__ sim, const float* __restrict__ ql, const float* __restrict__ kl) {
  __shared__ __align__(16) float Aq[64][68];
  __shared__ __align__(16) float Bk[64][68];
  int t = threadIdx.x;
  int tj = blockIdx.x, ti = blockIdx.y, bh = blockIdx.z;
  int r = t >> 2, cc = (t & 3) * 16;
  const float* ap = ql + ((size_t)bh * 256 + ti * 64 + r) * 64 + cc;
  const float* bp = kl + ((size_t)bh * 256 + tj * 64 + r) * 64 + cc;
#pragma unroll
  for (int i = 0; i < 16; i += 4) {
    *(float4*)&Aq[r][cc + i] = *(const float4*)(ap + i);
    *(float4*)&Bk[r][cc + i] = *(const float4*)(bp + i);
  }
  __syncthreads();
  int tx = t & 15, ty = t >> 4;
  float acc[4][4];
#pragma unroll
  for (int i = 0; i < 4; ++i)
#pragma unroll
    for (int j = 0; j < 4; ++j) acc[i][j] = 0.f;
  for (int d = 0; d < 64; d += 4) {
    float4 a4[4], b4[4];
#pragma unroll
    for (int ii = 0; ii < 4; ++ii) a4[ii] = *(float4*)&Aq[ty * 4 + ii][d];
#pragma unroll
    for (int jj = 0; jj < 4; ++jj) b4[jj] = *(float4*)&Bk[tx * 4 + jj][d];
#pragma unroll
    for (int ii = 0; ii < 4; ++ii)
#pragma unroll
      for (int jj = 0; jj < 4; ++jj)
        acc[ii][jj] += a4[ii].x * b4[jj].x + a4[ii].y * b4[jj].y + a4[ii].z * b4[jj].z +
                       a4[ii].w * b4[jj].w;
  }
#pragma unroll
  for (int ii = 0; ii < 4; ++ii)
#pragma unroll
    for (int jj = 0; jj < 4; ++jj)
      sim[((size_t)bh * 256 + ti * 64 + ty * 4 + ii) * 256 + tj * 64 + tx * 4 + jj] =
          acc[ii][jj];
}

// ---------------------------------------------------------------- row softmax (len 256)
__global__ __launch_bounds__(256) void k_softmax256(float* __restrict__ a) {
  int w = threadIdx.x >> 6, lane = threadIdx.x & 63;
  size_t row = (size_t)blockIdx.x * 4 + w;
  float* p = a + row * 256 + lane * 4;
  float4 v = *(float4*)p;
  float m = fmaxf(fmaxf(v.x, v.y), fmaxf(v.z, v.w));
  for (int o = 32; o; o >>= 1) m = fmaxf(m, __shfl_xor(m, o));
  v.x = expf(v.x - m); v.y = expf(v.y - m);
  v.z = expf(v.z - m); v.w = expf(v.w - m);
  float s = v.x + v.y + v.z + v.w;
  for (int o = 32; o; o >>= 1) s += __shfl_xor(s, o);
  float inv = 1.f / s;
  v.x *= inv; v.y *= inv; v.z *= inv; v.w *= inv;
  *(float4*)p = v;
}

// ---------------------------------------------------------------- pinv helpers
__global__ void k_pinv_sums(float* __restrict__ red, const float* __restrict__ a2) {
  int bh = blockIdx.x, t = threadIdx.x;
  const float* Ab = a2 + (size_t)bh * 65536;
  float s = 0.f;
  for (int i = 0; i < 256; ++i) s += fabsf(Ab[(size_t)i * 256 + t]);
  red[bh * 256 + t] = s;
  float c = 0.f;
  const float* rp = Ab + (size_t)t * 256;
  for (int j = 0; j < 256; j += 4) {
    float4 v = *(const float4*)(rp + j);
    c += fabsf(v.x) + fabsf(v.y) + fabsf(v.z) + fabsf(v.w);
  }
  red[4096 + bh * 256 + t] = c;
}

__global__ void k_pinv_scale(float* __restrict__ red) {
  __shared__ float sm[8];
  int t = threadIdx.x;
  float m1 = 0.f, m2 = 0.f;
  for (int k = t; k < 4096; k += 256) {
    m1 = fmaxf(m1, red[k]);
    m2 = fmaxf(m2, red[4096 + k]);
  }
  for (int o = 32; o; o >>= 1) {
    m1 = fmaxf(m1, __shfl_xor(m1, o));
    m2 = fmaxf(m2, __shfl_xor(m2, o));
  }
  int w = t >> 6;
  if ((t & 63) == 0) { sm[w] = m1; sm[4 + w] = m2; }
  __syncthreads();
  if (t == 0) {
    float a = fmaxf(fmaxf(sm[0], sm[1]), fmaxf(sm[2], sm[3]));
    float b = fmaxf(fmaxf(sm[4], sm[5]), fmaxf(sm[6], sm[7]));
    red[8192] = 1.0f / (a * b);
  }
}

__global__ void k_zinit(float* __restrict__ z, const float* __restrict__ a2,
                        const float* __restrict__ red) {
  float s = red[8192];
  int i = blockIdx.x, bh = blockIdx.y, j = threadIdx.x;
  z[((size_t)bh * 256 + i) * 256 + j] = a2[((size_t)bh * 256 + j) * 256 + i] * s;
}

// ---- shared BK=128 f16 3-term matmul core: acc += A[i0..i0+64) @ B (256xN)
__device__ __forceinline__ void bmm_core(
    short (*Ash)[136], short (*Asl)[136], short (*Bsh)[136], short (*Bsl)[136],
    const float* __restrict__ Ab, const float* __restrict__ Bb, int i0, int j0, int N,
    int t, f32x4 (&acc)[4]) {
  const int lane = t & 63, w = t >> 6;
  const int fr = lane & 15, kg = lane >> 4;
  const int ar = t >> 2, akseg = (t & 3) * 32;  // A: 32 floats / thread
  for (int k0 = 0; k0 < 256; k0 += 128) {
    __syncthreads();
    {  // stage A rows (f16 split): 64 rows x 128 k
      const float* p = Ab + (size_t)(i0 + ar) * 256 + k0 + akseg;
#pragma unroll
      for (int q = 0; q < 4; ++q) {
        float4 f0 = *(const float4*)(p + q * 8);
        float4 f1 = *(const float4*)(p + q * 8 + 4);
        unsigned h0, h1, h2, h3, l0, l1, l2, l3;
        split2h(f0.x, f0.y, h0, l0);
        split2h(f0.z, f0.w, h1, l1);
        split2h(f1.x, f1.y, h2, l2);
        split2h(f1.z, f1.w, h3, l3);
        *(uint4*)&Ash[ar][akseg + q * 8] = make_uint4(h0, h1, h2, h3);
        *(uint4*)&Asl[ar][akseg + q * 8] = make_uint4(l0, l1, l2, l3);
      }
    }
    {  // stage B transposed (f16 split): Bsh[j_local][k_local], 128 k-rows x 64 j
#pragma unroll
      for (int pass = 0; pass < 8; ++pass) {
        int kr = pass * 16 + (t >> 4);
        int jseg = (t & 15) * 4;
        const float* p = Bb + (size_t)(k0 + kr) * N + j0 + jseg;
        float4 f = *(const float4*)p;
        float fv[4] = {f.x, f.y, f.z, f.w};
#pragma unroll
        for (int c = 0; c < 4; ++c) {
          _Float16 hh = (_Float16)fv[c];
          float lo = fv[c] - (float)hh;
          Bsh[jseg + c][kr] = (short)__builtin_bit_cast(unsigned short, hh);
          Bsl[jseg + c][kr] = (short)f16_1(lo);
        }
      }
    }
    __syncthreads();
#pragma unroll
    for (int kw = 0; kw < 4; ++kw) {
      f16x8 bhf = *(const f16x8*)&Bsh[w * 16 + fr][kw * 32 + kg * 8];
      f16x8 blf = *(const f16x8*)&Bsl[w * 16 + fr][kw * 32 + kg * 8];
#pragma unroll
      for (int mf = 0; mf < 4; ++mf) {
        f16x8 ah = *(const f16x8*)&Ash[mf * 16 + fr][kw * 32 + kg * 8];
        f16x8 al = *(const f16x8*)&Asl[mf * 16 + fr][kw * 32 + kg * 8];
        acc[mf] = __builtin_amdgcn_mfma_f32_16x16x32_f16(ah, bhf, acc[mf], 0, 0, 0);
        acc[mf] = __builtin_amdgcn_mfma_f32_16x16x32_f16(al, bhf, acc[mf], 0, 0, 0);
        acc[mf] = __builtin_amdgcn_mfma_f32_16x16x32_f16(ah, blf, acc[mf], 0, 0, 0);
      }
    }
  }
}

// ------- batched 256x256 @ 256xN; C = a1*(A@B) + d1*I + e1*E (E optional)
__global__ __launch_bounds__(256) void k_bmm_poly(
    const float* __restrict__ A, const float* __restrict__ Bm,
    const float* __restrict__ E, float* __restrict__ C, float a1, float d1, float e1,
    int N) {
  __shared__ short Ash[64][136];
  __shared__ short Asl[64][136];
  __shared__ short Bsh[64][136];
  __shared__ short Bsl[64][136];
  const int t = threadIdx.x;
  const int bh = blockIdx.z;
  const int i0 = blockIdx.y * 64, j0 = blockIdx.x * 64;
  const int lane = t & 63, w = t >> 6;
  const int fr = lane & 15, kg = lane >> 4;
  f32x4 acc[4];
  f32x4 zero4 = {0.f, 0.f, 0.f, 0.f};
#pragma unroll
  for (int i = 0; i < 4; ++i) acc[i] = zero4;
  bmm_core(Ash, Asl, Bsh, Bsl, A + (size_t)bh * 65536, Bm + (size_t)bh * 256 * N, i0,
           j0, N, t, acc);
  int j = j0 + w * 16 + fr;
#pragma unroll
  for (int mf = 0; mf < 4; ++mf) {
#pragma unroll
    for (int rr = 0; rr < 4; ++rr) {
      int i = i0 + mf * 16 + kg * 4 + rr;
      float v = acc[mf][rr];
      size_t off = (size_t)bh * 256 * N + (size_t)i * N + j;
      float out = a1 * v + ((i == j) ? d1 : 0.f);
      if (E) out += e1 * E[off];
      C[off] = out;
    }
  }
}

// ------- dual batched: z<16: C0 = s*(A0@B); z>=16: C1 = s*(A1@B)   (N=256)
__global__ __launch_bounds__(256) void k_bmm_dual(
    const float* __restrict__ A0, const float* __restrict__ A1,
    const float* __restrict__ Bm, float* __restrict__ C0, float* __restrict__ C1,
    float s) {
  __shared__ short Ash[64][136];
  __shared__ short Asl[64][136];
  __shared__ short Bsh[64][136];
  __shared__ short Bsl[64][136];
  const int t = threadIdx.x;
  const int z = blockIdx.z;
  const int bh = z & 15;
  const int sel = z >> 4;
  const float* A = sel ? A1 : A0;
  float* C = sel ? C1 : C0;
  const int i0 = blockIdx.y * 64, j0 = blockIdx.x * 64;
  const int lane = t & 63, w = t >> 6;
  const int fr = lane & 15, kg = lane >> 4;
  f32x4 acc[4];
  f32x4 zero4 = {0.f, 0.f, 0.f, 0.f};
#pragma unroll
  for (int i = 0; i < 4; ++i) acc[i] = zero4;
  bmm_core(Ash, Asl, Bsh, Bsl, A + (size_t)bh * 65536, Bm + (size_t)bh * 65536, i0, j0,
           256, t, acc);
  int j = j0 + w * 16 + fr;
#pragma unroll
  for (int mf = 0; mf < 4; ++mf) {
#pragma unroll
    for (int rr = 0; rr < 4; ++rr) {
      int i = i0 + mf * 16 + kg * 4 + rr;
      size_t off = (size_t)bh * 65536 + (size_t)i * 256 + j;
      C[off] = s * acc[mf][rr];
    }
  }
}

// -------------------------- a3 @ v : MFMA flash (f16 qkv, no-max, split-K chunks)
__global__ __launch_bounds__(256, 2) void k_a3v_mfma(
    float* __restrict__ pacc, float* __restrict__ pL,
    const float* __restrict__ ql, const unsigned short* __restrict__ qkv) {
  __shared__ short Ks[64][72];
  __shared__ short Vt[64][72];
  __shared__ short Ps[4][64][72];
  const int t = threadIdx.x;
  const int bh = blockIdx.x;
  const int kc = blockIdx.y;
  const int b = bh >> 3, h = bh & 7;
  const int lane = t & 63, w = t >> 6;
  const int fr = lane & 15, kg = lane >> 4;

  f16x8 qf[4][2];
#pragma unroll
  for (int nf = 0; nf < 4; ++nf) {
    const float* qp = ql + ((size_t)bh * 256 + w * 64 + nf * 16 + fr) * 64 + kg * 8;
#pragma unroll
    for (int kw = 0; kw < 2; ++kw) {
      float4 a = *(const float4*)(qp + kw * 32);
      float4 c = *(const float4*)(qp + kw * 32 + 4);
      uint4 uu = make_uint4(pk_f16(a.x, a.y), pk_f16(a.z, a.w), pk_f16(c.x, c.y),
                            pk_f16(c.z, c.w));
      qf[nf][kw] = *(f16x8*)&uu;
    }
  }
  f32x4 oacc[4][4];
  f32x4 zero4 = {0.f, 0.f, 0.f, 0.f};
#pragma unroll
  for (int i = 0; i < 4; ++i)
#pragma unroll
    for (int j = 0; j < 4; ++j) oacc[i][j] = zero4;
  float Lp[4] = {0.f, 0.f, 0.f, 0.f};

  const int skey = t >> 2, sd = (t & 3) * 16;
  const unsigned short* kbase = qkv + (size_t)b * NPAD * 1536 + 512 + h * 64 + sd;

  for (int it = 0; it < A3CH / 64; ++it) {
    int nt = kc * A3CH + it * 64;
    __syncthreads();
    {
      const unsigned short* kp = kbase + (size_t)(nt + skey) * 1536;
      *(uint4*)&Ks[skey][sd] = *(const uint4*)kp;
      *(uint4*)&Ks[skey][sd + 8] = *(const uint4*)(kp + 8);
      const unsigned short* vp = kp + 512;
      uint4 v01 = *(const uint4*)vp;
      uint4 v23 = *(const uint4*)(vp + 8);
      Vt[sd + 0][skey] = (short)v01.x;
      Vt[sd + 1][skey] = (short)(v01.x >> 16);
      Vt[sd + 2][skey] = (short)v01.y;
      Vt[sd + 3][skey] = (short)(v01.y >> 16);
      Vt[sd + 4][skey] = (short)v01.z;
      Vt[sd + 5][skey] = (short)(v01.z >> 16);
      Vt[sd + 6][skey] = (short)v01.w;
      Vt[sd + 7][skey] = (short)(v01.w >> 16);
      Vt[sd + 8][skey] = (short)v23.x;
      Vt[sd + 9][skey] = (short)(v23.x >> 16);
      Vt[sd + 10][skey] = (short)v23.y;
      Vt[sd + 11][skey] = (short)(v23.y >> 16);
      Vt[sd + 12][skey] = (short)v23.z;
      Vt[sd + 13][skey] = (short)(v23.z >> 16);
      Vt[sd + 14][skey] = (short)v23.w;
      Vt[sd + 15][skey] = (short)(v23.w >> 16);
    }
    __syncthreads();
    f32x4 sacc[4][4];
#pragma unroll
    for (int i = 0; i < 4; ++i)
#pragma unroll
      for (int j = 0; j < 4; ++j) sacc[i][j] = zero4;
#pragma unroll
    for (int kw = 0; kw < 2; ++kw) {
      f16x8 kf[4];
#pragma unroll
      for (int mf = 0; mf < 4; ++mf)
        kf[mf] = *(const f16x8*)&Ks[mf * 16 + fr][kw * 32 + kg * 8];
#pragma unroll
      for (int mf = 0; mf < 4; ++mf)
#pragma unroll
        for (int nf = 0; nf < 4; ++nf)
          sacc[mf][nf] = __builtin_amdgcn_mfma_f32_16x16x32_f16(kf[mf], qf[nf][kw],
                                                                sacc[mf][nf], 0, 0, 0);
    }
#pragma unroll
    for (int mf = 0; mf < 4; ++mf)
#pragma unroll
      for (int nf = 0; nf < 4; ++nf) {
        f32x4 s = sacc[mf][nf];
        float p0 = __expf(s[0]);
        float p1 = __expf(s[1]);
        float p2 = __expf(s[2]);
        float p3 = __expf(s[3]);
        Lp[nf] += (p0 + p1) + (p2 + p3);
        uint2 pw = make_uint2(pk_f16(p0, p1), pk_f16(p2, p3));
        *(uint2*)&Ps[w][nf * 16 + fr][mf * 16 + kg * 4] = pw;
      }
    __syncthreads();
#pragma unroll
    for (int kw = 0; kw < 2; ++kw) {
      f16x8 vf[4], pf[4];
#pragma unroll
      for (int mf = 0; mf < 4; ++mf)
        vf[mf] = *(const f16x8*)&Vt[mf * 16 + fr][kw * 32 + kg * 8];
#pragma unroll
      for (int nf = 0; nf < 4; ++nf)
        pf[nf] = *(const f16x8*)&Ps[w][nf * 16 + fr][kw * 32 + kg * 8];
#pragma unroll
      for (int mf = 0; mf < 4; ++mf)
#pragma unroll
        for (int nf = 0; nf < 4; ++nf)
          oacc[mf][nf] = __builtin_amdgcn_mfma_f32_16x16x32_f16(vf[mf], pf[nf],
                                                                oacc[mf][nf], 0, 0, 0);
    }
  }
  size_t obase = ((size_t)kc * 16 + bh) * 256;
#pragma unroll
  for (int mf = 0; mf < 4; ++mf)
#pragma unroll
    for (int nf = 0; nf < 4; ++nf) {
      int lm = w * 64 + nf * 16 + fr;
      *(f32x4*)(pacc + (obase + lm) * 64 + mf * 16 + kg * 4) = oacc[mf][nf];
    }
#pragma unroll
  for (int nf = 0; nf < 4; ++nf) {
    Lp[nf] += __shfl_xor(Lp[nf], 16);
    Lp[nf] += __shfl_xor(Lp[nf], 32);
  }
  if (lane < 16) {
#pragma unroll
    for (int nf = 0; nf < 4; ++nf)
      pL[obase + w * 64 + nf * 16 + lane] = Lp[nf];
  }
}

__global__ __launch_bounds__(64) void k_a3v_red(
    float* __restrict__ bv, const float* __restrict__ pacc,
    const float* __restrict__ pL) {
  int row = blockIdx.x;
  int d = threadIdx.x;
  float A = 0.f, L = 0.f;
#pragma unroll
  for (int c = 0; c < A3KC; ++c) {
    size_t pr = (size_t)c * 4096 + row;
    A += pacc[pr * 64 + d];
    L += pL[pr];
  }
  bv[(size_t)row * 64 + d] = A / L;
}

// ------------- fused sim1: softmax(q @ (0.125*kl)^T) @ w2 -> single f16 attout
__global__ __launch_bounds__(256, 2) void k_att1(
    unsigned short* __restrict__ attf, const unsigned short* __restrict__ qkv,
    const float* __restrict__ kl, const float* __restrict__ w2) {
  __shared__ short KLs[64][72];
  __shared__ short W2t[64][72];
  __shared__ short Ps[4][64][72];
  const int t = threadIdx.x;
  const int tile = blockIdx.x, bh = blockIdx.y;
  const int b = bh >> 3, h = bh & 7;
  const int lane = t & 63, w = t >> 6;
  const int fr = lane & 15, kg = lane >> 4;
  const int n0 = tile * 256;

  f16x8 qf[4][2];
#pragma unroll
  for (int nf = 0; nf < 4; ++nf) {
    const unsigned short* qp =
        qkv + ((size_t)b * NPAD + n0 + w * 64 + nf * 16 + fr) * 1536 + h * 64 + kg * 8;
    qf[nf][0] = *(const f16x8*)qp;
    qf[nf][1] = *(const f16x8*)(qp + 32);
  }
  f32x4 oacc[4][4];
  f32x4 zero4 = {0.f, 0.f, 0.f, 0.f};
#pragma unroll
  for (int i = 0; i < 4; ++i)
#pragma unroll
    for (int j = 0; j < 4; ++j) oacc[i][j] = zero4;
  float Lp[4] = {0.f, 0.f, 0.f, 0.f};

  const int sr = t >> 2, sc = (t & 3) * 16;
  for (int cb = 0; cb < 4; ++cb) {
    __syncthreads();
    {
      const float* kp = kl + ((size_t)bh * 256 + cb * 64 + sr) * 64 + sc;
      float4 k0 = *(const float4*)kp;
      float4 k1 = *(const float4*)(kp + 4);
      float4 k2 = *(const float4*)(kp + 8);
      float4 k3 = *(const float4*)(kp + 12);
      *(uint4*)&KLs[sr][sc] =
          make_uint4(pk_f16(k0.x * 0.125f, k0.y * 0.125f),
                     pk_f16(k0.z * 0.125f, k0.w * 0.125f),
                     pk_f16(k1.x * 0.125f, k1.y * 0.125f),
                     pk_f16(k1.z * 0.125f, k1.w * 0.125f));
      *(uint4*)&KLs[sr][sc + 8] =
          make_uint4(pk_f16(k2.x * 0.125f, k2.y * 0.125f),
                     pk_f16(k2.z * 0.125f, k2.w * 0.125f),
                     pk_f16(k3.x * 0.125f, k3.y * 0.125f),
                     pk_f16(k3.z * 0.125f, k3.w * 0.125f));
      const float* wp = w2 + ((size_t)bh * 256 + cb * 64 + sr) * 64 + sc;
      float4 v0 = *(const float4*)wp;
      float4 v1 = *(const float4*)(wp + 4);
      float4 v2 = *(const float4*)(wp + 8);
      float4 v3 = *(const float4*)(wp + 12);
      W2t[sc + 0][sr] = (short)f16_1(v0.x);
      W2t[sc + 1][sr] = (short)f16_1(v0.y);
      W2t[sc + 2][sr] = (short)f16_1(v0.z);
      W2t[sc + 3][sr] = (short)f16_1(v0.w);
      W2t[sc + 4][sr] = (short)f16_1(v1.x);
      W2t[sc + 5][sr] = (short)f16_1(v1.y);
      W2t[sc + 6][sr] = (short)f16_1(v1.z);
      W2t[sc + 7][sr] = (short)f16_1(v1.w);
      W2t[sc + 8][sr] = (short)f16_1(v2.x);
      W2t[sc + 9][sr] = (short)f16_1(v2.y);
      W2t[sc + 10][sr] = (short)f16_1(v2.z);
      W2t[sc + 11][sr] = (short)f16_1(v2.w);
      W2t[sc + 12][sr] = (short)f16_1(v3.x);
      W2t[sc + 13][sr] = (short)f16_1(v3.y);
      W2t[sc + 14][sr] = (short)f16_1(v3.z);
      W2t[sc + 15][sr] = (short)f16_1(v3.w);
    }
    __syncthreads();
    f32x4 sacc[4][4];
#pragma unroll
    for (int i = 0; i < 4; ++i)
#pragma unroll
      for (int j = 0; j < 4; ++j) sacc[i][j] = zero4;
#pragma unroll
    for (int kw = 0; kw < 2; ++kw) {
      f16x8 kf[4];
#pragma unroll
      for (int mf = 0; mf < 4; ++mf)
        kf[mf] = *(const f16x8*)&KLs[mf * 16 + fr][kw * 32 + kg * 8];
#pragma unroll
      for (int mf = 0; mf < 4; ++mf)
#pragma unroll
        for (int nf = 0; nf < 4; ++nf)
          sacc[mf][nf] = __builtin_amdgcn_mfma_f32_16x16x32_f16(kf[mf], qf[nf][kw],
                                                                sacc[mf][nf], 0, 0, 0);
    }
#pragma unroll
    for (int mf = 0; mf < 4; ++mf)
#pragma unroll
      for (int nf = 0; nf < 4; ++nf) {
        f32x4 s = sacc[mf][nf];
        float p0 = __expf(s[0]);
        float p1 = __expf(s[1]);
        float p2 = __expf(s[2]);
        float p3 = __expf(s[3]);
        Lp[nf] += (p0 + p1) + (p2 + p3);
        uint2 pw = make_uint2(pk_f16(p0, p1), pk_f16(p2, p3));
        *(uint2*)&Ps[w][nf * 16 + fr][mf * 16 + kg * 4] = pw;
      }
    __syncthreads();
#pragma unroll
    for (int kw = 0; kw < 2; ++kw) {
      f16x8 vf[4], pf[4];
#pragma unroll
      for (int mf = 0; mf < 4; ++mf)
        vf[mf] = *(const f16x8*)&W2t[mf * 16 + fr][kw * 32 + kg * 8];
#pragma unroll
      for (int nf = 0; nf < 4; ++nf)
        pf[nf] = *(const f16x8*)&Ps[w][nf * 16 + fr][kw * 32 + kg * 8];
#pragma unroll
      for (int mf = 0; mf < 4; ++mf)
#pragma unroll
        for (int nf = 0; nf < 4; ++nf)
          oacc[mf][nf] = __builtin_amdgcn_mfma_f32_16x16x32_f16(vf[mf], pf[nf],
                                                                oacc[mf][nf], 0, 0, 0);
    }
  }
#pragma unroll
  for (int nf = 0; nf < 4; ++nf) {
    Lp[nf] += __shfl_xor(Lp[nf], 16);
    Lp[nf] += __shfl_xor(Lp[nf], 32);
  }
#pragma unroll
  for (int nf = 0; nf < 4; ++nf) {
    float inv = 1.0f / Lp[nf];
    int tok = n0 + w * 64 + nf * 16 + fr;
#pragma unroll
    for (int mf = 0; mf < 4; ++mf) {
      f32x4 o = oacc[mf][nf];
      ushort4 hs;
      hs.x = f16_1(o[0] * inv);
      hs.y = f16_1(o[1] * inv);
      hs.z = f16_1(o[2] * inv);
      hs.w = f16_1(o[3] * inv);
      *(ushort4*)(attf + ((size_t)b * NPAD + tok) * DD + h * 64 + mf * 16 + kg * 4) = hs;
    }
  }
}

// ---------------- attf += depthwise33(v); sliding-window (40 LDS loads/thread)
__global__ __launch_bounds__(256) void k_convres(
    unsigned short* __restrict__ attf, const unsigned short* __restrict__ qkv,
    const float* __restrict__ resw) {
  __shared__ float vS[96][68];
  __shared__ float w33[33];
  int t = threadIdx.x;
  int tb = blockIdx.x, bh = blockIdx.y;
  int b = bh >> 3, h = bh & 7;
  int n0 = tb * 64;
  if (t < 33) w33[t] = resw[h * 33 + t];
  int sc = (t & 3) * 16;
#pragma unroll
  for (int pass = 0; pass < 2; ++pass) {
    int r = (t >> 2) + pass * 64;
    if (r < 96) {
      int seq = n0 - 16 + r;
      if (seq >= 0 && seq < NPAD) {
        const unsigned short* p =
            qkv + ((size_t)b * NPAD + seq) * 1536 + 1024 + h * 64 + sc;
        uint4 u0 = *(const uint4*)p;
        uint4 u1 = *(const uint4*)(p + 8);
        float4 f0 = make_float4(f16f(u0.x), f16f(u0.x >> 16), f16f(u0.y),
                                f16f(u0.y >> 16));
        float4 f1 = make_float4(f16f(u0.z), f16f(u0.z >> 16), f16f(u0.w),
                                f16f(u0.w >> 16));
        float4 f2 = make_float4(f16f(u1.x), f16f(u1.x >> 16), f16f(u1.y),
                                f16f(u1.y >> 16));
        float4 f3 = make_float4(f16f(u1.z), f16f(u1.z >> 16), f16f(u1.w),
                                f16f(u1.w >> 16));
        *(float4*)&vS[r][sc + 0] = f0;
        *(float4*)&vS[r][sc + 4] = f1;
        *(float4*)&vS[r][sc + 8] = f2;
        *(float4*)&vS[r][sc + 12] = f3;
      } else {
        float4 z = make_float4(0.f, 0.f, 0.f, 0.f);
        *(float4*)&vS[r][sc + 0] = z;
        *(float4*)&vS[r][sc + 4] = z;
        *(float4*)&vS[r][sc + 8] = z;
        *(float4*)&vS[r][sc + 12] = z;
      }
    }
  }
  __syncthreads();
  int tg = t >> 5;
  int d2 = (t & 31) * 2;
  float ax[8], ay[8];
#pragma unroll
  for (int j = 0; j < 8; ++j) { ax[j] = 0.f; ay[j] = 0.f; }
  // rows tg*8 .. tg*8+39 cover taps k=0..32 for the 8 tokens tg*8+j
#pragma unroll
  for (int rr = 0; rr < 40; ++rr) {
    float2 v = *(float2*)&vS[tg * 8 + rr][d2];
#pragma unroll
    for (int j = 0; j < 8; ++j) {
      int k = rr - j;
      if (k >= 0 && k < 33) {
        ax[j] += w33[k] * v.x;
        ay[j] += w33[k] * v.y;
      }
    }
  }
#pragma unroll
  for (int j = 0; j < 8; ++j) {
    size_t off = ((size_t)b * NPAD + n0 + tg * 8 + j) * DD + h * 64 + d2;
    unsigned u = *(unsigned*)(attf + off);
    float x0 = f16f(u) + ax[j];
    float x1 = f16f(u >> 16) + ay[j];
    *(unsigned*)(attf + off) = pk_f16(x0, x1);
  }
}

// ---------------------------------------------------------------- PPEG (combined 7x7)
__global__ __launch_bounds__(128) void k_ppeg(
    float* __restrict__ hB, const float* __restrict__ hA,
    const float* __restrict__ w7, const float* __restrict__ b7,
    const float* __restrict__ w5, const float* __restrict__ b5,
    const float* __restrict__ w3, const float* __restrict__ b3) {
  __shared__ float cw[49][128];
  int t = threadIdx.x;
  int i = blockIdx.x >> 2;
  int j0 = (blockIdx.x & 3) * 32;
  int cg = blockIdx.y, b = blockIdx.z;
  int c = cg * 128 + t;
#pragma unroll
  for (int k = 0; k < 49; ++k) cw[k][t] = w7[c * 49 + k];
#pragma unroll
  for (int di = 0; di < 5; ++di)
#pragma unroll
    for (int dj = 0; dj < 5; ++dj)
      cw[(di + 1) * 7 + dj + 1][t] += w5[c * 25 + di * 5 + dj];
#pragma unroll
  for (int di = 0; di < 3; ++di)
#pragma unroll
    for (int dj = 0; dj < 3; ++dj)
      cw[(di + 2) * 7 + dj + 2][t] += w3[c * 9 + di * 3 + dj];
  cw[24][t] += 1.0f;
  float bias = b7[c] + b5[c] + b3[c];
  const float* base = hA + (size_t)b * TT * DD + DD + c;
  float* obase = hB + (size_t)b * TT * DD + DD + c;
  float acc[32];
#pragma unroll
  for (int j = 0; j < 32; ++j) acc[j] = bias;
  for (int di = 0; di < 7; ++di) {
    int ii = i + di - 3;
    if ((unsigned)ii >= 128u) continue;
    float win[38];
#pragma unroll
    for (int w = 0; w < 38; ++w) {
      int col = j0 - 3 + w;
      win[w] = ((unsigned)col < 128u) ? base[(size_t)(ii * 128 + col) * DD] : 0.f;
    }
#pragma unroll
    for (int dj = 0; dj < 7; ++dj) {
      float wv = cw[di * 7 + dj][t];
#pragma unroll
      for (int j = 0; j < 32; ++j) acc[j] += win[j + dj] * wv;
    }
  }
#pragma unroll
  for (int j = 0; j < 32; ++j) obase[(size_t)(i * 128 + j0 + j) * DD] = acc[j];
}

// ---------------------------------------------------------------- final head
__global__ __launch_bounds__(512) void k_final(
    float* __restrict__ out, const float* __restrict__ h,
    const float* __restrict__ g, const float* __restrict__ be,
    const float* __restrict__ cw, const float* __restrict__ cbias) {
  __shared__ float sm[16];
  int t = threadIdx.x;
  for (int b = 0; b < 2; ++b) {
    const float* row = h + (size_t)b * TT * DD;
    float x = row[t];
    float s = x;
    for (int o = 32; o; o >>= 1) s += __shfl_xor(s, o);
    if ((t & 63) == 0) sm[t >> 6] = s;
    __syncthreads();
    float mu = 0.f;
    for (int i = 0; i < 8; ++i) mu += sm[i];
    mu *= (1.f / 512.f);
    __syncthreads();
    float d = x - mu;
    s = d * d;
    for (int o = 32; o; o >>= 1) s += __shfl_xor(s, o);
    if ((t & 63) == 0) sm[t >> 6] = s;
    __syncthreads();
    float var = 0.f;
    for (int i = 0; i < 8; ++i) var += sm[i];
    var *= (1.f / 512.f);
    float rs = rsqrtf(var + 1e-5f);
    __syncthreads();
    float f = d * rs * g[t] + be[t];
    float p0 = f * cw[2 * t], p1 = f * cw[2 * t + 1];
    for (int o = 32; o; o >>= 1) {
      p0 += __shfl_xor(p0, o);
      p1 += __shfl_xor(p1, o);
    }
    if ((t & 63) == 0) {
      sm[t >> 6] = p0;
      sm[8 + (t >> 6)] = p1;
    }
    __syncthreads();
    if (t == 0) {
      float q0 = 0.f, q1 = 0.f;
      for (int i = 0; i < 8; ++i) {
        q0 += sm[i];
        q1 += sm[8 + i];
      }
      out[b * 2 + 0] = q0 + cbias[0];
      out[b * 2 + 1] = q1 + cbias[1];
    }
    __syncthreads();
  }
}

// ---------------------------------------------------------------- host side
static void run_attn(float* h, const float* lng, const float* lnb,
                     const float* wqkv, const float* wout, const float* bout,
                     const float* resw, float* xp, unsigned short* qkvh, float* ql,
                     float* kl, float* a2, float* z0, float* z1, float* xz, float* xz2,
                     float* yB, float* yC, float* bv, float* w2, float* red,
                     float* Sbuf, unsigned short* wth, hipStream_t stream) {
  // xp region: [f16 hi/lo planes for LN output], later [f16 attout in hi plane]
  unsigned short* xph = (unsigned short*)xp;
  unsigned short* xpl = xph + (size_t)BB * NPAD * DD;
  k_zero_pad<<<BB * PADF, 256, 0, stream>>>(xph, xpl);
  k_ln_pad<<<(BB * TT + 3) / 4, 256, 0, stream>>>(xph, xpl, h, lng, lnb);
  k_cvt_wt<<<dim3(DD / 32, 1536 / 32), 256, 0, stream>>>(wqkv, wth, DD, 1536);
  k_gemm_qkv8<<<dim3(BB * NPAD / 128, 1536 / 256), 512, 0, stream>>>(xph, xpl, wth,
                                                                     qkvh);
  k_landmarks<<<1024, 256, 0, stream>>>(ql, kl, qkvh);
  float* pacc = Sbuf;
  float* pL = Sbuf + (size_t)A3KC * 4096 * 64;
  k_a3v_mfma<<<dim3(16, A3KC), 256, 0, stream>>>(pacc, pL, ql, qkvh);
  k_a3v_red<<<4096, 64, 0, stream>>>(bv, pacc, pL);
  k_sim2<<<dim3(4, 4, 16), 256, 0, stream>>>(a2, ql, kl);
  k_softmax256<<<1024, 256, 0, stream>>>(a2);
  k_pinv_sums<<<16, 256, 0, stream>>>(red, a2);
  k_pinv_scale<<<1, 256, 0, stream>>>(red);
  k_zinit<<<dim3(256, 16), 256, 0, stream>>>(z0, a2, red);
  // Newton-Schulz: 3 matmuls/iter via P = a2@z carried forward
  float* zc = z0;
  float* zn = z1;
  float* P = xz;
  float* Pn = xz2;
  // P0 = a2 @ z0
  k_bmm_poly<<<dim3(4, 4, 16), 256, 0, stream>>>(a2, zc, nullptr, P, 1.f, 0.f, 0.f, 256);
  for (int it = 0; it < 6; ++it) {
    // yB = P@P + 15I - 7P   (== 15I - P@(7I - P))
    k_bmm_poly<<<dim3(4, 4, 16), 256, 0, stream>>>(P, P, P, yB, 1.f, 15.f, -7.f, 256);
    // yC = 13I - P@yB
    k_bmm_poly<<<dim3(4, 4, 16), 256, 0, stream>>>(P, yB, nullptr, yC, -1.f, 13.f, 0.f, 256);
    // zn = 0.25 zc@yC ; Pn = 0.25 P@yC  (batched)
    k_bmm_dual<<<dim3(4, 4, 32), 256, 0, stream>>>(zc, P, yC, zn, Pn, 0.25f);
    float* tmp = zc; zc = zn; zn = tmp;
    tmp = P; P = Pn; Pn = tmp;
  }
  k_bmm_poly<<<dim3(1, 4, 16), 256, 0, stream>>>(zc, bv, nullptr, w2, 1.f, 0.f, 0.f, 64);
  // attention output as single f16 in xph (LN planes are dead after qkv GEMM)
  k_att1<<<dim3(NPAD / 256, 16), 256, 0, stream>>>(xph, qkvh, kl, w2);
  k_convres<<<dim3(NPAD / 64, 16), 256, 0, stream>>>(xph, qkvh, resw);
  k_cvt_wt<<<dim3(DD / 32, DD / 32), 256, 0, stream>>>(wout, wth, DD, DD);
  k_gemm_proj<<<dim3(129, 2, BB), 512, 0, stream>>>(xph, wth, h, bout);
}

extern "C" void kernel_launch(void* const* d_in, const int* in_sizes, int n_in,
                              void* d_out, int out_size, void* d_ws, size_t ws_size,
                              hipStream_t stream) {
  const float* x        = (const float*)d_in[0];
  const float* w_feat   = (const float*)d_in[1];
  const float* b_feat   = (const float*)d_in[2];
  const float* cls_tok  = (const float*)d_in[3];
  const float* ln1_g    = (const float*)d_in[4];
  const float* ln1_b    = (const float*)d_in[5];
  const float* qkv1     = (const float*)d_in[6];
  const float* out1_w   = (const float*)d_in[7];
  const float* out1_b   = (const float*)d_in[8];
  const float* res1_w   = (const float*)d_in[9];
  const float* ppeg_w7  = (const float*)d_in[10];
  const float* ppeg_b7  = (const float*)d_in[11];
  const float* ppeg_w5  = (const float*)d_in[12];
  const float* ppeg_b5  = (const float*)d_in[13];
  const float* ppeg_w3  = (const float*)d_in[14];
  const float* ppeg_b3  = (const float*)d_in[15];
  const float* ln2_g    = (const float*)d_in[16];
  const float* ln2_b    = (const float*)d_in[17];
  const float* qkv2     = (const float*)d_in[18];
  const float* out2_w   = (const float*)d_in[19];
  const float* out2_b   = (const float*)d_in[20];
  const float* res2_w   = (const float*)d_in[21];
  const float* lnf_g    = (const float*)d_in[22];
  const float* lnf_b    = (const float*)d_in[23];
  const float* cls_w    = (const float*)d_in[24];
  const float* cls_b    = (const float*)d_in[25];

  float* ws = (float*)d_ws;
  size_t off = 0;
  float* hA  = ws + off; off += (size_t)BB * TT * DD;
  float* hB  = ws + off; off += (size_t)BB * TT * DD;
  float* xp  = ws + off; off += (size_t)BB * NPAD * DD;
  float* qkvf = ws + off; off += (size_t)BB * NPAD * 3 * DD;  // used as f16 (half)
  unsigned short* qkvh = (unsigned short*)qkvf;
  float* ql  = ws + off; off += (size_t)BB * HH * 256 * 64;
  float* kl  = ws + off; off += (size_t)BB * HH * 256 * 64;
  float* a2  = ws + off; off += (size_t)16 * 65536;
  float* z0  = ws + off; off += (size_t)16 * 65536;
  float* z1  = ws + off; off += (size_t)16 * 65536;
  float* xz  = ws + off; off += (size_t)16 * 65536;
  float* xz2 = ws + off; off += (size_t)16 * 65536;
  float* yB  = ws + off; off += (size_t)16 * 65536;
  float* yC  = ws + off; off += (size_t)16 * 65536;
  float* bv  = ws + off; off += (size_t)BB * HH * 256 * 64;
  float* w2  = ws + off; off += (size_t)BB * HH * 256 * 64;
  float* red = ws + off; off += 8448;
  unsigned short* wth = (unsigned short*)(ws + off); off += 393216;

  // Stage 1: h = gelu(x @ w_feat + b_feat), prepend cls token
  k_set_cls<<<2, 512, 0, stream>>>(hA, cls_tok);
  k_cvt_wt<<<dim3(1024 / 32, DD / 32), 256, 0, stream>>>(w_feat, wth, 1024, DD);
  k_gemm_mfma<0><<<dim3(32768 / 128, DD / 256), 512, 0, stream>>>(
      x, nullptr, nullptr, wth, b_feat, hA, 32768, 1024, DD, 1024);
  // Attention 1 (residual in-place on hA; hB is dead -> scratch)
  run_attn(hA, ln1_g, ln1_b, qkv1, out1_w, out1_b, res1_w, xp, qkvh, ql, kl, a2, z0, z1,
           xz, xz2, yB, yC, bv, w2, red, hB, wth, stream);
  // PPEG: hB = ppeg(hA)
  k_copy_cls<<<2, 512, 0, stream>>>(hB, hA);
  k_ppeg<<<dim3(512, 4, 2), 128, 0, stream>>>(hB, hA, ppeg_w7, ppeg_b7, ppeg_w5, ppeg_b5,
                                              ppeg_w3, ppeg_b3);
  // Attention 2 (residual in-place on hB; hA is dead -> scratch)
  run_attn(hB, ln2_g, ln2_b, qkv2, out2_w, out2_b, res2_w, xp, qkvh, ql, kl, a2, z0, z1,
           xz, xz2, yB, yC, bv, w2, red, hA, wth, stream);
  // Final: LN(cls) @ cls_w + cls_b
  k_final<<<1, 512, 0, stream>>>((float*)d_out, hB, lnf_g, lnf_b, cls_w, cls_b);
}

// Round 23
// 1373.909 us; speedup vs baseline: 1.2345x; 1.0562x over previous
//
#include <hip/hip_runtime.h>
#include <cstdint>
#include <cstddef>

#define BB 2
#define TT 16385
#define NPAD 16640
#define DD 512
#define HH 8
#define DHH 64
#define MLAND 256
#define PADF 255
#define A3KC 26
#define A3CH 640

typedef __attribute__((ext_vector_type(8))) _Float16 f16x8;
typedef __attribute__((ext_vector_type(4))) float f32x4;

__device__ __forceinline__ float gelu_f(float v) {
  float c = 0.7978845608028654f * (v + 0.044715f * v * v * v);
  return 0.5f * v * (1.0f + tanhf(c));
}

__device__ __forceinline__ unsigned short f16_1(float a) {
  _Float16 h = (_Float16)a;
  return __builtin_bit_cast(unsigned short, h);
}
__device__ __forceinline__ float f16f(unsigned u) {
  return (float)__builtin_bit_cast(_Float16, (unsigned short)(u & 0xffffu));
}
__device__ __forceinline__ unsigned pk_f16(float a, float b) {
  return (unsigned)f16_1(a) | ((unsigned)f16_1(b) << 16);
}
// split a,b into f16 hi (packed) and f16 residual-lo (packed)
__device__ __forceinline__ void split2h(float a, float b, unsigned& hi, unsigned& lo) {
  _Float16 ah = (_Float16)a, bh = (_Float16)b;
  hi = (unsigned)__builtin_bit_cast(unsigned short, ah) |
       ((unsigned)__builtin_bit_cast(unsigned short, bh) << 16);
  lo = pk_f16(a - (float)ah, b - (float)bh);
}

// async global->LDS 16B (wave-uniform LDS base + lane*16)
__device__ __forceinline__ void gload16(const unsigned short* g, short* l) {
  __builtin_amdgcn_global_load_lds(
      (const __attribute__((address_space(1))) void*)g,
      (__attribute__((address_space(3))) void*)l, 16, 0, 0);
}

// ---------------------------------------------------------------- cls rows
__global__ void k_set_cls(float* __restrict__ h, const float* __restrict__ cls) {
  h[(size_t)blockIdx.x * TT * DD + threadIdx.x] = cls[threadIdx.x];
}
__global__ void k_copy_cls(float* __restrict__ dst, const float* __restrict__ src) {
  size_t o = (size_t)blockIdx.x * TT * DD + threadIdx.x;
  dst[o] = src[o];
}

// ------------------------------------------------ W[K][N] -> Wt f16 [N][K]
__global__ __launch_bounds__(256) void k_cvt_wt(
    const float* __restrict__ W, unsigned short* __restrict__ Wth, int K, int N) {
  __shared__ float tile[32][33];
  int kb = blockIdx.x * 32, nb = blockIdx.y * 32;
  int t = threadIdx.x;
  int tr = t >> 3, tc4 = (t & 7) * 4;
  float4 v = *(const float4*)(W + (size_t)(kb + tr) * N + nb + tc4);
  tile[tr][tc4 + 0] = v.x;
  tile[tr][tc4 + 1] = v.y;
  tile[tr][tc4 + 2] = v.z;
  tile[tr][tc4 + 3] = v.w;
  __syncthreads();
  int n = nb + tr;
  ushort4 hs;
  hs.x = f16_1(tile[tc4 + 0][tr]);
  hs.y = f16_1(tile[tc4 + 1][tr]);
  hs.z = f16_1(tile[tc4 + 2][tr]);
  hs.w = f16_1(tile[tc4 + 3][tr]);
  *(ushort4*)(Wth + (size_t)n * K + kb + tc4) = hs;
}

// ---------------- fp32-via-2xf16 MFMA GEMM, 128x256 tile, 8 waves (512 thr)
// (MODE 0 feat-gelu only; qkv uses k_gemm_qkv8, proj uses k_gemm_proj)
template <int MODE>
__global__ __launch_bounds__(512) void k_gemm_mfma(
    const float* __restrict__ A, const unsigned short* __restrict__ Aph,
    const unsigned short* __restrict__ Apl, const unsigned short* __restrict__ Wth,
    const float* __restrict__ bias, void* __restrict__ Cv, int M, int K, int N,
    int lda) {
  __shared__ short Ash[128][44];
  __shared__ short Asl[128][44];
  __shared__ short Bsh[256][44];
  const int t = threadIdx.x;
  // bijective swizzle over (gridDim.x row-tiles) x (gridDim.y col-tiles)
  int nRow = gridDim.x, nCol = gridDim.y;
  int lin = blockIdx.x + blockIdx.y * nRow;
  int chunk = 8 * nCol;
  int group = lin / chunk;
  int rem = lin - group * chunk;
  int gbase = group * 8;
  int Geff = nRow - gbase;
  if (Geff > 8) Geff = 8;
  const int rb = (gbase + rem % Geff) * 128;
  const int cb = (rem / Geff) * 256;
  const float* Ab = A;
  float* Cf = (float*)Cv;
  unsigned short* Ch = (unsigned short*)Cv;
  if (MODE == 2) {
    int b = blockIdx.z;
    Ab = A + (size_t)b * NPAD * DD + (size_t)PADF * DD;
    Cf = (float*)Cv + (size_t)b * TT * DD;
  }
  const int lane = t & 63, wv = t >> 6;
  const int wr = wv >> 2, wc = wv & 3;
  const int fr = lane & 15, kg = lane >> 4;
  const int srow = t >> 2, skh = (t & 3) * 8;   // A: 8 shorts / thread / plane
  const int brow = t >> 1, bkh = (t & 1) * 16;  // B: 16 shorts / thread

  f32x4 acc[4][4];
  f32x4 zero4 = {0.f, 0.f, 0.f, 0.f};
#pragma unroll
  for (int i = 0; i < 4; ++i)
#pragma unroll
    for (int j = 0; j < 4; ++j) acc[i][j] = zero4;

  for (int k0 = 0; k0 < K; k0 += 32) {
    __syncthreads();
    if (MODE == 1) {
      const unsigned short* ph = Aph + (size_t)(rb + srow) * lda + k0 + skh;
      const unsigned short* pl = Apl + (size_t)(rb + srow) * lda + k0 + skh;
      *(uint4*)&Ash[srow][skh] = *(const uint4*)ph;
      *(uint4*)&Asl[srow][skh] = *(const uint4*)pl;
    } else {
      int grow = rb + srow;
      float4 f0 = {0, 0, 0, 0}, f1 = {0, 0, 0, 0};
      if (grow < M) {
        const float* p = Ab + (size_t)grow * lda + k0 + skh;
        f0 = *(const float4*)p;
        f1 = *(const float4*)(p + 4);
      }
      unsigned h0, h1, h2, h3, l0, l1, l2, l3;
      split2h(f0.x, f0.y, h0, l0);
      split2h(f0.z, f0.w, h1, l1);
      split2h(f1.x, f1.y, h2, l2);
      split2h(f1.z, f1.w, h3, l3);
      *(uint4*)&Ash[srow][skh] = make_uint4(h0, h1, h2, h3);
      *(uint4*)&Asl[srow][skh] = make_uint4(l0, l1, l2, l3);
    }
    {
      const unsigned short* ph = Wth + (size_t)(cb + brow) * K + k0 + bkh;
      *(uint4*)&Bsh[brow][bkh] = *(const uint4*)ph;
      *(uint4*)&Bsh[brow][bkh + 8] = *(const uint4*)(ph + 8);
    }
    __syncthreads();
    f16x8 ah[4], al[4];
#pragma unroll
    for (int mf = 0; mf < 4; ++mf) {
      ah[mf] = *(const f16x8*)&Ash[wr * 64 + mf * 16 + fr][kg * 8];
      al[mf] = *(const f16x8*)&Asl[wr * 64 + mf * 16 + fr][kg * 8];
    }
#pragma unroll
    for (int nf = 0; nf < 4; ++nf) {
      f16x8 bhf = *(const f16x8*)&Bsh[wc * 64 + nf * 16 + fr][kg * 8];
#pragma unroll
      for (int mf = 0; mf < 4; ++mf) {
        acc[mf][nf] =
            __builtin_amdgcn_mfma_f32_16x16x32_f16(ah[mf], bhf, acc[mf][nf], 0, 0, 0);
        acc[mf][nf] =
            __builtin_amdgcn_mfma_f32_16x16x32_f16(al[mf], bhf, acc[mf][nf], 0, 0, 0);
      }
    }
  }
#pragma unroll
  for (int mf = 0; mf < 4; ++mf) {
#pragma unroll
    for (int r = 0; r < 4; ++r) {
      int row = rb + wr * 64 + mf * 16 + kg * 4 + r;
      if (MODE == 2 && row >= M) continue;
      size_t orow = (MODE == 0) ? (size_t)(row + (row >> 14) + 1) : (size_t)row;
#pragma unroll
      for (int nf = 0; nf < 4; ++nf) {
        int col = cb + wc * 64 + nf * 16 + fr;
        float v = acc[mf][nf][r];
        if (MODE == 0) {
          Cf[orow * DD + col] = gelu_f(v + bias[col]);
        } else if (MODE == 1) {
          Ch[orow * (size_t)N + col] = f16_1(v);
        } else {
          float old = Cf[orow * DD + col];
          Cf[orow * DD + col] = old + v + bias[col];
        }
      }
    }
  }
}

// ---------------- qkv GEMM: pipelined, single-f16 A (LN output), f16 out
// BK=32, dbuf LDS 48KB -> 3 blocks/CU, 2-deep prefetch, vmcnt(3), XOR swizzle.
// (A operand single-f16: qkv output is f16 anyway, split-lo adds no precision)
__global__ __launch_bounds__(512) void k_gemm_qkv8(
    const unsigned short* __restrict__ Aph, const unsigned short* __restrict__ Wth,
    unsigned short* __restrict__ Ch) {
  __shared__ __align__(16) short Ah[2][128][32];
  __shared__ __align__(16) short Bs[2][256][32];
  const int t = threadIdx.x;
  // L2 block swizzle
  int nRow = gridDim.x, nCol = gridDim.y;
  int lin = blockIdx.x + blockIdx.y * nRow;
  int chunk = 8 * nCol;
  int group = lin / chunk;
  int rem = lin - group * chunk;
  int gbase = group * 8;
  int Geff = nRow - gbase;
  if (Geff > 8) Geff = 8;
  const int rb = (gbase + rem % Geff) * 128;
  const int cb = (rem / Geff) * 256;
  const int lane = t & 63, wv = t >> 6;
  const int wr = wv >> 2, wc = wv & 3;
  const int fr = lane & 15, kg = lane >> 4;
  const int lr4 = lane >> 2;                       // row-in-16 within a gload
  const int ss = (lane & 3) ^ (lr4 & 3);           // pre-swizzled src slot (16B)

  f32x4 acc[4][4];
  f32x4 zero4 = {0.f, 0.f, 0.f, 0.f};
#pragma unroll
  for (int i = 0; i < 4; ++i)
#pragma unroll
    for (int j = 0; j < 4; ++j) acc[i][j] = zero4;

  // stage K-step kt (K=32) into buffer bf: 3 gloads/wave (A 1, B 2)
  auto STAGE = [&](int kt, int bf) {
    const int k0 = kt * 32;
    {
      int lr = wv * 16;
      gload16(Aph + (size_t)(rb + lr + lr4) * DD + k0 + ss * 8, &Ah[bf][lr][0]);
    }
#pragma unroll
    for (int j = 0; j < 2; ++j) {
      int lr = wv * 32 + j * 16;
      gload16(Wth + (size_t)(cb + lr + lr4) * DD + k0 + ss * 8, &Bs[bf][lr][0]);
    }
  };

  STAGE(0, 0);
  STAGE(1, 1);
  const int sl = ((kg ^ (fr & 3))) * 8;  // swizzled read slot (shorts)
  for (int kt = 0; kt < 16; ++kt) {
    if (kt < 15) {
      asm volatile("s_waitcnt vmcnt(3)" ::: "memory");  // own tile-kt loads done
    } else {
      asm volatile("s_waitcnt vmcnt(0)" ::: "memory");  // final drain
    }
    __builtin_amdgcn_sched_barrier(0);
    __builtin_amdgcn_s_barrier();  // all waves' tile-kt data in LDS
    const int bf = kt & 1;
    f16x8 ah[4];
#pragma unroll
    for (int mf = 0; mf < 4; ++mf)
      ah[mf] = *(const f16x8*)&Ah[bf][wr * 64 + mf * 16 + fr][sl];
#pragma unroll
    for (int nf = 0; nf < 4; ++nf) {
      f16x8 bhf = *(const f16x8*)&Bs[bf][wc * 64 + nf * 16 + fr][sl];
#pragma unroll
      for (int mf = 0; mf < 4; ++mf)
        acc[mf][nf] =
            __builtin_amdgcn_mfma_f32_16x16x32_f16(ah[mf], bhf, acc[mf][nf], 0, 0, 0);
    }
    __builtin_amdgcn_s_barrier();  // all waves done reading buf bf
    if (kt + 2 < 16) STAGE(kt + 2, bf);
  }
#pragma unroll
  for (int mf = 0; mf < 4; ++mf) {
#pragma unroll
    for (int r = 0; r < 4; ++r) {
      int row = rb + wr * 64 + mf * 16 + kg * 4 + r;
#pragma unroll
      for (int nf = 0; nf < 4; ++nf) {
        int col = cb + wc * 64 + nf * 16 + fr;
        Ch[(size_t)row * 1536 + col] = f16_1(acc[mf][nf][r]);
      }
    }
  }
}

// ---------------- proj GEMM: pipelined, single-f16 A (attf), fp32 residual out
// BK=32, dbuf LDS 48KB -> 3 blocks/CU, 2-deep prefetch, vmcnt(3), XOR swizzle.
__global__ __launch_bounds__(512) void k_gemm_proj(
    const unsigned short* __restrict__ Af, const unsigned short* __restrict__ Wth,
    float* __restrict__ Cb, const float* __restrict__ bias) {
  __shared__ __align__(16) short Ah[2][128][32];
  __shared__ __align__(16) short Bs[2][256][32];
  const int t = threadIdx.x;
  int nRow = gridDim.x, nCol = gridDim.y;
  int lin = blockIdx.x + blockIdx.y * nRow;
  int chunk = 8 * nCol;
  int group = lin / chunk;
  int rem = lin - group * chunk;
  int gbase = group * 8;
  int Geff = nRow - gbase;
  if (Geff > 8) Geff = 8;
  const int rb = (gbase + rem % Geff) * 128;
  const int cb = (rem / Geff) * 256;
  const int lane = t & 63, wv = t >> 6;
  const int wr = wv >> 2, wc = wv & 3;
  const int fr = lane & 15, kg = lane >> 4;
  const int lr4 = lane >> 2;
  const int ss = (lane & 3) ^ (lr4 & 3);
  const size_t arow0 = (size_t)blockIdx.z * NPAD + PADF + rb;

  f32x4 acc[4][4];
  f32x4 zero4 = {0.f, 0.f, 0.f, 0.f};
#pragma unroll
  for (int i = 0; i < 4; ++i)
#pragma unroll
    for (int j = 0; j < 4; ++j) acc[i][j] = zero4;

  // stage K-step kt (K=32) into buffer bf: 3 gloads/wave (A 1, B 2)
  auto STAGE = [&](int kt, int bf) {
    const int k0 = kt * 32;
    {
      int lr = wv * 16;
      gload16(Af + (arow0 + lr + lr4) * DD + k0 + ss * 8, &Ah[bf][lr][0]);
    }
#pragma unroll
    for (int j = 0; j < 2; ++j) {
      int lr = wv * 32 + j * 16;
      gload16(Wth + (size_t)(cb + lr + lr4) * DD + k0 + ss * 8, &Bs[bf][lr][0]);
    }
  };

  STAGE(0, 0);
  STAGE(1, 1);
  const int sl = ((kg ^ (fr & 3))) * 8;
  for (int kt = 0; kt < 16; ++kt) {
    if (kt < 15) {
      asm volatile("s_waitcnt vmcnt(3)" ::: "memory");
    } else {
      asm volatile("s_waitcnt vmcnt(0)" ::: "memory");
    }
    __builtin_amdgcn_sched_barrier(0);
    __builtin_amdgcn_s_barrier();
    const int bf = kt & 1;
    f16x8 ah[4];
#pragma unroll
    for (int mf = 0; mf < 4; ++mf)
      ah[mf] = *(const f16x8*)&Ah[bf][wr * 64 + mf * 16 + fr][sl];
#pragma unroll
    for (int nf = 0; nf < 4; ++nf) {
      f16x8 bhf = *(const f16x8*)&Bs[bf][wc * 64 + nf * 16 + fr][sl];
#pragma unroll
      for (int mf = 0; mf < 4; ++mf)
        acc[mf][nf] =
            __builtin_amdgcn_mfma_f32_16x16x32_f16(ah[mf], bhf, acc[mf][nf], 0, 0, 0);
    }
    __builtin_amdgcn_s_barrier();
    if (kt + 2 < 16) STAGE(kt + 2, bf);
  }
  float* Cf = Cb + (size_t)blockIdx.z * TT * DD;
#pragma unroll
  for (int mf = 0; mf < 4; ++mf) {
#pragma unroll
    for (int r = 0; r < 4; ++r) {
      int row = rb + wr * 64 + mf * 16 + kg * 4 + r;
      if (row >= TT) continue;
#pragma unroll
      for (int nf = 0; nf < 4; ++nf) {
        int col = cb + wc * 64 + nf * 16 + fr;
        float old = Cf[(size_t)row * DD + col];
        Cf[(size_t)row * DD + col] = old + acc[mf][nf][r] + bias[col];
      }
    }
  }
}

// ------------------------- LN + pad -> writes single f16 plane (qkv A operand)
__global__ __launch_bounds__(256) void k_ln_pad(
    unsigned short* __restrict__ xph, const float* __restrict__ h,
    const float* __restrict__ gam, const float* __restrict__ bet) {
  int w = threadIdx.x >> 6, lane = threadIdx.x & 63;
  int row = blockIdx.x * 4 + w;
  if (row >= BB * TT) return;
  int b = row / TT, i = row - b * TT;
  const float* src = h + (size_t)row * DD;
  float4 x0 = *(const float4*)(src + lane * 4);
  float4 x1 = *(const float4*)(src + 256 + lane * 4);
  float s = x0.x + x0.y + x0.z + x0.w + x1.x + x1.y + x1.z + x1.w;
  for (int o = 32; o; o >>= 1) s += __shfl_xor(s, o);
  float mu = s * (1.f / 512.f);
  float q = (x0.x - mu) * (x0.x - mu) + (x0.y - mu) * (x0.y - mu) +
            (x0.z - mu) * (x0.z - mu) + (x0.w - mu) * (x0.w - mu) +
            (x1.x - mu) * (x1.x - mu) + (x1.y - mu) * (x1.y - mu) +
            (x1.z - mu) * (x1.z - mu) + (x1.w - mu) * (x1.w - mu);
  for (int o = 32; o; o >>= 1) q += __shfl_xor(q, o);
  float rs = rsqrtf(q * (1.f / 512.f) + 1e-5f);
  float4 g0 = *(const float4*)(gam + lane * 4);
  float4 g1 = *(const float4*)(gam + 256 + lane * 4);
  float4 b0 = *(const float4*)(bet + lane * 4);
  float4 b1 = *(const float4*)(bet + 256 + lane * 4);
  float4 o0, o1;
  o0.x = (x0.x - mu) * rs * g0.x + b0.x;
  o0.y = (x0.y - mu) * rs * g0.y + b0.y;
  o0.z = (x0.z - mu) * rs * g0.z + b0.z;
  o0.w = (x0.w - mu) * rs * g0.w + b0.w;
  o1.x = (x1.x - mu) * rs * g1.x + b1.x;
  o1.y = (x1.y - mu) * rs * g1.y + b1.y;
  o1.z = (x1.z - mu) * rs * g1.z + b1.z;
  o1.w = (x1.w - mu) * rs * g1.w + b1.w;
  size_t ro = ((size_t)b * NPAD + PADF + i) * DD;
  *(uint2*)(xph + ro + lane * 4) = make_uint2(pk_f16(o0.x, o0.y), pk_f16(o0.z, o0.w));
  *(uint2*)(xph + ro + 256 + lane * 4) =
      make_uint2(pk_f16(o1.x, o1.y), pk_f16(o1.z, o1.w));
}

__global__ void k_zero_pad(unsigned short* __restrict__ xph) {
  int r = blockIdx.x;
  int b = r / PADF, j = r - b * PADF;
  size_t ro = ((size_t)b * NPAD + j) * DD;
  ((unsigned*)(xph + ro))[threadIdx.x] = 0u;
}

// ---------------------------------------------------------------- landmarks (f16 qkv)
__global__ __launch_bounds__(256) void k_landmarks(
    float* __restrict__ ql, float* __restrict__ kl,
    const unsigned short* __restrict__ qkv) {
  int t = threadIdx.x;
  int mi = t >> 6, d = t & 63;
  int blk = blockIdx.x;
  int bh = blk >> 6, mg = blk & 63;
  int b = bh >> 3, h = bh & 7;
  int m = mg * 4 + mi;
  const unsigned short* base = qkv + (size_t)b * NPAD * 1536 + h * 64 + d;
  float sq = 0.f, sk = 0.f;
  int t0 = m * 65;
  for (int j = 0; j < 65; ++j) {
    const unsigned short* p = base + (size_t)(t0 + j) * 1536;
    sq += f16f(p[0]);
    sk += f16f(p[512]);
  }
  ql[((size_t)bh * 256 + m) * 64 + d] = sq * (0.125f / 65.f);
  kl[((size_t)bh * 256 + m) * 64 + d] = sk * (1.f / 65.f);
}

// ---------------------------------------------------------------- sim2 = ql @ kl^T
__global__ __launch_bounds__(256) void k_sim2(
    float* __restrict__ sim, const float* __restrict__ ql, const float* __restrict__ kl) {
  __shared__ __align__(16) float Aq[64][68];
  __shared__ __align__(16) float Bk[64][68];
  int t = threadIdx.x;
  int tj = blockIdx.x, ti = blockIdx.y, bh = blockIdx.z;
  int r = t >> 2, cc = (t & 3) * 16;
  const float* ap = ql + ((size_t)bh * 256 + ti * 64 + r) * 64 + cc;
  const float* bp = kl + ((size_t)bh * 256 + tj * 64 + r) * 64 + cc;
#pragma unroll
  for (int i = 0; i < 16; i += 4) {
    *(float4*)&Aq[r][cc + i] = *(const float4*)(ap + i);
    *(float4*)&Bk[r][cc + i] = *(const float4*)(bp + i);
  }
  __syncthreads();
  int tx = t & 15, ty = t >> 4;
  float acc[4][4];
#pragma unroll
  for (int i = 0; i < 4; ++i)
#pragma unroll
    for (int j = 0; j < 4; ++j) acc[i][j] = 0.f;
  for (int d = 0; d < 64; d += 4) {
    float4 a4[4], b4[4];
#pragma unroll
    for (int ii = 0; ii < 4; ++ii) a4[ii] = *(float4*)&Aq[ty * 4 + ii][d];
#pragma unroll
    for (int jj = 0; jj < 4; ++jj) b4[jj] = *(float4*)&Bk[tx * 4 + jj][d];
#pragma unroll
    for (int ii = 0; ii < 4; ++ii)
#pragma unroll
      for (int jj = 0; jj < 4; ++jj)
        acc[ii][jj] += a4[ii].x * b4[jj].x + a4[ii].y * b4[jj].y + a4[ii].z * b4[jj].z +
                       a4[ii].w * b4[jj].w;
  }
#pragma unroll
  for (int ii = 0; ii < 4; ++ii)
#pragma unroll
    for (int jj = 0; jj < 4; ++jj)
      sim[((size_t)bh * 256 + ti * 64 + ty * 4 + ii) * 256 + tj * 64 + tx * 4 + jj] =
          acc[ii][jj];
}

// ---------------------------------------------------------------- row softmax (len 256)
__global__ __launch_bounds__(256) void k_softmax256(float* __restrict__ a) {
  int w = threadIdx.x >> 6, lane = threadIdx.x & 63;
  size_t row = (size_t)blockIdx.x * 4 + w;
  float* p = a + row * 256 + lane * 4;
  float4 v = *(float4*)p;
  float m = fmaxf(fmaxf(v.x, v.y), fmaxf(v.z, v.w));
  for (int o = 32; o; o >>= 1) m = fmaxf(m, __shfl_xor(m, o));
  v.x = expf(v.x - m); v.y = expf(v.y - m);
  v.z = expf(v.z - m); v.w = expf(v.w - m);
  float s = v.x + v.y + v.z + v.w;
  for (int o = 32; o; o >>= 1) s += __shfl_xor(s, o);
  float inv = 1.f / s;
  v.x *= inv; v.y *= inv; v.z *= inv; v.w *= inv;
  *(float4*)p = v;
}

// ---------------------------------------------------------------- pinv helpers
__global__ void k_pinv_sums(float* __restrict__ red, const float* __restrict__ a2) {
  int bh = blockIdx.x, t = threadIdx.x;
  const float* Ab = a2 + (size_t)bh * 65536;
  float s = 0.f;
  for (int i = 0; i < 256; ++i) s += fabsf(Ab[(size_t)i * 256 + t]);
  red[bh * 256 + t] = s;
  float c = 0.f;
  const float* rp = Ab + (size_t)t * 256;
  for (int j = 0; j < 256; j += 4) {
    float4 v = *(const float4*)(rp + j);
    c += fabsf(v.x) + fabsf(v.y) + fabsf(v.z) + fabsf(v.w);
  }
  red[4096 + bh * 256 + t] = c;
}

__global__ void k_pinv_scale(float* __restrict__ red) {
  __shared__ float sm[8];
  int t = threadIdx.x;
  float m1 = 0.f, m2 = 0.f;
  for (int k = t; k < 4096; k += 256) {
    m1 = fmaxf(m1, red[k]);
    m2 = fmaxf(m2, red[4096 + k]);
  }
  for (int o = 32; o; o >>= 1) {
    m1 = fmaxf(m1, __shfl_xor(m1, o));
    m2 = fmaxf(m2, __shfl_xor(m2, o));
  }
  int w = t >> 6;
  if ((t & 63) == 0) { sm[w] = m1; sm[4 + w] = m2; }
  __syncthreads();
  if (t == 0) {
    float a = fmaxf(fmaxf(sm[0], sm[1]), fmaxf(sm[2], sm[3]));
    float b = fmaxf(fmaxf(sm[4], sm[5]), fmaxf(sm[6], sm[7]));
    red[8192] = 1.0f / (a * b);
  }
}

__global__ void k_zinit(float* __restrict__ z, const float* __restrict__ a2,
                        const float* __restrict__ red) {
  float s = red[8192];
  int i = blockIdx.x, bh = blockIdx.y, j = threadIdx.x;
  z[((size_t)bh * 256 + i) * 256 + j] = a2[((size_t)bh * 256 + j) * 256 + i] * s;
}

// ---- shared BK=128 f16 3-term matmul core: acc += A[i0..i0+64) @ B (256xN)
__device__ __forceinline__ void bmm_core(
    short (*Ash)[136], short (*Asl)[136], short (*Bsh)[136], short (*Bsl)[136],
    const float* __restrict__ Ab, const float* __restrict__ Bb, int i0, int j0, int N,
    int t, f32x4 (&acc)[4]) {
  const int lane = t & 63, w = t >> 6;
  const int fr = lane & 15, kg = lane >> 4;
  const int ar = t >> 2, akseg = (t & 3) * 32;  // A: 32 floats / thread
  for (int k0 = 0; k0 < 256; k0 += 128) {
    __syncthreads();
    {  // stage A rows (f16 split): 64 rows x 128 k
      const float* p = Ab + (size_t)(i0 + ar) * 256 + k0 + akseg;
#pragma unroll
      for (int q = 0; q < 4; ++q) {
        float4 f0 = *(const float4*)(p + q * 8);
        float4 f1 = *(const float4*)(p + q * 8 + 4);
        unsigned h0, h1, h2, h3, l0, l1, l2, l3;
        split2h(f0.x, f0.y, h0, l0);
        split2h(f0.z, f0.w, h1, l1);
        split2h(f1.x, f1.y, h2, l2);
        split2h(f1.z, f1.w, h3, l3);
        *(uint4*)&Ash[ar][akseg + q * 8] = make_uint4(h0, h1, h2, h3);
        *(uint4*)&Asl[ar][akseg + q * 8] = make_uint4(l0, l1, l2, l3);
      }
    }
    {  // stage B transposed (f16 split): Bsh[j_local][k_local], 128 k-rows x 64 j
#pragma unroll
      for (int pass = 0; pass < 8; ++pass) {
        int kr = pass * 16 + (t >> 4);
        int jseg = (t & 15) * 4;
        const float* p = Bb + (size_t)(k0 + kr) * N + j0 + jseg;
        float4 f = *(const float4*)p;
        float fv[4] = {f.x, f.y, f.z, f.w};
#pragma unroll
        for (int c = 0; c < 4; ++c) {
          _Float16 hh = (_Float16)fv[c];
          float lo = fv[c] - (float)hh;
          Bsh[jseg + c][kr] = (short)__builtin_bit_cast(unsigned short, hh);
          Bsl[jseg + c][kr] = (short)f16_1(lo);
        }
      }
    }
    __syncthreads();
#pragma unroll
    for (int kw = 0; kw < 4; ++kw) {
      f16x8 bhf = *(const f16x8*)&Bsh[w * 16 + fr][kw * 32 + kg * 8];
      f16x8 blf = *(const f16x8*)&Bsl[w * 16 + fr][kw * 32 + kg * 8];
#pragma unroll
      for (int mf = 0; mf < 4; ++mf) {
        f16x8 ah = *(const f16x8*)&Ash[mf * 16 + fr][kw * 32 + kg * 8];
        f16x8 al = *(const f16x8*)&Asl[mf * 16 + fr][kw * 32 + kg * 8];
        acc[mf] = __builtin_amdgcn_mfma_f32_16x16x32_f16(ah, bhf, acc[mf], 0, 0, 0);
        acc[mf] = __builtin_amdgcn_mfma_f32_16x16x32_f16(al, bhf, acc[mf], 0, 0, 0);
        acc[mf] = __builtin_amdgcn_mfma_f32_16x16x32_f16(ah, blf, acc[mf], 0, 0, 0);
      }
    }
  }
}

// ------- batched 256x256 @ 256xN; C = a1*(A@B) + d1*I + e1*E (E optional)
__global__ __launch_bounds__(256) void k_bmm_poly(
    const float* __restrict__ A, const float* __restrict__ Bm,
    const float* __restrict__ E, float* __restrict__ C, float a1, float d1, float e1,
    int N) {
  __shared__ short Ash[64][136];
  __shared__ short Asl[64][136];
  __shared__ short Bsh[64][136];
  __shared__ short Bsl[64][136];
  const int t = threadIdx.x;
  const int bh = blockIdx.z;
  const int i0 = blockIdx.y * 64, j0 = blockIdx.x * 64;
  const int lane = t & 63, w = t >> 6;
  const int fr = lane & 15, kg = lane >> 4;
  f32x4 acc[4];
  f32x4 zero4 = {0.f, 0.f, 0.f, 0.f};
#pragma unroll
  for (int i = 0; i < 4; ++i) acc[i] = zero4;
  bmm_core(Ash, Asl, Bsh, Bsl, A + (size_t)bh * 65536, Bm + (size_t)bh * 256 * N, i0,
           j0, N, t, acc);
  int j = j0 + w * 16 + fr;
#pragma unroll
  for (int mf = 0; mf < 4; ++mf) {
#pragma unroll
    for (int rr = 0; rr < 4; ++rr) {
      int i = i0 + mf * 16 + kg * 4 + rr;
      float v = acc[mf][rr];
      size_t off = (size_t)bh * 256 * N + (size_t)i * N + j;
      float out = a1 * v + ((i == j) ? d1 : 0.f);
      if (E) out += e1 * E[off];
      C[off] = out;
    }
  }
}

// ------- dual batched: z<16: C0 = s*(A0@B); z>=16: C1 = s*(A1@B)   (N=256)
__global__ __launch_bounds__(256) void k_bmm_dual(
    const float* __restrict__ A0, const float* __restrict__ A1,
    const float* __restrict__ Bm, float* __restrict__ C0, float* __restrict__ C1,
    float s) {
  __shared__ short Ash[64][136];
  __shared__ short Asl[64][136];
  __shared__ short Bsh[64][136];
  __shared__ short Bsl[64][136];
  const int t = threadIdx.x;
  const int z = blockIdx.z;
  const int bh = z & 15;
  const int sel = z >> 4;
  const float* A = sel ? A1 : A0;
  float* C = sel ? C1 : C0;
  const int i0 = blockIdx.y * 64, j0 = blockIdx.x * 64;
  const int lane = t & 63, w = t >> 6;
  const int fr = lane & 15, kg = lane >> 4;
  f32x4 acc[4];
  f32x4 zero4 = {0.f, 0.f, 0.f, 0.f};
#pragma unroll
  for (int i = 0; i < 4; ++i) acc[i] = zero4;
  bmm_core(Ash, Asl, Bsh, Bsl, A + (size_t)bh * 65536, Bm + (size_t)bh * 65536, i0, j0,
           256, t, acc);
  int j = j0 + w * 16 + fr;
#pragma unroll
  for (int mf = 0; mf < 4; ++mf) {
#pragma unroll
    for (int rr = 0; rr < 4; ++rr) {
      int i = i0 + mf * 16 + kg * 4 + rr;
      size_t off = (size_t)bh * 65536 + (size_t)i * 256 + j;
      C[off] = s * acc[mf][rr];
    }
  }
}

// -------------------------- a3 @ v : MFMA flash (f16 qkv, no-max, split-K chunks)
__global__ __launch_bounds__(256, 2) void k_a3v_mfma(
    float* __restrict__ pacc, float* __restrict__ pL,
    const float* __restrict__ ql, const unsigned short* __restrict__ qkv) {
  __shared__ short Ks[64][72];
  __shared__ short Vt[64][72];
  __shared__ short Ps[4][64][72];
  const int t = threadIdx.x;
  const int bh = blockIdx.x;
  const int kc = blockIdx.y;
  const int b = bh >> 3, h = bh & 7;
  const int lane = t & 63, w = t >> 6;
  const int fr = lane & 15, kg = lane >> 4;

  f16x8 qf[4][2];
#pragma unroll
  for (int nf = 0; nf < 4; ++nf) {
    const float* qp = ql + ((size_t)bh * 256 + w * 64 + nf * 16 + fr) * 64 + kg * 8;
#pragma unroll
    for (int kw = 0; kw < 2; ++kw) {
      float4 a = *(const float4*)(qp + kw * 32);
      float4 c = *(const float4*)(qp + kw * 32 + 4);
      uint4 uu = make_uint4(pk_f16(a.x, a.y), pk_f16(a.z, a.w), pk_f16(c.x, c.y),
                            pk_f16(c.z, c.w));
      qf[nf][kw] = *(f16x8*)&uu;
    }
  }
  f32x4 oacc[4][4];
  f32x4 zero4 = {0.f, 0.f, 0.f, 0.f};
#pragma unroll
  for (int i = 0; i < 4; ++i)
#pragma unroll
    for (int j = 0; j < 4; ++j) oacc[i][j] = zero4;
  float Lp[4] = {0.f, 0.f, 0.f, 0.f};

  const int skey = t >> 2, sd = (t & 3) * 16;
  const unsigned short* kbase = qkv + (size_t)b * NPAD * 1536 + 512 + h * 64 + sd;

  for (int it = 0; it < A3CH / 64; ++it) {
    int nt = kc * A3CH + it * 64;
    __syncthreads();
    {
      const unsigned short* kp = kbase + (size_t)(nt + skey) * 1536;
      *(uint4*)&Ks[skey][sd] = *(const uint4*)kp;
      *(uint4*)&Ks[skey][sd + 8] = *(const uint4*)(kp + 8);
      const unsigned short* vp = kp + 512;
      uint4 v01 = *(const uint4*)vp;
      uint4 v23 = *(const uint4*)(vp + 8);
      Vt[sd + 0][skey] = (short)v01.x;
      Vt[sd + 1][skey] = (short)(v01.x >> 16);
      Vt[sd + 2][skey] = (short)v01.y;
      Vt[sd + 3][skey] = (short)(v01.y >> 16);
      Vt[sd + 4][skey] = (short)v01.z;
      Vt[sd + 5][skey] = (short)(v01.z >> 16);
      Vt[sd + 6][skey] = (short)v01.w;
      Vt[sd + 7][skey] = (short)(v01.w >> 16);
      Vt[sd + 8][skey] = (short)v23.x;
      Vt[sd + 9][skey] = (short)(v23.x >> 16);
      Vt[sd + 10][skey] = (short)v23.y;
      Vt[sd + 11][skey] = (short)(v23.y >> 16);
      Vt[sd + 12][skey] = (short)v23.z;
      Vt[sd + 13][skey] = (short)(v23.z >> 16);
      Vt[sd + 14][skey] = (short)v23.w;
      Vt[sd + 15][skey] = (short)(v23.w >> 16);
    }
    __syncthreads();
    f32x4 sacc[4][4];
#pragma unroll
    for (int i = 0; i < 4; ++i)
#pragma unroll
      for (int j = 0; j < 4; ++j) sacc[i][j] = zero4;
#pragma unroll
    for (int kw = 0; kw < 2; ++kw) {
      f16x8 kf[4];
#pragma unroll
      for (int mf = 0; mf < 4; ++mf)
        kf[mf] = *(const f16x8*)&Ks[mf * 16 + fr][kw * 32 + kg * 8];
#pragma unroll
      for (int mf = 0; mf < 4; ++mf)
#pragma unroll
        for (int nf = 0; nf < 4; ++nf)
          sacc[mf][nf] = __builtin_amdgcn_mfma_f32_16x16x32_f16(kf[mf], qf[nf][kw],
                                                                sacc[mf][nf], 0, 0, 0);
    }
#pragma unroll
    for (int mf = 0; mf < 4; ++mf)
#pragma unroll
      for (int nf = 0; nf < 4; ++nf) {
        f32x4 s = sacc[mf][nf];
        float p0 = __expf(s[0]);
        float p1 = __expf(s[1]);
        float p2 = __expf(s[2]);
        float p3 = __expf(s[3]);
        Lp[nf] += (p0 + p1) + (p2 + p3);
        uint2 pw = make_uint2(pk_f16(p0, p1), pk_f16(p2, p3));
        *(uint2*)&Ps[w][nf * 16 + fr][mf * 16 + kg * 4] = pw;
      }
    __syncthreads();
#pragma unroll
    for (int kw = 0; kw < 2; ++kw) {
      f16x8 vf[4], pf[4];
#pragma unroll
      for (int mf = 0; mf < 4; ++mf)
        vf[mf] = *(const f16x8*)&Vt[mf * 16 + fr][kw * 32 + kg * 8];
#pragma unroll
      for (int nf = 0; nf < 4; ++nf)
        pf[nf] = *(const f16x8*)&Ps[w][nf * 16 + fr][kw * 32 + kg * 8];
#pragma unroll
      for (int mf = 0; mf < 4; ++mf)
#pragma unroll
        for (int nf = 0; nf < 4; ++nf)
          oacc[mf][nf] = __builtin_amdgcn_mfma_f32_16x16x32_f16(vf[mf], pf[nf],
                                                                oacc[mf][nf], 0, 0, 0);
    }
  }
  size_t obase = ((size_t)kc * 16 + bh) * 256;
#pragma unroll
  for (int mf = 0; mf < 4; ++mf)
#pragma unroll
    for (int nf = 0; nf < 4; ++nf) {
      int lm = w * 64 + nf * 16 + fr;
      *(f32x4*)(pacc + (obase + lm) * 64 + mf * 16 + kg * 4) = oacc[mf][nf];
    }
#pragma unroll
  for (int nf = 0; nf < 4; ++nf) {
    Lp[nf] += __shfl_xor(Lp[nf], 16);
    Lp[nf] += __shfl_xor(Lp[nf], 32);
  }
  if (lane < 16) {
#pragma unroll
    for (int nf = 0; nf < 4; ++nf)
      pL[obase + w * 64 + nf * 16 + lane] = Lp[nf];
  }
}

__global__ __launch_bounds__(64) void k_a3v_red(
    float* __restrict__ bv, const float* __restrict__ pacc,
    const float* __restrict__ pL) {
  int row = blockIdx.x;
  int d = threadIdx.x;
  float A = 0.f, L = 0.f;
#pragma unroll
  for (int c = 0; c < A3KC; ++c) {
    size_t pr = (size_t)c * 4096 + row;
    A += pacc[pr * 64 + d];
    L += pL[pr];
  }
  bv[(size_t)row * 64 + d] = A / L;
}

// ------------- fused sim1: softmax(q @ (0.125*kl)^T) @ w2 -> single f16 attout
__global__ __launch_bounds__(256, 2) void k_att1(
    unsigned short* __restrict__ attf, const unsigned short* __restrict__ qkv,
    const float* __restrict__ kl, const float* __restrict__ w2) {
  __shared__ short KLs[64][72];
  __shared__ short W2t[64][72];
  __shared__ short Ps[4][64][72];
  const int t = threadIdx.x;
  const int tile = blockIdx.x, bh = blockIdx.y;
  const int b = bh >> 3, h = bh & 7;
  const int lane = t & 63, w = t >> 6;
  const int fr = lane & 15, kg = lane >> 4;
  const int n0 = tile * 256;

  f16x8 qf[4][2];
#pragma unroll
  for (int nf = 0; nf < 4; ++nf) {
    const unsigned short* qp =
        qkv + ((size_t)b * NPAD + n0 + w * 64 + nf * 16 + fr) * 1536 + h * 64 + kg * 8;
    qf[nf][0] = *(const f16x8*)qp;
    qf[nf][1] = *(const f16x8*)(qp + 32);
  }
  f32x4 oacc[4][4];
  f32x4 zero4 = {0.f, 0.f, 0.f, 0.f};
#pragma unroll
  for (int i = 0; i < 4; ++i)
#pragma unroll
    for (int j = 0; j < 4; ++j) oacc[i][j] = zero4;
  float Lp[4] = {0.f, 0.f, 0.f, 0.f};

  const int sr = t >> 2, sc = (t & 3) * 16;
  for (int cb = 0; cb < 4; ++cb) {
    __syncthreads();
    {
      const float* kp = kl + ((size_t)bh * 256 + cb * 64 + sr) * 64 + sc;
      float4 k0 = *(const float4*)kp;
      float4 k1 = *(const float4*)(kp + 4);
      float4 k2 = *(const float4*)(kp + 8);
      float4 k3 = *(const float4*)(kp + 12);
      *(uint4*)&KLs[sr][sc] =
          make_uint4(pk_f16(k0.x * 0.125f, k0.y * 0.125f),
                     pk_f16(k0.z * 0.125f, k0.w * 0.125f),
                     pk_f16(k1.x * 0.125f, k1.y * 0.125f),
                     pk_f16(k1.z * 0.125f, k1.w * 0.125f));
      *(uint4*)&KLs[sr][sc + 8] =
          make_uint4(pk_f16(k2.x * 0.125f, k2.y * 0.125f),
                     pk_f16(k2.z * 0.125f, k2.w * 0.125f),
                     pk_f16(k3.x * 0.125f, k3.y * 0.125f),
                     pk_f16(k3.z * 0.125f, k3.w * 0.125f));
      const float* wp = w2 + ((size_t)bh * 256 + cb * 64 + sr) * 64 + sc;
      float4 v0 = *(const float4*)wp;
      float4 v1 = *(const float4*)(wp + 4);
      float4 v2 = *(const float4*)(wp + 8);
      float4 v3 = *(const float4*)(wp + 12);
      W2t[sc + 0][sr] = (short)f16_1(v0.x);
      W2t[sc + 1][sr] = (short)f16_1(v0.y);
      W2t[sc + 2][sr] = (short)f16_1(v0.z);
      W2t[sc + 3][sr] = (short)f16_1(v0.w);
      W2t[sc + 4][sr] = (short)f16_1(v1.x);
      W2t[sc + 5][sr] = (short)f16_1(v1.y);
      W2t[sc + 6][sr] = (short)f16_1(v1.z);
      W2t[sc + 7][sr] = (short)f16_1(v1.w);
      W2t[sc + 8][sr] = (short)f16_1(v2.x);
      W2t[sc + 9][sr] = (short)f16_1(v2.y);
      W2t[sc + 10][sr] = (short)f16_1(v2.z);
      W2t[sc + 11][sr] = (short)f16_1(v2.w);
      W2t[sc + 12][sr] = (short)f16_1(v3.x);
      W2t[sc + 13][sr] = (short)f16_1(v3.y);
      W2t[sc + 14][sr] = (short)f16_1(v3.z);
      W2t[sc + 15][sr] = (short)f16_1(v3.w);
    }
    __syncthreads();
    f32x4 sacc[4][4];
#pragma unroll
    for (int i = 0; i < 4; ++i)
#pragma unroll
      for (int j = 0; j < 4; ++j) sacc[i][j] = zero4;
#pragma unroll
    for (int kw = 0; kw < 2; ++kw) {
      f16x8 kf[4];
#pragma unroll
      for (int mf = 0; mf < 4; ++mf)
        kf[mf] = *(const f16x8*)&KLs[mf * 16 + fr][kw * 32 + kg * 8];
#pragma unroll
      for (int mf = 0; mf < 4; ++mf)
#pragma unroll
        for (int nf = 0; nf < 4; ++nf)
          sacc[mf][nf] = __builtin_amdgcn_mfma_f32_16x16x32_f16(kf[mf], qf[nf][kw],
                                                                sacc[mf][nf], 0, 0, 0);
    }
#pragma unroll
    for (int mf = 0; mf < 4; ++mf)
#pragma unroll
      for (int nf = 0; nf < 4; ++nf) {
        f32x4 s = sacc[mf][nf];
        float p0 = __expf(s[0]);
        float p1 = __expf(s[1]);
        float p2 = __expf(s[2]);
        float p3 = __expf(s[3]);
        Lp[nf] += (p0 + p1) + (p2 + p3);
        uint2 pw = make_uint2(pk_f16(p0, p1), pk_f16(p2, p3));
        *(uint2*)&Ps[w][nf * 16 + fr][mf * 16 + kg * 4] = pw;
      }
    __syncthreads();
#pragma unroll
    for (int kw = 0; kw < 2; ++kw) {
      f16x8 vf[4], pf[4];
#pragma unroll
      for (int mf = 0; mf < 4; ++mf)
        vf[mf] = *(const f16x8*)&W2t[mf * 16 + fr][kw * 32 + kg * 8];
#pragma unroll
      for (int nf = 0; nf < 4; ++nf)
        pf[nf] = *(const f16x8*)&Ps[w][nf * 16 + fr][kw * 32 + kg * 8];
#pragma unroll
      for (int mf = 0; mf < 4; ++mf)
#pragma unroll
        for (int nf = 0; nf < 4; ++nf)
          oacc[mf][nf] = __builtin_amdgcn_mfma_f32_16x16x32_f16(vf[mf], pf[nf],
                                                                oacc[mf][nf], 0, 0, 0);
    }
  }
#pragma unroll
  for (int nf = 0; nf < 4; ++nf) {
    Lp[nf] += __shfl_xor(Lp[nf], 16);
    Lp[nf] += __shfl_xor(Lp[nf], 32);
  }
#pragma unroll
  for (int nf = 0; nf < 4; ++nf) {
    float inv = 1.0f / Lp[nf];
    int tok = n0 + w * 64 + nf * 16 + fr;
#pragma unroll
    for (int mf = 0; mf < 4; ++mf) {
      f32x4 o = oacc[mf][nf];
      ushort4 hs;
      hs.x = f16_1(o[0] * inv);
      hs.y = f16_1(o[1] * inv);
      hs.z = f16_1(o[2] * inv);
      hs.w = f16_1(o[3] * inv);
      *(ushort4*)(attf + ((size_t)b * NPAD + tok) * DD + h * 64 + mf * 16 + kg * 4) = hs;
    }
  }
}

// ---------------- attf += depthwise33(v); sliding-window (40 LDS loads/thread)
__global__ __launch_bounds__(256) void k_convres(
    unsigned short* __restrict__ attf, const unsigned short* __restrict__ qkv,
    const float* __restrict__ resw) {
  __shared__ float vS[96][68];
  __shared__ float w33[33];
  int t = threadIdx.x;
  int tb = blockIdx.x, bh = blockIdx.y;
  int b = bh >> 3, h = bh & 7;
  int n0 = tb * 64;
  if (t < 33) w33[t] = resw[h * 33 + t];
  int sc = (t & 3) * 16;
#pragma unroll
  for (int pass = 0; pass < 2; ++pass) {
    int r = (t >> 2) + pass * 64;
    if (r < 96) {
      int seq = n0 - 16 + r;
      if (seq >= 0 && seq < NPAD) {
        const unsigned short* p =
            qkv + ((size_t)b * NPAD + seq) * 1536 + 1024 + h * 64 + sc;
        uint4 u0 = *(const uint4*)p;
        uint4 u1 = *(const uint4*)(p + 8);
        float4 f0 = make_float4(f16f(u0.x), f16f(u0.x >> 16), f16f(u0.y),
                                f16f(u0.y >> 16));
        float4 f1 = make_float4(f16f(u0.z), f16f(u0.z >> 16), f16f(u0.w),
                                f16f(u0.w >> 16));
        float4 f2 = make_float4(f16f(u1.x), f16f(u1.x >> 16), f16f(u1.y),
                                f16f(u1.y >> 16));
        float4 f3 = make_float4(f16f(u1.z), f16f(u1.z >> 16), f16f(u1.w),
                                f16f(u1.w >> 16));
        *(float4*)&vS[r][sc + 0] = f0;
        *(float4*)&vS[r][sc + 4] = f1;
        *(float4*)&vS[r][sc + 8] = f2;
        *(float4*)&vS[r][sc + 12] = f3;
      } else {
        float4 z = make_float4(0.f, 0.f, 0.f, 0.f);
        *(float4*)&vS[r][sc + 0] = z;
        *(float4*)&vS[r][sc + 4] = z;
        *(float4*)&vS[r][sc + 8] = z;
        *(float4*)&vS[r][sc + 12] = z;
      }
    }
  }
  __syncthreads();
  int tg = t >> 5;
  int d2 = (t & 31) * 2;
  float ax[8], ay[8];
#pragma unroll
  for (int j = 0; j < 8; ++j) { ax[j] = 0.f; ay[j] = 0.f; }
  // rows tg*8 .. tg*8+39 cover taps k=0..32 for the 8 tokens tg*8+j
#pragma unroll
  for (int rr = 0; rr < 40; ++rr) {
    float2 v = *(float2*)&vS[tg * 8 + rr][d2];
#pragma unroll
    for (int j = 0; j < 8; ++j) {
      int k = rr - j;
      if (k >= 0 && k < 33) {
        ax[j] += w33[k] * v.x;
        ay[j] += w33[k] * v.y;
      }
    }
  }
#pragma unroll
  for (int j = 0; j < 8; ++j) {
    size_t off = ((size_t)b * NPAD + n0 + tg * 8 + j) * DD + h * 64 + d2;
    unsigned u = *(unsigned*)(attf + off);
    float x0 = f16f(u) + ax[j];
    float x1 = f16f(u >> 16) + ay[j];
    *(unsigned*)(attf + off) = pk_f16(x0, x1);
  }
}

// ---------------------------------------------------------------- PPEG (combined 7x7)
__global__ __launch_bounds__(128) void k_ppeg(
    float* __restrict__ hB, const float* __restrict__ hA,
    const float* __restrict__ w7, const float* __restrict__ b7,
    const float* __restrict__ w5, const float* __restrict__ b5,
    const float* __restrict__ w3, const float* __restrict__ b3) {
  __shared__ float cw[49][128];
  int t = threadIdx.x;
  int i = blockIdx.x >> 2;
  int j0 = (blockIdx.x & 3) * 32;
  int cg = blockIdx.y, b = blockIdx.z;
  int c = cg * 128 + t;
#pragma unroll
  for (int k = 0; k < 49; ++k) cw[k][t] = w7[c * 49 + k];
#pragma unroll
  for (int di = 0; di < 5; ++di)
#pragma unroll
    for (int dj = 0; dj < 5; ++dj)
      cw[(di + 1) * 7 + dj + 1][t] += w5[c * 25 + di * 5 + dj];
#pragma unroll
  for (int di = 0; di < 3; ++di)
#pragma unroll
    for (int dj = 0; dj < 3; ++dj)
      cw[(di + 2) * 7 + dj + 2][t] += w3[c * 9 + di * 3 + dj];
  cw[24][t] += 1.0f;
  float bias = b7[c] + b5[c] + b3[c];
  const float* base = hA + (size_t)b * TT * DD + DD + c;
  float* obase = hB + (size_t)b * TT * DD + DD + c;
  float acc[32];
#pragma unroll
  for (int j = 0; j < 32; ++j) acc[j] = bias;
  for (int di = 0; di < 7; ++di) {
    int ii = i + di - 3;
    if ((unsigned)ii >= 128u) continue;
    float win[38];
#pragma unroll
    for (int w = 0; w < 38; ++w) {
      int col = j0 - 3 + w;
      win[w] = ((unsigned)col < 128u) ? base[(size_t)(ii * 128 + col) * DD] : 0.f;
    }
#pragma unroll
    for (int dj = 0; dj < 7; ++dj) {
      float wv = cw[di * 7 + dj][t];
#pragma unroll
      for (int j = 0; j < 32; ++j) acc[j] += win[j + dj] * wv;
    }
  }
#pragma unroll
  for (int j = 0; j < 32; ++j) obase[(size_t)(i * 128 + j0 + j) * DD] = acc[j];
}

// ---------------------------------------------------------------- final head
__global__ __launch_bounds__(512) void k_final(
    float* __restrict__ out, const float* __restrict__ h,
    const float* __restrict__ g, const float* __restrict__ be,
    const float* __restrict__ cw, const float* __restrict__ cbias) {
  __shared__ float sm[16];
  int t = threadIdx.x;
  for (int b = 0; b < 2; ++b) {
    const float* row = h + (size_t)b * TT * DD;
    float x = row[t];
    float s = x;
    for (int o = 32; o; o >>= 1) s += __shfl_xor(s, o);
    if ((t & 63) == 0) sm[t >> 6] = s;
    __syncthreads();
    float mu = 0.f;
    for (int i = 0; i < 8; ++i) mu += sm[i];
    mu *= (1.f / 512.f);
    __syncthreads();
    float d = x - mu;
    s = d * d;
    for (int o = 32; o; o >>= 1) s += __shfl_xor(s, o);
    if ((t & 63) == 0) sm[t >> 6] = s;
    __syncthreads();
    float var = 0.f;
    for (int i = 0; i < 8; ++i) var += sm[i];
    var *= (1.f / 512.f);
    float rs = rsqrtf(var + 1e-5f);
    __syncthreads();
    float f = d * rs * g[t] + be[t];
    float p0 = f * cw[2 * t], p1 = f * cw[2 * t + 1];
    for (int o = 32; o; o >>= 1) {
      p0 += __shfl_xor(p0, o);
      p1 += __shfl_xor(p1, o);
    }
    if ((t & 63) == 0) {
      sm[t >> 6] = p0;
      sm[8 + (t >> 6)] = p1;
    }
    __syncthreads();
    if (t == 0) {
      float q0 = 0.f, q1 = 0.f;
      for (int i = 0; i < 8; ++i) {
        q0 += sm[i];
        q1 += sm[8 + i];
      }
      out[b * 2 + 0] = q0 + cbias[0];
      out[b * 2 + 1] = q1 + cbias[1];
    }
    __syncthreads();
  }
}

// ---------------------------------------------------------------- host side
static void run_attn(float* h, const float* lng, const float* lnb,
                     const float* wqkv, const float* wout, const float* bout,
                     const float* resw, float* xp, unsigned short* qkvh, float* ql,
                     float* kl, float* a2, float* z0, float* z1, float* xz, float* xz2,
                     float* yB, float* yC, float* bv, float* w2, float* red,
                     float* Sbuf, unsigned short* wth, hipStream_t stream) {
  // xp region: [single f16 plane: LN output, later attention output]
  unsigned short* xph = (unsigned short*)xp;
  k_zero_pad<<<BB * PADF, 256, 0, stream>>>(xph);
  k_ln_pad<<<(BB * TT + 3) / 4, 256, 0, stream>>>(xph, h, lng, lnb);
  k_cvt_wt<<<dim3(DD / 32, 1536 / 32), 256, 0, stream>>>(wqkv, wth, DD, 1536);
  k_gemm_qkv8<<<dim3(BB * NPAD / 128, 1536 / 256), 512, 0, stream>>>(xph, wth, qkvh);
  k_landmarks<<<1024, 256, 0, stream>>>(ql, kl, qkvh);
  float* pacc = Sbuf;
  float* pL = Sbuf + (size_t)A3KC * 4096 * 64;
  k_a3v_mfma<<<dim3(16, A3KC), 256, 0, stream>>>(pacc, pL, ql, qkvh);
  k_a3v_red<<<4096, 64, 0, stream>>>(bv, pacc, pL);
  k_sim2<<<dim3(4, 4, 16), 256, 0, stream>>>(a2, ql, kl);
  k_softmax256<<<1024, 256, 0, stream>>>(a2);
  k_pinv_sums<<<16, 256, 0, stream>>>(red, a2);
  k_pinv_scale<<<1, 256, 0, stream>>>(red);
  k_zinit<<<dim3(256, 16), 256, 0, stream>>>(z0, a2, red);
  // Newton-Schulz: 3 matmuls/iter via P = a2@z carried forward
  float* zc = z0;
  float* zn = z1;
  float* P = xz;
  float* Pn = xz2;
  // P0 = a2 @ z0
  k_bmm_poly<<<dim3(4, 4, 16), 256, 0, stream>>>(a2, zc, nullptr, P, 1.f, 0.f, 0.f, 256);
  for (int it = 0; it < 6; ++it) {
    // yB = P@P + 15I - 7P   (== 15I - P@(7I - P))
    k_bmm_poly<<<dim3(4, 4, 16), 256, 0, stream>>>(P, P, P, yB, 1.f, 15.f, -7.f, 256);
    // yC = 13I - P@yB
    k_bmm_poly<<<dim3(4, 4, 16), 256, 0, stream>>>(P, yB, nullptr, yC, -1.f, 13.f, 0.f, 256);
    // zn = 0.25 zc@yC ; Pn = 0.25 P@yC  (batched)
    k_bmm_dual<<<dim3(4, 4, 32), 256, 0, stream>>>(zc, P, yC, zn, Pn, 0.25f);
    float* tmp = zc; zc = zn; zn = tmp;
    tmp = P; P = Pn; Pn = tmp;
  }
  k_bmm_poly<<<dim3(1, 4, 16), 256, 0, stream>>>(zc, bv, nullptr, w2, 1.f, 0.f, 0.f, 64);
  // attention output as single f16 in xph (LN plane is dead after qkv GEMM)
  k_att1<<<dim3(NPAD / 256, 16), 256, 0, stream>>>(xph, qkvh, kl, w2);
  k_convres<<<dim3(NPAD / 64, 16), 256, 0, stream>>>(xph, qkvh, resw);
  k_cvt_wt<<<dim3(DD / 32, DD / 32), 256, 0, stream>>>(wout, wth, DD, DD);
  k_gemm_proj<<<dim3(129, 2, BB), 512, 0, stream>>>(xph, wth, h, bout);
}

extern "C" void kernel_launch(void* const* d_in, const int* in_sizes, int n_in,
                              void* d_out, int out_size, void* d_ws, size_t ws_size,
                              hipStream_t stream) {
  const float* x        = (const float*)d_in[0];
  const float* w_feat   = (const float*)d_in[1];
  const float* b_feat   = (const float*)d_in[2];
  const float* cls_tok  = (const float*)d_in[3];
  const float* ln1_g    = (const float*)d_in[4];
  const float* ln1_b    = (const float*)d_in[5];
  const float* qkv1     = (const float*)d_in[6];
  const float* out1_w   = (const float*)d_in[7];
  const float* out1_b   = (const float*)d_in[8];
  const float* res1_w   = (const float*)d_in[9];
  const float* ppeg_w7  = (const float*)d_in[10];
  const float* ppeg_b7  = (const float*)d_in[11];
  const float* ppeg_w5  = (const float*)d_in[12];
  const float* ppeg_b5  = (const float*)d_in[13];
  const float* ppeg_w3  = (const float*)d_in[14];
  const float* ppeg_b3  = (const float*)d_in[15];
  const float* ln2_g    = (const float*)d_in[16];
  const float* ln2_b    = (const float*)d_in[17];
  const float* qkv2     = (const float*)d_in[18];
  const float* out2_w   = (const float*)d_in[19];
  const float* out2_b   = (const float*)d_in[20];
  const float* res2_w   = (const float*)d_in[21];
  const float* lnf_g    = (const float*)d_in[22];
  const float* lnf_b    = (const float*)d_in[23];
  const float* cls_w    = (const float*)d_in[24];
  const float* cls_b    = (const float*)d_in[25];

  float* ws = (float*)d_ws;
  size_t off = 0;
  float* hA  = ws + off; off += (size_t)BB * TT * DD;
  float* hB  = ws + off; off += (size_t)BB * TT * DD;
  float* xp  = ws + off; off += (size_t)BB * NPAD * DD;
  float* qkvf = ws + off; off += (size_t)BB * NPAD * 3 * DD;  // used as f16 (half)
  unsigned short* qkvh = (unsigned short*)qkvf;
  float* ql  = ws + off; off += (size_t)BB * HH * 256 * 64;
  float* kl  = ws + off; off += (size_t)BB * HH * 256 * 64;
  float* a2  = ws + off; off += (size_t)16 * 65536;
  float* z0  = ws + off; off += (size_t)16 * 65536;
  float* z1  = ws + off; off += (size_t)16 * 65536;
  float* xz  = ws + off; off += (size_t)16 * 65536;
  float* xz2 = ws + off; off += (size_t)16 * 65536;
  float* yB  = ws + off; off += (size_t)16 * 65536;
  float* yC  = ws + off; off += (size_t)16 * 65536;
  float* bv  = ws + off; off += (size_t)BB * HH * 256 * 64;
  float* w2  = ws + off; off += (size_t)BB * HH * 256 * 64;
  float* red = ws + off; off += 8448;
  unsigned short* wth = (unsigned short*)(ws + off); off += 393216;

  // Stage 1: h = gelu(x @ w_feat + b_feat), prepend cls token
  k_set_cls<<<2, 512, 0, stream>>>(hA, cls_tok);
  k_cvt_wt<<<dim3(1024 / 32, DD / 32), 256, 0, stream>>>(w_feat, wth, 1024, DD);
  k_gemm_mfma<0><<<dim3(32768 / 128, DD / 256), 512, 0, stream>>>(
      x, nullptr, nullptr, wth, b_feat, hA, 32768, 1024, DD, 1024);
  // Attention 1 (residual in-place on hA; hB is dead -> scratch)
  run_attn(hA, ln1_g, ln1_b, qkv1, out1_w, out1_b, res1_w, xp, qkvh, ql, kl, a2, z0, z1,
           xz, xz2, yB, yC, bv, w2, red, hB, wth, stream);
  // PPEG: hB = ppeg(hA)
  k_copy_cls<<<2, 512, 0, stream>>>(hB, hA);
  k_ppeg<<<dim3(512, 4, 2), 128, 0, stream>>>(hB, hA, ppeg_w7, ppeg_b7, ppeg_w5, ppeg_b5,
                                              ppeg_w3, ppeg_b3);
  // Attention 2 (residual in-place on hB; hA is dead -> scratch)
  run_attn(hB, ln2_g, ln2_b, qkv2, out2_w, out2_b, res2_w, xp, qkvh, ql, kl, a2, z0, z1,
           xz, xz2, yB, yC, bv, w2, red, hA, wth, stream);
  // Final: LN(cls) @ cls_w + cls_b
  k_final<<<1, 512, 0, stream>>>((float*)d_out, hB, lnf_g, lnf_b, cls_w, cls_b);
}

// Round 24
// 1359.152 us; speedup vs baseline: 1.2479x; 1.0109x over previous
//
#include <hip/hip_runtime.h>
#include <cstdint>
#include <cstddef>

#define BB 2
#define TT 16385
#define NPAD 16640
#define DD 512
#define HH 8
#define DHH 64
#define MLAND 256
#define PADF 255
#define A3KC 26
#define A3CH 640

typedef __attribute__((ext_vector_type(8))) _Float16 f16x8;
typedef __attribute__((ext_vector_type(4))) float f32x4;

__device__ __forceinline__ float gelu_f(float v) {
  float c = 0.7978845608028654f * (v + 0.044715f * v * v * v);
  return 0.5f * v * (1.0f + tanhf(c));
}

__device__ __forceinline__ unsigned short f16_1(float a) {
  _Float16 h = (_Float16)a;
  return __builtin_bit_cast(unsigned short, h);
}
__device__ __forceinline__ float f16f(unsigned u) {
  return (float)__builtin_bit_cast(_Float16, (unsigned short)(u & 0xffffu));
}
__device__ __forceinline__ unsigned pk_f16(float a, float b) {
  return (unsigned)f16_1(a) | ((unsigned)f16_1(b) << 16);
}
// split a,b into f16 hi (packed) and f16 residual-lo (packed)
__device__ __forceinline__ void split2h(float a, float b, unsigned& hi, unsigned& lo) {
  _Float16 ah = (_Float16)a, bh = (_Float16)b;
  hi = (unsigned)__builtin_bit_cast(unsigned short, ah) |
       ((unsigned)__builtin_bit_cast(unsigned short, bh) << 16);
  lo = pk_f16(a - (float)ah, b - (float)bh);
}

// async global->LDS 16B (wave-uniform LDS base + lane*16)
__device__ __forceinline__ void gload16(const unsigned short* g, short* l) {
  __builtin_amdgcn_global_load_lds(
      (const __attribute__((address_space(1))) void*)g,
      (__attribute__((address_space(3))) void*)l, 16, 0, 0);
}

// ---------------------------------------------------------------- cls rows
__global__ void k_set_cls(float* __restrict__ h, const float* __restrict__ cls) {
  h[(size_t)blockIdx.x * TT * DD + threadIdx.x] = cls[threadIdx.x];
}
__global__ void k_copy_cls(float* __restrict__ dst, const float* __restrict__ src) {
  size_t o = (size_t)blockIdx.x * TT * DD + threadIdx.x;
  dst[o] = src[o];
}

// ------------------------------------------------ x fp32 -> f16 plane
__global__ __launch_bounds__(256) void k_cvt_x(
    unsigned short* __restrict__ xh, const float* __restrict__ x) {
  size_t i = ((size_t)blockIdx.x * 256 + threadIdx.x) * 8;
  float4 a = *(const float4*)(x + i);
  float4 b = *(const float4*)(x + i + 4);
  uint4 u;
  u.x = pk_f16(a.x, a.y);
  u.y = pk_f16(a.z, a.w);
  u.z = pk_f16(b.x, b.y);
  u.w = pk_f16(b.z, b.w);
  *(uint4*)(xh + i) = u;
}

// ------------------------------------------------ W[K][N] -> Wt f16 [N][K]
__global__ __launch_bounds__(256) void k_cvt_wt(
    const float* __restrict__ W, unsigned short* __restrict__ Wth, int K, int N) {
  __shared__ float tile[32][33];
  int kb = blockIdx.x * 32, nb = blockIdx.y * 32;
  int t = threadIdx.x;
  int tr = t >> 3, tc4 = (t & 7) * 4;
  float4 v = *(const float4*)(W + (size_t)(kb + tr) * N + nb + tc4);
  tile[tr][tc4 + 0] = v.x;
  tile[tr][tc4 + 1] = v.y;
  tile[tr][tc4 + 2] = v.z;
  tile[tr][tc4 + 3] = v.w;
  __syncthreads();
  int n = nb + tr;
  ushort4 hs;
  hs.x = f16_1(tile[tc4 + 0][tr]);
  hs.y = f16_1(tile[tc4 + 1][tr]);
  hs.z = f16_1(tile[tc4 + 2][tr]);
  hs.w = f16_1(tile[tc4 + 3][tr]);
  *(ushort4*)(Wth + (size_t)n * K + kb + tc4) = hs;
}

// ---------------- feat GEMM: pipelined, single-f16 x, gelu+bias fp32 out
// K=1024 (32 steps), BK=32, dbuf LDS 48KB -> 3 blocks/CU, vmcnt(3), XOR swizzle.
__global__ __launch_bounds__(512) void k_gemm_feat(
    const unsigned short* __restrict__ Xh, const unsigned short* __restrict__ Wth,
    float* __restrict__ Cf, const float* __restrict__ bias) {
  __shared__ __align__(16) short Ah[2][128][32];
  __shared__ __align__(16) short Bs[2][256][32];
  const int t = threadIdx.x;
  int nRow = gridDim.x, nCol = gridDim.y;
  int lin = blockIdx.x + blockIdx.y * nRow;
  int chunk = 8 * nCol;
  int group = lin / chunk;
  int rem = lin - group * chunk;
  int gbase = group * 8;
  int Geff = nRow - gbase;
  if (Geff > 8) Geff = 8;
  const int rb = (gbase + rem % Geff) * 128;
  const int cb = (rem / Geff) * 256;
  const int lane = t & 63, wv = t >> 6;
  const int wr = wv >> 2, wc = wv & 3;
  const int fr = lane & 15, kg = lane >> 4;
  const int lr4 = lane >> 2;
  const int ss = (lane & 3) ^ (lr4 & 3);

  f32x4 acc[4][4];
  f32x4 zero4 = {0.f, 0.f, 0.f, 0.f};
#pragma unroll
  for (int i = 0; i < 4; ++i)
#pragma unroll
    for (int j = 0; j < 4; ++j) acc[i][j] = zero4;

  // stage K-step kt (K=32) into buffer bf: 3 gloads/wave (A 1, B 2)
  auto STAGE = [&](int kt, int bf) {
    const int k0 = kt * 32;
    {
      int lr = wv * 16;
      gload16(Xh + (size_t)(rb + lr + lr4) * 1024 + k0 + ss * 8, &Ah[bf][lr][0]);
    }
#pragma unroll
    for (int j = 0; j < 2; ++j) {
      int lr = wv * 32 + j * 16;
      gload16(Wth + (size_t)(cb + lr + lr4) * 1024 + k0 + ss * 8, &Bs[bf][lr][0]);
    }
  };

  STAGE(0, 0);
  STAGE(1, 1);
  const int sl = ((kg ^ (fr & 3))) * 8;
  for (int kt = 0; kt < 32; ++kt) {
    if (kt < 31) {
      asm volatile("s_waitcnt vmcnt(3)" ::: "memory");
    } else {
      asm volatile("s_waitcnt vmcnt(0)" ::: "memory");
    }
    __builtin_amdgcn_sched_barrier(0);
    __builtin_amdgcn_s_barrier();
    const int bf = kt & 1;
    f16x8 ah[4];
#pragma unroll
    for (int mf = 0; mf < 4; ++mf)
      ah[mf] = *(const f16x8*)&Ah[bf][wr * 64 + mf * 16 + fr][sl];
#pragma unroll
    for (int nf = 0; nf < 4; ++nf) {
      f16x8 bhf = *(const f16x8*)&Bs[bf][wc * 64 + nf * 16 + fr][sl];
#pragma unroll
      for (int mf = 0; mf < 4; ++mf)
        acc[mf][nf] =
            __builtin_amdgcn_mfma_f32_16x16x32_f16(ah[mf], bhf, acc[mf][nf], 0, 0, 0);
    }
    __builtin_amdgcn_s_barrier();
    if (kt + 2 < 32) STAGE(kt + 2, bf);
  }
#pragma unroll
  for (int mf = 0; mf < 4; ++mf) {
#pragma unroll
    for (int r = 0; r < 4; ++r) {
      int row = rb + wr * 64 + mf * 16 + kg * 4 + r;
      size_t orow = (size_t)(row + (row >> 14) + 1);
#pragma unroll
      for (int nf = 0; nf < 4; ++nf) {
        int col = cb + wc * 64 + nf * 16 + fr;
        Cf[orow * DD + col] = gelu_f(acc[mf][nf][r] + bias[col]);
      }
    }
  }
}

// ---------------- qkv GEMM: pipelined, single-f16 A (LN output), f16 out
// BK=32, dbuf LDS 48KB -> 3 blocks/CU, 2-deep prefetch, vmcnt(3), XOR swizzle.
__global__ __launch_bounds__(512) void k_gemm_qkv8(
    const unsigned short* __restrict__ Aph, const unsigned short* __restrict__ Wth,
    unsigned short* __restrict__ Ch) {
  __shared__ __align__(16) short Ah[2][128][32];
  __shared__ __align__(16) short Bs[2][256][32];
  const int t = threadIdx.x;
  // L2 block swizzle
  int nRow = gridDim.x, nCol = gridDim.y;
  int lin = blockIdx.x + blockIdx.y * nRow;
  int chunk = 8 * nCol;
  int group = lin / chunk;
  int rem = lin - group * chunk;
  int gbase = group * 8;
  int Geff = nRow - gbase;
  if (Geff > 8) Geff = 8;
  const int rb = (gbase + rem % Geff) * 128;
  const int cb = (rem / Geff) * 256;
  const int lane = t & 63, wv = t >> 6;
  const int wr = wv >> 2, wc = wv & 3;
  const int fr = lane & 15, kg = lane >> 4;
  const int lr4 = lane >> 2;                       // row-in-16 within a gload
  const int ss = (lane & 3) ^ (lr4 & 3);           // pre-swizzled src slot (16B)

  f32x4 acc[4][4];
  f32x4 zero4 = {0.f, 0.f, 0.f, 0.f};
#pragma unroll
  for (int i = 0; i < 4; ++i)
#pragma unroll
    for (int j = 0; j < 4; ++j) acc[i][j] = zero4;

  // stage K-step kt (K=32) into buffer bf: 3 gloads/wave (A 1, B 2)
  auto STAGE = [&](int kt, int bf) {
    const int k0 = kt * 32;
    {
      int lr = wv * 16;
      gload16(Aph + (size_t)(rb + lr + lr4) * DD + k0 + ss * 8, &Ah[bf][lr][0]);
    }
#pragma unroll
    for (int j = 0; j < 2; ++j) {
      int lr = wv * 32 + j * 16;
      gload16(Wth + (size_t)(cb + lr + lr4) * DD + k0 + ss * 8, &Bs[bf][lr][0]);
    }
  };

  STAGE(0, 0);
  STAGE(1, 1);
  const int sl = ((kg ^ (fr & 3))) * 8;  // swizzled read slot (shorts)
  for (int kt = 0; kt < 16; ++kt) {
    if (kt < 15) {
      asm volatile("s_waitcnt vmcnt(3)" ::: "memory");  // own tile-kt loads done
    } else {
      asm volatile("s_waitcnt vmcnt(0)" ::: "memory");  // final drain
    }
    __builtin_amdgcn_sched_barrier(0);
    __builtin_amdgcn_s_barrier();  // all waves' tile-kt data in LDS
    const int bf = kt & 1;
    f16x8 ah[4];
#pragma unroll
    for (int mf = 0; mf < 4; ++mf)
      ah[mf] = *(const f16x8*)&Ah[bf][wr * 64 + mf * 16 + fr][sl];
#pragma unroll
    for (int nf = 0; nf < 4; ++nf) {
      f16x8 bhf = *(const f16x8*)&Bs[bf][wc * 64 + nf * 16 + fr][sl];
#pragma unroll
      for (int mf = 0; mf < 4; ++mf)
        acc[mf][nf] =
            __builtin_amdgcn_mfma_f32_16x16x32_f16(ah[mf], bhf, acc[mf][nf], 0, 0, 0);
    }
    __builtin_amdgcn_s_barrier();  // all waves done reading buf bf
    if (kt + 2 < 16) STAGE(kt + 2, bf);
  }
#pragma unroll
  for (int mf = 0; mf < 4; ++mf) {
#pragma unroll
    for (int r = 0; r < 4; ++r) {
      int row = rb + wr * 64 + mf * 16 + kg * 4 + r;
#pragma unroll
      for (int nf = 0; nf < 4; ++nf) {
        int col = cb + wc * 64 + nf * 16 + fr;
        Ch[(size_t)row * 1536 + col] = f16_1(acc[mf][nf][r]);
      }
    }
  }
}

// ---------------- proj GEMM: pipelined, single-f16 A (attf), fp32 residual out
// BK=32, dbuf LDS 48KB -> 3 blocks/CU, 2-deep prefetch, vmcnt(3), XOR swizzle.
__global__ __launch_bounds__(512) void k_gemm_proj(
    const unsigned short* __restrict__ Af, const unsigned short* __restrict__ Wth,
    float* __restrict__ Cb, const float* __restrict__ bias) {
  __shared__ __align__(16) short Ah[2][128][32];
  __shared__ __align__(16) short Bs[2][256][32];
  const int t = threadIdx.x;
  int nRow = gridDim.x, nCol = gridDim.y;
  int lin = blockIdx.x + blockIdx.y * nRow;
  int chunk = 8 * nCol;
  int group = lin / chunk;
  int rem = lin - group * chunk;
  int gbase = group * 8;
  int Geff = nRow - gbase;
  if (Geff > 8) Geff = 8;
  const int rb = (gbase + rem % Geff) * 128;
  const int cb = (rem / Geff) * 256;
  const int lane = t & 63, wv = t >> 6;
  const int wr = wv >> 2, wc = wv & 3;
  const int fr = lane & 15, kg = lane >> 4;
  const int lr4 = lane >> 2;
  const int ss = (lane & 3) ^ (lr4 & 3);
  const size_t arow0 = (size_t)blockIdx.z * NPAD + PADF + rb;

  f32x4 acc[4][4];
  f32x4 zero4 = {0.f, 0.f, 0.f, 0.f};
#pragma unroll
  for (int i = 0; i < 4; ++i)
#pragma unroll
    for (int j = 0; j < 4; ++j) acc[i][j] = zero4;

  // stage K-step kt (K=32) into buffer bf: 3 gloads/wave (A 1, B 2)
  auto STAGE = [&](int kt, int bf) {
    const int k0 = kt * 32;
    {
      int lr = wv * 16;
      gload16(Af + (arow0 + lr + lr4) * DD + k0 + ss * 8, &Ah[bf][lr][0]);
    }
#pragma unroll
    for (int j = 0; j < 2; ++j) {
      int lr = wv * 32 + j * 16;
      gload16(Wth + (size_t)(cb + lr + lr4) * DD + k0 + ss * 8, &Bs[bf][lr][0]);
    }
  };

  STAGE(0, 0);
  STAGE(1, 1);
  const int sl = ((kg ^ (fr & 3))) * 8;
  for (int kt = 0; kt < 16; ++kt) {
    if (kt < 15) {
      asm volatile("s_waitcnt vmcnt(3)" ::: "memory");
    } else {
      asm volatile("s_waitcnt vmcnt(0)" ::: "memory");
    }
    __builtin_amdgcn_sched_barrier(0);
    __builtin_amdgcn_s_barrier();
    const int bf = kt & 1;
    f16x8 ah[4];
#pragma unroll
    for (int mf = 0; mf < 4; ++mf)
      ah[mf] = *(const f16x8*)&Ah[bf][wr * 64 + mf * 16 + fr][sl];
#pragma unroll
    for (int nf = 0; nf < 4; ++nf) {
      f16x8 bhf = *(const f16x8*)&Bs[bf][wc * 64 + nf * 16 + fr][sl];
#pragma unroll
      for (int mf = 0; mf < 4; ++mf)
        acc[mf][nf] =
            __builtin_amdgcn_mfma_f32_16x16x32_f16(ah[mf], bhf, acc[mf][nf], 0, 0, 0);
    }
    __builtin_amdgcn_s_barrier();
    if (kt + 2 < 16) STAGE(kt + 2, bf);
  }
  float* Cf = Cb + (size_t)blockIdx.z * TT * DD;
#pragma unroll
  for (int mf = 0; mf < 4; ++mf) {
#pragma unroll
    for (int r = 0; r < 4; ++r) {
      int row = rb + wr * 64 + mf * 16 + kg * 4 + r;
      if (row >= TT) continue;
#pragma unroll
      for (int nf = 0; nf < 4; ++nf) {
        int col = cb + wc * 64 + nf * 16 + fr;
        float old = Cf[(size_t)row * DD + col];
        Cf[(size_t)row * DD + col] = old + acc[mf][nf][r] + bias[col];
      }
    }
  }
}

// ------------------------- LN + pad -> writes single f16 plane (qkv A operand)
__global__ __launch_bounds__(256) void k_ln_pad(
    unsigned short* __restrict__ xph, const float* __restrict__ h,
    const float* __restrict__ gam, const float* __restrict__ bet) {
  int w = threadIdx.x >> 6, lane = threadIdx.x & 63;
  int row = blockIdx.x * 4 + w;
  if (row >= BB * TT) return;
  int b = row / TT, i = row - b * TT;
  const float* src = h + (size_t)row * DD;
  float4 x0 = *(const float4*)(src + lane * 4);
  float4 x1 = *(const float4*)(src + 256 + lane * 4);
  float s = x0.x + x0.y + x0.z + x0.w + x1.x + x1.y + x1.z + x1.w;
  for (int o = 32; o; o >>= 1) s += __shfl_xor(s, o);
  float mu = s * (1.f / 512.f);
  float q = (x0.x - mu) * (x0.x - mu) + (x0.y - mu) * (x0.y - mu) +
            (x0.z - mu) * (x0.z - mu) + (x0.w - mu) * (x0.w - mu) +
            (x1.x - mu) * (x1.x - mu) + (x1.y - mu) * (x1.y - mu) +
            (x1.z - mu) * (x1.z - mu) + (x1.w - mu) * (x1.w - mu);
  for (int o = 32; o; o >>= 1) q += __shfl_xor(q, o);
  float rs = rsqrtf(q * (1.f / 512.f) + 1e-5f);
  float4 g0 = *(const float4*)(gam + lane * 4);
  float4 g1 = *(const float4*)(gam + 256 + lane * 4);
  float4 b0 = *(const float4*)(bet + lane * 4);
  float4 b1 = *(const float4*)(bet + 256 + lane * 4);
  float4 o0, o1;
  o0.x = (x0.x - mu) * rs * g0.x + b0.x;
  o0.y = (x0.y - mu) * rs * g0.y + b0.y;
  o0.z = (x0.z - mu) * rs * g0.z + b0.z;
  o0.w = (x0.w - mu) * rs * g0.w + b0.w;
  o1.x = (x1.x - mu) * rs * g1.x + b1.x;
  o1.y = (x1.y - mu) * rs * g1.y + b1.y;
  o1.z = (x1.z - mu) * rs * g1.z + b1.z;
  o1.w = (x1.w - mu) * rs * g1.w + b1.w;
  size_t ro = ((size_t)b * NPAD + PADF + i) * DD;
  *(uint2*)(xph + ro + lane * 4) = make_uint2(pk_f16(o0.x, o0.y), pk_f16(o0.z, o0.w));
  *(uint2*)(xph + ro + 256 + lane * 4) =
      make_uint2(pk_f16(o1.x, o1.y), pk_f16(o1.z, o1.w));
}

__global__ void k_zero_pad(unsigned short* __restrict__ xph) {
  int r = blockIdx.x;
  int b = r / PADF, j = r - b * PADF;
  size_t ro = ((size_t)b * NPAD + j) * DD;
  ((unsigned*)(xph + ro))[threadIdx.x] = 0u;
}

// ---------------------------------------------------------------- landmarks (f16 qkv)
__global__ __launch_bounds__(256) void k_landmarks(
    float* __restrict__ ql, float* __restrict__ kl,
    const unsigned short* __restrict__ qkv) {
  int t = threadIdx.x;
  int mi = t >> 6, d = t & 63;
  int blk = blockIdx.x;
  int bh = blk >> 6, mg = blk & 63;
  int b = bh >> 3, h = bh & 7;
  int m = mg * 4 + mi;
  const unsigned short* base = qkv + (size_t)b * NPAD * 1536 + h * 64 + d;
  float sq = 0.f, sk = 0.f;
  int t0 = m * 65;
  for (int j = 0; j < 65; ++j) {
    const unsigned short* p = base + (size_t)(t0 + j) * 1536;
    sq += f16f(p[0]);
    sk += f16f(p[512]);
  }
  ql[((size_t)bh * 256 + m) * 64 + d] = sq * (0.125f / 65.f);
  kl[((size_t)bh * 256 + m) * 64 + d] = sk * (1.f / 65.f);
}

// ---------------------------------------------------------------- sim2 = ql @ kl^T
__global__ __launch_bounds__(256) void k_sim2(
    float* __restrict__ sim, const float* __restrict__ ql, const float* __restrict__ kl) {
  __shared__ __align__(16) float Aq[64][68];
  __shared__ __align__(16) float Bk[64][68];
  int t = threadIdx.x;
  int tj = blockIdx.x, ti = blockIdx.y, bh = blockIdx.z;
  int r = t >> 2, cc = (t & 3) * 16;
  const float* ap = ql + ((size_t)bh * 256 + ti * 64 + r) * 64 + cc;
  const float* bp = kl + ((size_t)bh * 256 + tj * 64 + r) * 64 + cc;
#pragma unroll
  for (int i = 0; i < 16; i += 4) {
    *(float4*)&Aq[r][cc + i] = *(const float4*)(ap + i);
    *(float4*)&Bk[r][cc + i] = *(const float4*)(bp + i);
  }
  __syncthreads();
  int tx = t & 15, ty = t >> 4;
  float acc[4][4];
#pragma unroll
  for (int i = 0; i < 4; ++i)
#pragma unroll
    for (int j = 0; j < 4; ++j) acc[i][j] = 0.f;
  for (int d = 0; d < 64; d += 4) {
    float4 a4[4], b4[4];
#pragma unroll
    for (int ii = 0; ii < 4; ++ii) a4[ii] = *(float4*)&Aq[ty * 4 + ii][d];
#pragma unroll
    for (int jj = 0; jj < 4; ++jj) b4[jj] = *(float4*)&Bk[tx * 4 + jj][d];
#pragma unroll
    for (int ii = 0; ii < 4; ++ii)
#pragma unroll
      for (int jj = 0; jj < 4; ++jj)
        acc[ii][jj] += a4[ii].x * b4[jj].x + a4[ii].y * b4[jj].y + a4[ii].z * b4[jj].z +
                       a4[ii].w * b4[jj].w;
  }
#pragma unroll
  for (int ii = 0; ii < 4; ++ii)
#pragma unroll
    for (int jj = 0; jj < 4; ++jj)
      sim[((size_t)bh * 256 + ti * 64 + ty * 4 + ii) * 256 + tj * 64 + tx * 4 + jj] =
          acc[ii][jj];
}

// ---------------------------------------------------------------- row softmax (len 256)
__global__ __launch_bounds__(256) void k_softmax256(float* __restrict__ a) {
  int w = threadIdx.x >> 6, lane = threadIdx.x & 63;
  size_t row = (size_t)blockIdx.x * 4 + w;
  float* p = a + row * 256 + lane * 4;
  float4 v = *(float4*)p;
  float m = fmaxf(fmaxf(v.x, v.y), fmaxf(v.z, v.w));
  for (int o = 32; o; o >>= 1) m = fmaxf(m, __shfl_xor(m, o));
  v.x = expf(v.x - m); v.y = expf(v.y - m);
  v.z = expf(v.z - m); v.w = expf(v.w - m);
  float s = v.x + v.y + v.z + v.w;
  for (int o = 32; o; o >>= 1) s += __shfl_xor(s, o);
  float inv = 1.f / s;
  v.x *= inv; v.y *= inv; v.z *= inv; v.w *= inv;
  *(float4*)p = v;
}

// ---------------------------------------------------------------- pinv helpers
__global__ void k_pinv_sums(float* __restrict__ red, const float* __restrict__ a2) {
  int bh = blockIdx.x, t = threadIdx.x;
  const float* Ab = a2 + (size_t)bh * 65536;
  float s = 0.f;
  for (int i = 0; i < 256; ++i) s += fabsf(Ab[(size_t)i * 256 + t]);
  red[bh * 256 + t] = s;
  float c = 0.f;
  const float* rp = Ab + (size_t)t * 256;
  for (int j = 0; j < 256; j += 4) {
    float4 v = *(const float4*)(rp + j);
    c += fabsf(v.x) + fabsf(v.y) + fabsf(v.z) + fabsf(v.w);
  }
  red[4096 + bh * 256 + t] = c;
}

__global__ void k_pinv_scale(float* __restrict__ red) {
  __shared__ float sm[8];
  int t = threadIdx.x;
  float m1 = 0.f, m2 = 0.f;
  for (int k = t; k < 4096; k += 256) {
    m1 = fmaxf(m1, red[k]);
    m2 = fmaxf(m2, red[4096 + k]);
  }
  for (int o = 32; o; o >>= 1) {
    m1 = fmaxf(m1, __shfl_xor(m1, o));
    m2 = fmaxf(m2, __shfl_xor(m2, o));
  }
  int w = t >> 6;
  if ((t & 63) == 0) { sm[w] = m1; sm[4 + w] = m2; }
  __syncthreads();
  if (t == 0) {
    float a = fmaxf(fmaxf(sm[0], sm[1]), fmaxf(sm[2], sm[3]));
    float b = fmaxf(fmaxf(sm[4], sm[5]), fmaxf(sm[6], sm[7]));
    red[8192] = 1.0f / (a * b);
  }
}

__global__ void k_zinit(float* __restrict__ z, const float* __restrict__ a2,
                        const float* __restrict__ red) {
  float s = red[8192];
  int i = blockIdx.x, bh = blockIdx.y, j = threadIdx.x;
  z[((size_t)bh * 256 + i) * 256 + j] = a2[((size_t)bh * 256 + j) * 256 + i] * s;
}

// ---- shared BK=128 f16 3-term matmul core: acc += A[i0..i0+64) @ B (256xN)
__device__ __forceinline__ void bmm_core(
    short (*Ash)[136], short (*Asl)[136], short (*Bsh)[136], short (*Bsl)[136],
    const float* __restrict__ Ab, const float* __restrict__ Bb, int i0, int j0, int N,
    int t, f32x4 (&acc)[4]) {
  const int lane = t & 63, w = t >> 6;
  const int fr = lane & 15, kg = lane >> 4;
  const int ar = t >> 2, akseg = (t & 3) * 32;  // A: 32 floats / thread
  for (int k0 = 0; k0 < 256; k0 += 128) {
    __syncthreads();
    {  // stage A rows (f16 split): 64 rows x 128 k
      const float* p = Ab + (size_t)(i0 + ar) * 256 + k0 + akseg;
#pragma unroll
      for (int q = 0; q < 4; ++q) {
        float4 f0 = *(const float4*)(p + q * 8);
        float4 f1 = *(const float4*)(p + q * 8 + 4);
        unsigned h0, h1, h2, h3, l0, l1, l2, l3;
        split2h(f0.x, f0.y, h0, l0);
        split2h(f0.z, f0.w, h1, l1);
        split2h(f1.x, f1.y, h2, l2);
        split2h(f1.z, f1.w, h3, l3);
        *(uint4*)&Ash[ar][akseg + q * 8] = make_uint4(h0, h1, h2, h3);
        *(uint4*)&Asl[ar][akseg + q * 8] = make_uint4(l0, l1, l2, l3);
      }
    }
    {  // stage B transposed (f16 split): Bsh[j_local][k_local], 128 k-rows x 64 j
#pragma unroll
      for (int pass = 0; pass < 8; ++pass) {
        int kr = pass * 16 + (t >> 4);
        int jseg = (t & 15) * 4;
        const float* p = Bb + (size_t)(k0 + kr) * N + j0 + jseg;
        float4 f = *(const float4*)p;
        float fv[4] = {f.x, f.y, f.z, f.w};
#pragma unroll
        for (int c = 0; c < 4; ++c) {
          _Float16 hh = (_Float16)fv[c];
          float lo = fv[c] - (float)hh;
          Bsh[jseg + c][kr] = (short)__builtin_bit_cast(unsigned short, hh);
          Bsl[jseg + c][kr] = (short)f16_1(lo);
        }
      }
    }
    __syncthreads();
#pragma unroll
    for (int kw = 0; kw < 4; ++kw) {
      f16x8 bhf = *(const f16x8*)&Bsh[w * 16 + fr][kw * 32 + kg * 8];
      f16x8 blf = *(const f16x8*)&Bsl[w * 16 + fr][kw * 32 + kg * 8];
#pragma unroll
      for (int mf = 0; mf < 4; ++mf) {
        f16x8 ah = *(const f16x8*)&Ash[mf * 16 + fr][kw * 32 + kg * 8];
        f16x8 al = *(const f16x8*)&Asl[mf * 16 + fr][kw * 32 + kg * 8];
        acc[mf] = __builtin_amdgcn_mfma_f32_16x16x32_f16(ah, bhf, acc[mf], 0, 0, 0);
        acc[mf] = __builtin_amdgcn_mfma_f32_16x16x32_f16(al, bhf, acc[mf], 0, 0, 0);
        acc[mf] = __builtin_amdgcn_mfma_f32_16x16x32_f16(ah, blf, acc[mf], 0, 0, 0);
      }
    }
  }
}

// ------- batched 256x256 @ 256xN; C = a1*(A@B) + d1*I + e1*E (E optional)
__global__ __launch_bounds__(256) void k_bmm_poly(
    const float* __restrict__ A, const float* __restrict__ Bm,
    const float* __restrict__ E, float* __restrict__ C, float a1, float d1, float e1,
    int N) {
  __shared__ short Ash[64][136];
  __shared__ short Asl[64][136];
  __shared__ short Bsh[64][136];
  __shared__ short Bsl[64][136];
  const int t = threadIdx.x;
  const int bh = blockIdx.z;
  const int i0 = blockIdx.y * 64, j0 = blockIdx.x * 64;
  const int lane = t & 63, w = t >> 6;
  const int fr = lane & 15, kg = lane >> 4;
  f32x4 acc[4];
  f32x4 zero4 = {0.f, 0.f, 0.f, 0.f};
#pragma unroll
  for (int i = 0; i < 4; ++i) acc[i] = zero4;
  bmm_core(Ash, Asl, Bsh, Bsl, A + (size_t)bh * 65536, Bm + (size_t)bh * 256 * N, i0,
           j0, N, t, acc);
  int j = j0 + w * 16 + fr;
#pragma unroll
  for (int mf = 0; mf < 4; ++mf) {
#pragma unroll
    for (int rr = 0; rr < 4; ++rr) {
      int i = i0 + mf * 16 + kg * 4 + rr;
      float v = acc[mf][rr];
      size_t off = (size_t)bh * 256 * N + (size_t)i * N + j;
      float out = a1 * v + ((i == j) ? d1 : 0.f);
      if (E) out += e1 * E[off];
      C[off] = out;
    }
  }
}

// ------- dual batched: z<16: C0 = s*(A0@B); z>=16: C1 = s*(A1@B)   (N=256)
__global__ __launch_bounds__(256) void k_bmm_dual(
    const float* __restrict__ A0, const float* __restrict__ A1,
    const float* __restrict__ Bm, float* __restrict__ C0, float* __restrict__ C1,
    float s) {
  __shared__ short Ash[64][136];
  __shared__ short Asl[64][136];
  __shared__ short Bsh[64][136];
  __shared__ short Bsl[64][136];
  const int t = threadIdx.x;
  const int z = blockIdx.z;
  const int bh = z & 15;
  const int sel = z >> 4;
  const float* A = sel ? A1 : A0;
  float* C = sel ? C1 : C0;
  const int i0 = blockIdx.y * 64, j0 = blockIdx.x * 64;
  const int lane = t & 63, w = t >> 6;
  const int fr = lane & 15, kg = lane >> 4;
  f32x4 acc[4];
  f32x4 zero4 = {0.f, 0.f, 0.f, 0.f};
#pragma unroll
  for (int i = 0; i < 4; ++i) acc[i] = zero4;
  bmm_core(Ash, Asl, Bsh, Bsl, A + (size_t)bh * 65536, Bm + (size_t)bh * 65536, i0, j0,
           256, t, acc);
  int j = j0 + w * 16 + fr;
#pragma unroll
  for (int mf = 0; mf < 4; ++mf) {
#pragma unroll
    for (int rr = 0; rr < 4; ++rr) {
      int i = i0 + mf * 16 + kg * 4 + rr;
      size_t off = (size_t)bh * 65536 + (size_t)i * 256 + j;
      C[off] = s * acc[mf][rr];
    }
  }
}

// -------------------------- a3 @ v : MFMA flash (f16 qkv, no-max, split-K chunks)
__global__ __launch_bounds__(256, 2) void k_a3v_mfma(
    float* __restrict__ pacc, float* __restrict__ pL,
    const float* __restrict__ ql, const unsigned short* __restrict__ qkv) {
  __shared__ short Ks[64][72];
  __shared__ short Vt[64][72];
  __shared__ short Ps[4][64][72];
  const int t = threadIdx.x;
  const int bh = blockIdx.x;
  const int kc = blockIdx.y;
  const int b = bh >> 3, h = bh & 7;
  const int lane = t & 63, w = t >> 6;
  const int fr = lane & 15, kg = lane >> 4;

  f16x8 qf[4][2];
#pragma unroll
  for (int nf = 0; nf < 4; ++nf) {
    const float* qp = ql + ((size_t)bh * 256 + w * 64 + nf * 16 + fr) * 64 + kg * 8;
#pragma unroll
    for (int kw = 0; kw < 2; ++kw) {
      float4 a = *(const float4*)(qp + kw * 32);
      float4 c = *(const float4*)(qp + kw * 32 + 4);
      uint4 uu = make_uint4(pk_f16(a.x, a.y), pk_f16(a.z, a.w), pk_f16(c.x, c.y),
                            pk_f16(c.z, c.w));
      qf[nf][kw] = *(f16x8*)&uu;
    }
  }
  f32x4 oacc[4][4];
  f32x4 zero4 = {0.f, 0.f, 0.f, 0.f};
#pragma unroll
  for (int i = 0; i < 4; ++i)
#pragma unroll
    for (int j = 0; j < 4; ++j) oacc[i][j] = zero4;
  float Lp[4] = {0.f, 0.f, 0.f, 0.f};

  const int skey = t >> 2, sd = (t & 3) * 16;
  const unsigned short* kbase = qkv + (size_t)b * NPAD * 1536 + 512 + h * 64 + sd;

  for (int it = 0; it < A3CH / 64; ++it) {
    int nt = kc * A3CH + it * 64;
    __syncthreads();
    {
      const unsigned short* kp = kbase + (size_t)(nt + skey) * 1536;
      *(uint4*)&Ks[skey][sd] = *(const uint4*)kp;
      *(uint4*)&Ks[skey][sd + 8] = *(const uint4*)(kp + 8);
      const unsigned short* vp = kp + 512;
      uint4 v01 = *(const uint4*)vp;
      uint4 v23 = *(const uint4*)(vp + 8);
      Vt[sd + 0][skey] = (short)v01.x;
      Vt[sd + 1][skey] = (short)(v01.x >> 16);
      Vt[sd + 2][skey] = (short)v01.y;
      Vt[sd + 3][skey] = (short)(v01.y >> 16);
      Vt[sd + 4][skey] = (short)v01.z;
      Vt[sd + 5][skey] = (short)(v01.z >> 16);
      Vt[sd + 6][skey] = (short)v01.w;
      Vt[sd + 7][skey] = (short)(v01.w >> 16);
      Vt[sd + 8][skey] = (short)v23.x;
      Vt[sd + 9][skey] = (short)(v23.x >> 16);
      Vt[sd + 10][skey] = (short)v23.y;
      Vt[sd + 11][skey] = (short)(v23.y >> 16);
      Vt[sd + 12][skey] = (short)v23.z;
      Vt[sd + 13][skey] = (short)(v23.z >> 16);
      Vt[sd + 14][skey] = (short)v23.w;
      Vt[sd + 15][skey] = (short)(v23.w >> 16);
    }
    __syncthreads();
    f32x4 sacc[4][4];
#pragma unroll
    for (int i = 0; i < 4; ++i)
#pragma unroll
      for (int j = 0; j < 4; ++j) sacc[i][j] = zero4;
#pragma unroll
    for (int kw = 0; kw < 2; ++kw) {
      f16x8 kf[4];
#pragma unroll
      for (int mf = 0; mf < 4; ++mf)
        kf[mf] = *(const f16x8*)&Ks[mf * 16 + fr][kw * 32 + kg * 8];
#pragma unroll
      for (int mf = 0; mf < 4; ++mf)
#pragma unroll
        for (int nf = 0; nf < 4; ++nf)
          sacc[mf][nf] = __builtin_amdgcn_mfma_f32_16x16x32_f16(kf[mf], qf[nf][kw],
                                                                sacc[mf][nf], 0, 0, 0);
    }
#pragma unroll
    for (int mf = 0; mf < 4; ++mf)
#pragma unroll
      for (int nf = 0; nf < 4; ++nf) {
        f32x4 s = sacc[mf][nf];
        float p0 = __expf(s[0]);
        float p1 = __expf(s[1]);
        float p2 = __expf(s[2]);
        float p3 = __expf(s[3]);
        Lp[nf] += (p0 + p1) + (p2 + p3);
        uint2 pw = make_uint2(pk_f16(p0, p1), pk_f16(p2, p3));
        *(uint2*)&Ps[w][nf * 16 + fr][mf * 16 + kg * 4] = pw;
      }
    __syncthreads();
#pragma unroll
    for (int kw = 0; kw < 2; ++kw) {
      f16x8 vf[4], pf[4];
#pragma unroll
      for (int mf = 0; mf < 4; ++mf)
        vf[mf] = *(const f16x8*)&Vt[mf * 16 + fr][kw * 32 + kg * 8];
#pragma unroll
      for (int nf = 0; nf < 4; ++nf)
        pf[nf] = *(const f16x8*)&Ps[w][nf * 16 + fr][kw * 32 + kg * 8];
#pragma unroll
      for (int mf = 0; mf < 4; ++mf)
#pragma unroll
        for (int nf = 0; nf < 4; ++nf)
          oacc[mf][nf] = __builtin_amdgcn_mfma_f32_16x16x32_f16(vf[mf], pf[nf],
                                                                oacc[mf][nf], 0, 0, 0);
    }
  }
  size_t obase = ((size_t)kc * 16 + bh) * 256;
#pragma unroll
  for (int mf = 0; mf < 4; ++mf)
#pragma unroll
    for (int nf = 0; nf < 4; ++nf) {
      int lm = w * 64 + nf * 16 + fr;
      *(f32x4*)(pacc + (obase + lm) * 64 + mf * 16 + kg * 4) = oacc[mf][nf];
    }
#pragma unroll
  for (int nf = 0; nf < 4; ++nf) {
    Lp[nf] += __shfl_xor(Lp[nf], 16);
    Lp[nf] += __shfl_xor(Lp[nf], 32);
  }
  if (lane < 16) {
#pragma unroll
    for (int nf = 0; nf < 4; ++nf)
      pL[obase + w * 64 + nf * 16 + lane] = Lp[nf];
  }
}

__global__ __launch_bounds__(64) void k_a3v_red(
    float* __restrict__ bv, const float* __restrict__ pacc,
    const float* __restrict__ pL) {
  int row = blockIdx.x;
  int d = threadIdx.x;
  float A = 0.f, L = 0.f;
#pragma unroll
  for (int c = 0; c < A3KC; ++c) {
    size_t pr = (size_t)c * 4096 + row;
    A += pacc[pr * 64 + d];
    L += pL[pr];
  }
  bv[(size_t)row * 64 + d] = A / L;
}

// ------------- fused sim1: softmax(q @ (0.125*kl)^T) @ w2 -> single f16 attout
__global__ __launch_bounds__(256, 2) void k_att1(
    unsigned short* __restrict__ attf, const unsigned short* __restrict__ qkv,
    const float* __restrict__ kl, const float* __restrict__ w2) {
  __shared__ short KLs[64][72];
  __shared__ short W2t[64][72];
  __shared__ short Ps[4][64][72];
  const int t = threadIdx.x;
  const int tile = blockIdx.x, bh = blockIdx.y;
  const int b = bh >> 3, h = bh & 7;
  const int lane = t & 63, w = t >> 6;
  const int fr = lane & 15, kg = lane >> 4;
  const int n0 = tile * 256;

  f16x8 qf[4][2];
#pragma unroll
  for (int nf = 0; nf < 4; ++nf) {
    const unsigned short* qp =
        qkv + ((size_t)b * NPAD + n0 + w * 64 + nf * 16 + fr) * 1536 + h * 64 + kg * 8;
    qf[nf][0] = *(const f16x8*)qp;
    qf[nf][1] = *(const f16x8*)(qp + 32);
  }
  f32x4 oacc[4][4];
  f32x4 zero4 = {0.f, 0.f, 0.f, 0.f};
#pragma unroll
  for (int i = 0; i < 4; ++i)
#pragma unroll
    for (int j = 0; j < 4; ++j) oacc[i][j] = zero4;
  float Lp[4] = {0.f, 0.f, 0.f, 0.f};

  const int sr = t >> 2, sc = (t & 3) * 16;
  for (int cb = 0; cb < 4; ++cb) {
    __syncthreads();
    {
      const float* kp = kl + ((size_t)bh * 256 + cb * 64 + sr) * 64 + sc;
      float4 k0 = *(const float4*)kp;
      float4 k1 = *(const float4*)(kp + 4);
      float4 k2 = *(const float4*)(kp + 8);
      float4 k3 = *(const float4*)(kp + 12);
      *(uint4*)&KLs[sr][sc] =
          make_uint4(pk_f16(k0.x * 0.125f, k0.y * 0.125f),
                     pk_f16(k0.z * 0.125f, k0.w * 0.125f),
                     pk_f16(k1.x * 0.125f, k1.y * 0.125f),
                     pk_f16(k1.z * 0.125f, k1.w * 0.125f));
      *(uint4*)&KLs[sr][sc + 8] =
          make_uint4(pk_f16(k2.x * 0.125f, k2.y * 0.125f),
                     pk_f16(k2.z * 0.125f, k2.w * 0.125f),
                     pk_f16(k3.x * 0.125f, k3.y * 0.125f),
                     pk_f16(k3.z * 0.125f, k3.w * 0.125f));
      const float* wp = w2 + ((size_t)bh * 256 + cb * 64 + sr) * 64 + sc;
      float4 v0 = *(const float4*)wp;
      float4 v1 = *(const float4*)(wp + 4);
      float4 v2 = *(const float4*)(wp + 8);
      float4 v3 = *(const float4*)(wp + 12);
      W2t[sc + 0][sr] = (short)f16_1(v0.x);
      W2t[sc + 1][sr] = (short)f16_1(v0.y);
      W2t[sc + 2][sr] = (short)f16_1(v0.z);
      W2t[sc + 3][sr] = (short)f16_1(v0.w);
      W2t[sc + 4][sr] = (short)f16_1(v1.x);
      W2t[sc + 5][sr] = (short)f16_1(v1.y);
      W2t[sc + 6][sr] = (short)f16_1(v1.z);
      W2t[sc + 7][sr] = (short)f16_1(v1.w);
      W2t[sc + 8][sr] = (short)f16_1(v2.x);
      W2t[sc + 9][sr] = (short)f16_1(v2.y);
      W2t[sc + 10][sr] = (short)f16_1(v2.z);
      W2t[sc + 11][sr] = (short)f16_1(v2.w);
      W2t[sc + 12][sr] = (short)f16_1(v3.x);
      W2t[sc + 13][sr] = (short)f16_1(v3.y);
      W2t[sc + 14][sr] = (short)f16_1(v3.z);
      W2t[sc + 15][sr] = (short)f16_1(v3.w);
    }
    __syncthreads();
    f32x4 sacc[4][4];
#pragma unroll
    for (int i = 0; i < 4; ++i)
#pragma unroll
      for (int j = 0; j < 4; ++j) sacc[i][j] = zero4;
#pragma unroll
    for (int kw = 0; kw < 2; ++kw) {
      f16x8 kf[4];
#pragma unroll
      for (int mf = 0; mf < 4; ++mf)
        kf[mf] = *(const f16x8*)&KLs[mf * 16 + fr][kw * 32 + kg * 8];
#pragma unroll
      for (int mf = 0; mf < 4; ++mf)
#pragma unroll
        for (int nf = 0; nf < 4; ++nf)
          sacc[mf][nf] = __builtin_amdgcn_mfma_f32_16x16x32_f16(kf[mf], qf[nf][kw],
                                                                sacc[mf][nf], 0, 0, 0);
    }
#pragma unroll
    for (int mf = 0; mf < 4; ++mf)
#pragma unroll
      for (int nf = 0; nf < 4; ++nf) {
        f32x4 s = sacc[mf][nf];
        float p0 = __expf(s[0]);
        float p1 = __expf(s[1]);
        float p2 = __expf(s[2]);
        float p3 = __expf(s[3]);
        Lp[nf] += (p0 + p1) + (p2 + p3);
        uint2 pw = make_uint2(pk_f16(p0, p1), pk_f16(p2, p3));
        *(uint2*)&Ps[w][nf * 16 + fr][mf * 16 + kg * 4] = pw;
      }
    __syncthreads();
#pragma unroll
    for (int kw = 0; kw < 2; ++kw) {
      f16x8 vf[4], pf[4];
#pragma unroll
      for (int mf = 0; mf < 4; ++mf)
        vf[mf] = *(const f16x8*)&W2t[mf * 16 + fr][kw * 32 + kg * 8];
#pragma unroll
      for (int nf = 0; nf < 4; ++nf)
        pf[nf] = *(const f16x8*)&Ps[w][nf * 16 + fr][kw * 32 + kg * 8];
#pragma unroll
      for (int mf = 0; mf < 4; ++mf)
#pragma unroll
        for (int nf = 0; nf < 4; ++nf)
          oacc[mf][nf] = __builtin_amdgcn_mfma_f32_16x16x32_f16(vf[mf], pf[nf],
                                                                oacc[mf][nf], 0, 0, 0);
    }
  }
#pragma unroll
  for (int nf = 0; nf < 4; ++nf) {
    Lp[nf] += __shfl_xor(Lp[nf], 16);
    Lp[nf] += __shfl_xor(Lp[nf], 32);
  }
#pragma unroll
  for (int nf = 0; nf < 4; ++nf) {
    float inv = 1.0f / Lp[nf];
    int tok = n0 + w * 64 + nf * 16 + fr;
#pragma unroll
    for (int mf = 0; mf < 4; ++mf) {
      f32x4 o = oacc[mf][nf];
      ushort4 hs;
      hs.x = f16_1(o[0] * inv);
      hs.y = f16_1(o[1] * inv);
      hs.z = f16_1(o[2] * inv);
      hs.w = f16_1(o[3] * inv);
      *(ushort4*)(attf + ((size_t)b * NPAD + tok) * DD + h * 64 + mf * 16 + kg * 4) = hs;
    }
  }
}

// ---------------- attf += depthwise33(v); sliding-window (40 LDS loads/thread)
__global__ __launch_bounds__(256) void k_convres(
    unsigned short* __restrict__ attf, const unsigned short* __restrict__ qkv,
    const float* __restrict__ resw) {
  __shared__ float vS[96][68];
  __shared__ float w33[33];
  int t = threadIdx.x;
  int tb = blockIdx.x, bh = blockIdx.y;
  int b = bh >> 3, h = bh & 7;
  int n0 = tb * 64;
  if (t < 33) w33[t] = resw[h * 33 + t];
  int sc = (t & 3) * 16;
#pragma unroll
  for (int pass = 0; pass < 2; ++pass) {
    int r = (t >> 2) + pass * 64;
    if (r < 96) {
      int seq = n0 - 16 + r;
      if (seq >= 0 && seq < NPAD) {
        const unsigned short* p =
            qkv + ((size_t)b * NPAD + seq) * 1536 + 1024 + h * 64 + sc;
        uint4 u0 = *(const uint4*)p;
        uint4 u1 = *(const uint4*)(p + 8);
        float4 f0 = make_float4(f16f(u0.x), f16f(u0.x >> 16), f16f(u0.y),
                                f16f(u0.y >> 16));
        float4 f1 = make_float4(f16f(u0.z), f16f(u0.z >> 16), f16f(u0.w),
                                f16f(u0.w >> 16));
        float4 f2 = make_float4(f16f(u1.x), f16f(u1.x >> 16), f16f(u1.y),
                                f16f(u1.y >> 16));
        float4 f3 = make_float4(f16f(u1.z), f16f(u1.z >> 16), f16f(u1.w),
                                f16f(u1.w >> 16));
        *(float4*)&vS[r][sc + 0] = f0;
        *(float4*)&vS[r][sc + 4] = f1;
        *(float4*)&vS[r][sc + 8] = f2;
        *(float4*)&vS[r][sc + 12] = f3;
      } else {
        float4 z = make_float4(0.f, 0.f, 0.f, 0.f);
        *(float4*)&vS[r][sc + 0] = z;
        *(float4*)&vS[r][sc + 4] = z;
        *(float4*)&vS[r][sc + 8] = z;
        *(float4*)&vS[r][sc + 12] = z;
      }
    }
  }
  __syncthreads();
  int tg = t >> 5;
  int d2 = (t & 31) * 2;
  float ax[8], ay[8];
#pragma unroll
  for (int j = 0; j < 8; ++j) { ax[j] = 0.f; ay[j] = 0.f; }
  // rows tg*8 .. tg*8+39 cover taps k=0..32 for the 8 tokens tg*8+j
#pragma unroll
  for (int rr = 0; rr < 40; ++rr) {
    float2 v = *(float2*)&vS[tg * 8 + rr][d2];
#pragma unroll
    for (int j = 0; j < 8; ++j) {
      int k = rr - j;
      if (k >= 0 && k < 33) {
        ax[j] += w33[k] * v.x;
        ay[j] += w33[k] * v.y;
      }
    }
  }
#pragma unroll
  for (int j = 0; j < 8; ++j) {
    size_t off = ((size_t)b * NPAD + n0 + tg * 8 + j) * DD + h * 64 + d2;
    unsigned u = *(unsigned*)(attf + off);
    float x0 = f16f(u) + ax[j];
    float x1 = f16f(u >> 16) + ay[j];
    *(unsigned*)(attf + off) = pk_f16(x0, x1);
  }
}

// ---------------------------------------------------------------- PPEG (combined 7x7)
__global__ __launch_bounds__(128) void k_ppeg(
    float* __restrict__ hB, const float* __restrict__ hA,
    const float* __restrict__ w7, const float* __restrict__ b7,
    const float* __restrict__ w5, const float* __restrict__ b5,
    const float* __restrict__ w3, const float* __restrict__ b3) {
  __shared__ float cw[49][128];
  int t = threadIdx.x;
  int i = blockIdx.x >> 2;
  int j0 = (blockIdx.x & 3) * 32;
  int cg = blockIdx.y, b = blockIdx.z;
  int c = cg * 128 + t;
#pragma unroll
  for (int k = 0; k < 49; ++k) cw[k][t] = w7[c * 49 + k];
#pragma unroll
  for (int di = 0; di < 5; ++di)
#pragma unroll
    for (int dj = 0; dj < 5; ++dj)
      cw[(di + 1) * 7 + dj + 1][t] += w5[c * 25 + di * 5 + dj];
#pragma unroll
  for (int di = 0; di < 3; ++di)
#pragma unroll
    for (int dj = 0; dj < 3; ++dj)
      cw[(di + 2) * 7 + dj + 2][t] += w3[c * 9 + di * 3 + dj];
  cw[24][t] += 1.0f;
  float bias = b7[c] + b5[c] + b3[c];
  const float* base = hA + (size_t)b * TT * DD + DD + c;
  float* obase = hB + (size_t)b * TT * DD + DD + c;
  float acc[32];
#pragma unroll
  for (int j = 0; j < 32; ++j) acc[j] = bias;
  for (int di = 0; di < 7; ++di) {
    int ii = i + di - 3;
    if ((unsigned)ii >= 128u) continue;
    float win[38];
#pragma unroll
    for (int w = 0; w < 38; ++w) {
      int col = j0 - 3 + w;
      win[w] = ((unsigned)col < 128u) ? base[(size_t)(ii * 128 + col) * DD] : 0.f;
    }
#pragma unroll
    for (int dj = 0; dj < 7; ++dj) {
      float wv = cw[di * 7 + dj][t];
#pragma unroll
      for (int j = 0; j < 32; ++j) acc[j] += win[j + dj] * wv;
    }
  }
#pragma unroll
  for (int j = 0; j < 32; ++j) obase[(size_t)(i * 128 + j0 + j) * DD] = acc[j];
}

// ---------------------------------------------------------------- final head
__global__ __launch_bounds__(512) void k_final(
    float* __restrict__ out, const float* __restrict__ h,
    const float* __restrict__ g, const float* __restrict__ be,
    const float* __restrict__ cw, const float* __restrict__ cbias) {
  __shared__ float sm[16];
  int t = threadIdx.x;
  for (int b = 0; b < 2; ++b) {
    const float* row = h + (size_t)b * TT * DD;
    float x = row[t];
    float s = x;
    for (int o = 32; o; o >>= 1) s += __shfl_xor(s, o);
    if ((t & 63) == 0) sm[t >> 6] = s;
    __syncthreads();
    float mu = 0.f;
    for (int i = 0; i < 8; ++i) mu += sm[i];
    mu *= (1.f / 512.f);
    __syncthreads();
    float d = x - mu;
    s = d * d;
    for (int o = 32; o; o >>= 1) s += __shfl_xor(s, o);
    if ((t & 63) == 0) sm[t >> 6] = s;
    __syncthreads();
    float var = 0.f;
    for (int i = 0; i < 8; ++i) var += sm[i];
    var *= (1.f / 512.f);
    float rs = rsqrtf(var + 1e-5f);
    __syncthreads();
    float f = d * rs * g[t] + be[t];
    float p0 = f * cw[2 * t], p1 = f * cw[2 * t + 1];
    for (int o = 32; o; o >>= 1) {
      p0 += __shfl_xor(p0, o);
      p1 += __shfl_xor(p1, o);
    }
    if ((t & 63) == 0) {
      sm[t >> 6] = p0;
      sm[8 + (t >> 6)] = p1;
    }
    __syncthreads();
    if (t == 0) {
      float q0 = 0.f, q1 = 0.f;
      for (int i = 0; i < 8; ++i) {
        q0 += sm[i];
        q1 += sm[8 + i];
      }
      out[b * 2 + 0] = q0 + cbias[0];
      out[b * 2 + 1] = q1 + cbias[1];
    }
    __syncthreads();
  }
}

// ---------------------------------------------------------------- host side
static void run_attn(float* h, const float* lng, const float* lnb,
                     const float* wqkv, const float* wout, const float* bout,
                     const float* resw, float* xp, unsigned short* qkvh, float* ql,
                     float* kl, float* a2, float* z0, float* z1, float* xz, float* xz2,
                     float* yB, float* yC, float* bv, float* w2, float* red,
                     float* Sbuf, unsigned short* wth, hipStream_t stream) {
  // xp region: [single f16 plane: LN output, later attention output]
  unsigned short* xph = (unsigned short*)xp;
  k_zero_pad<<<BB * PADF, 256, 0, stream>>>(xph);
  k_ln_pad<<<(BB * TT + 3) / 4, 256, 0, stream>>>(xph, h, lng, lnb);
  k_cvt_wt<<<dim3(DD / 32, 1536 / 32), 256, 0, stream>>>(wqkv, wth, DD, 1536);
  k_gemm_qkv8<<<dim3(BB * NPAD / 128, 1536 / 256), 512, 0, stream>>>(xph, wth, qkvh);
  k_landmarks<<<1024, 256, 0, stream>>>(ql, kl, qkvh);
  float* pacc = Sbuf;
  float* pL = Sbuf + (size_t)A3KC * 4096 * 64;
  k_a3v_mfma<<<dim3(16, A3KC), 256, 0, stream>>>(pacc, pL, ql, qkvh);
  k_a3v_red<<<4096, 64, 0, stream>>>(bv, pacc, pL);
  k_sim2<<<dim3(4, 4, 16), 256, 0, stream>>>(a2, ql, kl);
  k_softmax256<<<1024, 256, 0, stream>>>(a2);
  k_pinv_sums<<<16, 256, 0, stream>>>(red, a2);
  k_pinv_scale<<<1, 256, 0, stream>>>(red);
  k_zinit<<<dim3(256, 16), 256, 0, stream>>>(z0, a2, red);
  // Newton-Schulz: 3 matmuls/iter via P = a2@z carried forward
  float* zc = z0;
  float* zn = z1;
  float* P = xz;
  float* Pn = xz2;
  // P0 = a2 @ z0
  k_bmm_poly<<<dim3(4, 4, 16), 256, 0, stream>>>(a2, zc, nullptr, P, 1.f, 0.f, 0.f, 256);
  for (int it = 0; it < 6; ++it) {
    // yB = P@P + 15I - 7P   (== 15I - P@(7I - P))
    k_bmm_poly<<<dim3(4, 4, 16), 256, 0, stream>>>(P, P, P, yB, 1.f, 15.f, -7.f, 256);
    // yC = 13I - P@yB
    k_bmm_poly<<<dim3(4, 4, 16), 256, 0, stream>>>(P, yB, nullptr, yC, -1.f, 13.f, 0.f, 256);
    // zn = 0.25 zc@yC ; Pn = 0.25 P@yC  (batched)
    k_bmm_dual<<<dim3(4, 4, 32), 256, 0, stream>>>(zc, P, yC, zn, Pn, 0.25f);
    float* tmp = zc; zc = zn; zn = tmp;
    tmp = P; P = Pn; Pn = tmp;
  }
  k_bmm_poly<<<dim3(1, 4, 16), 256, 0, stream>>>(zc, bv, nullptr, w2, 1.f, 0.f, 0.f, 64);
  // attention output as single f16 in xph (LN plane is dead after qkv GEMM)
  k_att1<<<dim3(NPAD / 256, 16), 256, 0, stream>>>(xph, qkvh, kl, w2);
  k_convres<<<dim3(NPAD / 64, 16), 256, 0, stream>>>(xph, qkvh, resw);
  k_cvt_wt<<<dim3(DD / 32, DD / 32), 256, 0, stream>>>(wout, wth, DD, DD);
  k_gemm_proj<<<dim3(129, 2, BB), 512, 0, stream>>>(xph, wth, h, bout);
}

extern "C" void kernel_launch(void* const* d_in, const int* in_sizes, int n_in,
                              void* d_out, int out_size, void* d_ws, size_t ws_size,
                              hipStream_t stream) {
  const float* x        = (const float*)d_in[0];
  const float* w_feat   = (const float*)d_in[1];
  const float* b_feat   = (const float*)d_in[2];
  const float* cls_tok  = (const float*)d_in[3];
  const float* ln1_g    = (const float*)d_in[4];
  const float* ln1_b    = (const float*)d_in[5];
  const float* qkv1     = (const float*)d_in[6];
  const float* out1_w   = (const float*)d_in[7];
  const float* out1_b   = (const float*)d_in[8];
  const float* res1_w   = (const float*)d_in[9];
  const float* ppeg_w7  = (const float*)d_in[10];
  const float* ppeg_b7  = (const float*)d_in[11];
  const float* ppeg_w5  = (const float*)d_in[12];
  const float* ppeg_b5  = (const float*)d_in[13];
  const float* ppeg_w3  = (const float*)d_in[14];
  const float* ppeg_b3  = (const float*)d_in[15];
  const float* ln2_g    = (const float*)d_in[16];
  const float* ln2_b    = (const float*)d_in[17];
  const float* qkv2     = (const float*)d_in[18];
  const float* out2_w   = (const float*)d_in[19];
  const float* out2_b   = (const float*)d_in[20];
  const float* res2_w   = (const float*)d_in[21];
  const float* lnf_g    = (const float*)d_in[22];
  const float* lnf_b    = (const float*)d_in[23];
  const float* cls_w    = (const float*)d_in[24];
  const float* cls_b    = (const float*)d_in[25];

  float* ws = (float*)d_ws;
  size_t off = 0;
  float* hA  = ws + off; off += (size_t)BB * TT * DD;
  float* hB  = ws + off; off += (size_t)BB * TT * DD;
  float* xp  = ws + off; off += (size_t)BB * NPAD * DD;
  float* qkvf = ws + off; off += (size_t)BB * NPAD * 3 * DD;  // used as f16 (half)
  unsigned short* qkvh = (unsigned short*)qkvf;
  float* ql  = ws + off; off += (size_t)BB * HH * 256 * 64;
  float* kl  = ws + off; off += (size_t)BB * HH * 256 * 64;
  float* a2  = ws + off; off += (size_t)16 * 65536;
  float* z0  = ws + off; off += (size_t)16 * 65536;
  float* z1  = ws + off; off += (size_t)16 * 65536;
  float* xz  = ws + off; off += (size_t)16 * 65536;
  float* xz2 = ws + off; off += (size_t)16 * 65536;
  float* yB  = ws + off; off += (size_t)16 * 65536;
  float* yC  = ws + off; off += (size_t)16 * 65536;
  float* bv  = ws + off; off += (size_t)BB * HH * 256 * 64;
  float* w2  = ws + off; off += (size_t)BB * HH * 256 * 64;
  float* red = ws + off; off += 8448;
  unsigned short* wth = (unsigned short*)(ws + off); off += 393216;

  // Stage 1: h = gelu(x @ w_feat + b_feat), prepend cls token
  // (x pre-rounded to f16 in the then-dead qkvh buffer; pipelined GEMM)
  k_set_cls<<<2, 512, 0, stream>>>(hA, cls_tok);
  k_cvt_wt<<<dim3(1024 / 32, DD / 32), 256, 0, stream>>>(w_feat, wth, 1024, DD);
  k_cvt_x<<<16384, 256, 0, stream>>>(qkvh, x);
  k_gemm_feat<<<dim3(256, 2), 512, 0, stream>>>(qkvh, wth, hA, b_feat);
  // Attention 1 (residual in-place on hA; hB is dead -> scratch)
  run_attn(hA, ln1_g, ln1_b, qkv1, out1_w, out1_b, res1_w, xp, qkvh, ql, kl, a2, z0, z1,
           xz, xz2, yB, yC, bv, w2, red, hB, wth, stream);
  // PPEG: hB = ppeg(hA)
  k_copy_cls<<<2, 512, 0, stream>>>(hB, hA);
  k_ppeg<<<dim3(512, 4, 2), 128, 0, stream>>>(hB, hA, ppeg_w7, ppeg_b7, ppeg_w5, ppeg_b5,
                                              ppeg_w3, ppeg_b3);
  // Attention 2 (residual in-place on hB; hA is dead -> scratch)
  run_attn(hB, ln2_g, ln2_b, qkv2, out2_w, out2_b, res2_w, xp, qkvh, ql, kl, a2, z0, z1,
           xz, xz2, yB, yC, bv, w2, red, hA, wth, stream);
  // Final: LN(cls) @ cls_w + cls_b
  k_final<<<1, 512, 0, stream>>>((float*)d_out, hB, lnf_g, lnf_b, cls_w, cls_b);
}

// Round 25
// 1342.750 us; speedup vs baseline: 1.2632x; 1.0122x over previous
//
#include <hip/hip_runtime.h>
#include <cstdint>
#include <cstddef>

#define BB 2
#define TT 16385
#define NPAD 16640
#define DD 512
#define HH 8
#define DHH 64
#define MLAND 256
#define PADF 255
#define A3KC 26
#define A3CH 640

typedef __attribute__((ext_vector_type(8))) _Float16 f16x8;
typedef __attribute__((ext_vector_type(4))) float f32x4;

__device__ __forceinline__ float gelu_f(float v) {
  float c = 0.7978845608028654f * (v + 0.044715f * v * v * v);
  return 0.5f * v * (1.0f + tanhf(c));
}

__device__ __forceinline__ unsigned short f16_1(float a) {
  _Float16 h = (_Float16)a;
  return __builtin_bit_cast(unsigned short, h);
}
__device__ __forceinline__ float f16f(unsigned u) {
  return (float)__builtin_bit_cast(_Float16, (unsigned short)(u & 0xffffu));
}
__device__ __forceinline__ unsigned pk_f16(float a, float b) {
  return (unsigned)f16_1(a) | ((unsigned)f16_1(b) << 16);
}
// split a,b into f16 hi (packed) and f16 residual-lo (packed)
__device__ __forceinline__ void split2h(float a, float b, unsigned& hi, unsigned& lo) {
  _Float16 ah = (_Float16)a, bh = (_Float16)b;
  hi = (unsigned)__builtin_bit_cast(unsigned short, ah) |
       ((unsigned)__builtin_bit_cast(unsigned short, bh) << 16);
  lo = pk_f16(a - (float)ah, b - (float)bh);
}

// async global->LDS 16B (wave-uniform LDS base + lane*16)
__device__ __forceinline__ void gload16(const unsigned short* g, short* l) {
  __builtin_amdgcn_global_load_lds(
      (const __attribute__((address_space(1))) void*)g,
      (__attribute__((address_space(3))) void*)l, 16, 0, 0);
}

// ---------------------------------------------------------------- cls rows
__global__ void k_set_cls(float* __restrict__ h, const float* __restrict__ cls) {
  h[(size_t)blockIdx.x * TT * DD + threadIdx.x] = cls[threadIdx.x];
}
__global__ void k_copy_cls(float* __restrict__ dst, const float* __restrict__ src) {
  size_t o = (size_t)blockIdx.x * TT * DD + threadIdx.x;
  dst[o] = src[o];
}

// ------------------------------------------------ x fp32 -> f16 plane
__global__ __launch_bounds__(256) void k_cvt_x(
    unsigned short* __restrict__ xh, const float* __restrict__ x) {
  size_t i = ((size_t)blockIdx.x * 256 + threadIdx.x) * 8;
  float4 a = *(const float4*)(x + i);
  float4 b = *(const float4*)(x + i + 4);
  uint4 u;
  u.x = pk_f16(a.x, a.y);
  u.y = pk_f16(a.z, a.w);
  u.z = pk_f16(b.x, b.y);
  u.w = pk_f16(b.z, b.w);
  *(uint4*)(xh + i) = u;
}

// ------------------------------------------------ W[K][N] -> Wt f16 [N][K]
__global__ __launch_bounds__(256) void k_cvt_wt(
    const float* __restrict__ W, unsigned short* __restrict__ Wth, int K, int N) {
  __shared__ float tile[32][33];
  int kb = blockIdx.x * 32, nb = blockIdx.y * 32;
  int t = threadIdx.x;
  int tr = t >> 3, tc4 = (t & 7) * 4;
  float4 v = *(const float4*)(W + (size_t)(kb + tr) * N + nb + tc4);
  tile[tr][tc4 + 0] = v.x;
  tile[tr][tc4 + 1] = v.y;
  tile[tr][tc4 + 2] = v.z;
  tile[tr][tc4 + 3] = v.w;
  __syncthreads();
  int n = nb + tr;
  ushort4 hs;
  hs.x = f16_1(tile[tc4 + 0][tr]);
  hs.y = f16_1(tile[tc4 + 1][tr]);
  hs.z = f16_1(tile[tc4 + 2][tr]);
  hs.w = f16_1(tile[tc4 + 3][tr]);
  *(ushort4*)(Wth + (size_t)n * K + kb + tc4) = hs;
}

// ---------------- feat GEMM: pipelined, single-f16 x, gelu+bias fp32 out
// K=1024 (32 steps), BK=32, dbuf LDS 48KB -> 3 blocks/CU, vmcnt(3), XOR swizzle.
__global__ __launch_bounds__(512) void k_gemm_feat(
    const unsigned short* __restrict__ Xh, const unsigned short* __restrict__ Wth,
    float* __restrict__ Cf, const float* __restrict__ bias) {
  __shared__ __align__(16) short Ah[2][128][32];
  __shared__ __align__(16) short Bs[2][256][32];
  const int t = threadIdx.x;
  int nRow = gridDim.x, nCol = gridDim.y;
  int lin = blockIdx.x + blockIdx.y * nRow;
  int chunk = 8 * nCol;
  int group = lin / chunk;
  int rem = lin - group * chunk;
  int gbase = group * 8;
  int Geff = nRow - gbase;
  if (Geff > 8) Geff = 8;
  const int rb = (gbase + rem % Geff) * 128;
  const int cb = (rem / Geff) * 256;
  const int lane = t & 63, wv = t >> 6;
  const int wr = wv >> 2, wc = wv & 3;
  const int fr = lane & 15, kg = lane >> 4;
  const int lr4 = lane >> 2;
  const int ss = (lane & 3) ^ (lr4 & 3);

  f32x4 acc[4][4];
  f32x4 zero4 = {0.f, 0.f, 0.f, 0.f};
#pragma unroll
  for (int i = 0; i < 4; ++i)
#pragma unroll
    for (int j = 0; j < 4; ++j) acc[i][j] = zero4;

  // stage K-step kt (K=32) into buffer bf: 3 gloads/wave (A 1, B 2)
  auto STAGE = [&](int kt, int bf) {
    const int k0 = kt * 32;
    {
      int lr = wv * 16;
      gload16(Xh + (size_t)(rb + lr + lr4) * 1024 + k0 + ss * 8, &Ah[bf][lr][0]);
    }
#pragma unroll
    for (int j = 0; j < 2; ++j) {
      int lr = wv * 32 + j * 16;
      gload16(Wth + (size_t)(cb + lr + lr4) * 1024 + k0 + ss * 8, &Bs[bf][lr][0]);
    }
  };

  STAGE(0, 0);
  STAGE(1, 1);
  const int sl = ((kg ^ (fr & 3))) * 8;
  for (int kt = 0; kt < 32; ++kt) {
    if (kt < 31) {
      asm volatile("s_waitcnt vmcnt(3)" ::: "memory");
    } else {
      asm volatile("s_waitcnt vmcnt(0)" ::: "memory");
    }
    __builtin_amdgcn_sched_barrier(0);
    __builtin_amdgcn_s_barrier();
    const int bf = kt & 1;
    f16x8 ah[4];
#pragma unroll
    for (int mf = 0; mf < 4; ++mf)
      ah[mf] = *(const f16x8*)&Ah[bf][wr * 64 + mf * 16 + fr][sl];
#pragma unroll
    for (int nf = 0; nf < 4; ++nf) {
      f16x8 bhf = *(const f16x8*)&Bs[bf][wc * 64 + nf * 16 + fr][sl];
#pragma unroll
      for (int mf = 0; mf < 4; ++mf)
        acc[mf][nf] =
            __builtin_amdgcn_mfma_f32_16x16x32_f16(ah[mf], bhf, acc[mf][nf], 0, 0, 0);
    }
    __builtin_amdgcn_s_barrier();
    if (kt + 2 < 32) STAGE(kt + 2, bf);
  }
#pragma unroll
  for (int mf = 0; mf < 4; ++mf) {
#pragma unroll
    for (int r = 0; r < 4; ++r) {
      int row = rb + wr * 64 + mf * 16 + kg * 4 + r;
      size_t orow = (size_t)(row + (row >> 14) + 1);
#pragma unroll
      for (int nf = 0; nf < 4; ++nf) {
        int col = cb + wc * 64 + nf * 16 + fr;
        Cf[orow * DD + col] = gelu_f(acc[mf][nf][r] + bias[col]);
      }
    }
  }
}

// ---------------- qkv GEMM: pipelined, single-f16 A (LN output), f16 out
// BK=32, dbuf LDS 48KB -> 3 blocks/CU, 2-deep prefetch, vmcnt(3), XOR swizzle.
__global__ __launch_bounds__(512) void k_gemm_qkv8(
    const unsigned short* __restrict__ Aph, const unsigned short* __restrict__ Wth,
    unsigned short* __restrict__ Ch) {
  __shared__ __align__(16) short Ah[2][128][32];
  __shared__ __align__(16) short Bs[2][256][32];
  const int t = threadIdx.x;
  // L2 block swizzle
  int nRow = gridDim.x, nCol = gridDim.y;
  int lin = blockIdx.x + blockIdx.y * nRow;
  int chunk = 8 * nCol;
  int group = lin / chunk;
  int rem = lin - group * chunk;
  int gbase = group * 8;
  int Geff = nRow - gbase;
  if (Geff > 8) Geff = 8;
  const int rb = (gbase + rem % Geff) * 128;
  const int cb = (rem / Geff) * 256;
  const int lane = t & 63, wv = t >> 6;
  const int wr = wv >> 2, wc = wv & 3;
  const int fr = lane & 15, kg = lane >> 4;
  const int lr4 = lane >> 2;                       // row-in-16 within a gload
  const int ss = (lane & 3) ^ (lr4 & 3);           // pre-swizzled src slot (16B)

  f32x4 acc[4][4];
  f32x4 zero4 = {0.f, 0.f, 0.f, 0.f};
#pragma unroll
  for (int i = 0; i < 4; ++i)
#pragma unroll
    for (int j = 0; j < 4; ++j) acc[i][j] = zero4;

  // stage K-step kt (K=32) into buffer bf: 3 gloads/wave (A 1, B 2)
  auto STAGE = [&](int kt, int bf) {
    const int k0 = kt * 32;
    {
      int lr = wv * 16;
      gload16(Aph + (size_t)(rb + lr + lr4) * DD + k0 + ss * 8, &Ah[bf][lr][0]);
    }
#pragma unroll
    for (int j = 0; j < 2; ++j) {
      int lr = wv * 32 + j * 16;
      gload16(Wth + (size_t)(cb + lr + lr4) * DD + k0 + ss * 8, &Bs[bf][lr][0]);
    }
  };

  STAGE(0, 0);
  STAGE(1, 1);
  const int sl = ((kg ^ (fr & 3))) * 8;  // swizzled read slot (shorts)
  for (int kt = 0; kt < 16; ++kt) {
    if (kt < 15) {
      asm volatile("s_waitcnt vmcnt(3)" ::: "memory");  // own tile-kt loads done
    } else {
      asm volatile("s_waitcnt vmcnt(0)" ::: "memory");  // final drain
    }
    __builtin_amdgcn_sched_barrier(0);
    __builtin_amdgcn_s_barrier();  // all waves' tile-kt data in LDS
    const int bf = kt & 1;
    f16x8 ah[4];
#pragma unroll
    for (int mf = 0; mf < 4; ++mf)
      ah[mf] = *(const f16x8*)&Ah[bf][wr * 64 + mf * 16 + fr][sl];
#pragma unroll
    for (int nf = 0; nf < 4; ++nf) {
      f16x8 bhf = *(const f16x8*)&Bs[bf][wc * 64 + nf * 16 + fr][sl];
#pragma unroll
      for (int mf = 0; mf < 4; ++mf)
        acc[mf][nf] =
            __builtin_amdgcn_mfma_f32_16x16x32_f16(ah[mf], bhf, acc[mf][nf], 0, 0, 0);
    }
    __builtin_amdgcn_s_barrier();  // all waves done reading buf bf
    if (kt + 2 < 16) STAGE(kt + 2, bf);
  }
#pragma unroll
  for (int mf = 0; mf < 4; ++mf) {
#pragma unroll
    for (int r = 0; r < 4; ++r) {
      int row = rb + wr * 64 + mf * 16 + kg * 4 + r;
#pragma unroll
      for (int nf = 0; nf < 4; ++nf) {
        int col = cb + wc * 64 + nf * 16 + fr;
        Ch[(size_t)row * 1536 + col] = f16_1(acc[mf][nf][r]);
      }
    }
  }
}

// ---------------- proj GEMM: pipelined, single-f16 A (attf), fp32 residual out
// BK=32, dbuf LDS 48KB -> 3 blocks/CU, 2-deep prefetch, vmcnt(3), XOR swizzle.
__global__ __launch_bounds__(512) void k_gemm_proj(
    const unsigned short* __restrict__ Af, const unsigned short* __restrict__ Wth,
    float* __restrict__ Cb, const float* __restrict__ bias) {
  __shared__ __align__(16) short Ah[2][128][32];
  __shared__ __align__(16) short Bs[2][256][32];
  const int t = threadIdx.x;
  int nRow = gridDim.x, nCol = gridDim.y;
  int lin = blockIdx.x + blockIdx.y * nRow;
  int chunk = 8 * nCol;
  int group = lin / chunk;
  int rem = lin - group * chunk;
  int gbase = group * 8;
  int Geff = nRow - gbase;
  if (Geff > 8) Geff = 8;
  const int rb = (gbase + rem % Geff) * 128;
  const int cb = (rem / Geff) * 256;
  const int lane = t & 63, wv = t >> 6;
  const int wr = wv >> 2, wc = wv & 3;
  const int fr = lane & 15, kg = lane >> 4;
  const int lr4 = lane >> 2;
  const int ss = (lane & 3) ^ (lr4 & 3);
  const size_t arow0 = (size_t)blockIdx.z * NPAD + PADF + rb;

  f32x4 acc[4][4];
  f32x4 zero4 = {0.f, 0.f, 0.f, 0.f};
#pragma unroll
  for (int i = 0; i < 4; ++i)
#pragma unroll
    for (int j = 0; j < 4; ++j) acc[i][j] = zero4;

  // stage K-step kt (K=32) into buffer bf: 3 gloads/wave (A 1, B 2)
  auto STAGE = [&](int kt, int bf) {
    const int k0 = kt * 32;
    {
      int lr = wv * 16;
      gload16(Af + (arow0 + lr + lr4) * DD + k0 + ss * 8, &Ah[bf][lr][0]);
    }
#pragma unroll
    for (int j = 0; j < 2; ++j) {
      int lr = wv * 32 + j * 16;
      gload16(Wth + (size_t)(cb + lr + lr4) * DD + k0 + ss * 8, &Bs[bf][lr][0]);
    }
  };

  STAGE(0, 0);
  STAGE(1, 1);
  const int sl = ((kg ^ (fr & 3))) * 8;
  for (int kt = 0; kt < 16; ++kt) {
    if (kt < 15) {
      asm volatile("s_waitcnt vmcnt(3)" ::: "memory");
    } else {
      asm volatile("s_waitcnt vmcnt(0)" ::: "memory");
    }
    __builtin_amdgcn_sched_barrier(0);
    __builtin_amdgcn_s_barrier();
    const int bf = kt & 1;
    f16x8 ah[4];
#pragma unroll
    for (int mf = 0; mf < 4; ++mf)
      ah[mf] = *(const f16x8*)&Ah[bf][wr * 64 + mf * 16 + fr][sl];
#pragma unroll
    for (int nf = 0; nf < 4; ++nf) {
      f16x8 bhf = *(const f16x8*)&Bs[bf][wc * 64 + nf * 16 + fr][sl];
#pragma unroll
      for (int mf = 0; mf < 4; ++mf)
        acc[mf][nf] =
            __builtin_amdgcn_mfma_f32_16x16x32_f16(ah[mf], bhf, acc[mf][nf], 0, 0, 0);
    }
    __builtin_amdgcn_s_barrier();
    if (kt + 2 < 16) STAGE(kt + 2, bf);
  }
  float* Cf = Cb + (size_t)blockIdx.z * TT * DD;
#pragma unroll
  for (int mf = 0; mf < 4; ++mf) {
#pragma unroll
    for (int r = 0; r < 4; ++r) {
      int row = rb + wr * 64 + mf * 16 + kg * 4 + r;
      if (row >= TT) continue;
#pragma unroll
      for (int nf = 0; nf < 4; ++nf) {
        int col = cb + wc * 64 + nf * 16 + fr;
        float old = Cf[(size_t)row * DD + col];
        Cf[(size_t)row * DD + col] = old + acc[mf][nf][r] + bias[col];
      }
    }
  }
}

// ------------------------- LN + pad -> writes single f16 plane (qkv A operand)
__global__ __launch_bounds__(256) void k_ln_pad(
    unsigned short* __restrict__ xph, const float* __restrict__ h,
    const float* __restrict__ gam, const float* __restrict__ bet) {
  int w = threadIdx.x >> 6, lane = threadIdx.x & 63;
  int row = blockIdx.x * 4 + w;
  if (row >= BB * TT) return;
  int b = row / TT, i = row - b * TT;
  const float* src = h + (size_t)row * DD;
  float4 x0 = *(const float4*)(src + lane * 4);
  float4 x1 = *(const float4*)(src + 256 + lane * 4);
  float s = x0.x + x0.y + x0.z + x0.w + x1.x + x1.y + x1.z + x1.w;
  for (int o = 32; o; o >>= 1) s += __shfl_xor(s, o);
  float mu = s * (1.f / 512.f);
  float q = (x0.x - mu) * (x0.x - mu) + (x0.y - mu) * (x0.y - mu) +
            (x0.z - mu) * (x0.z - mu) + (x0.w - mu) * (x0.w - mu) +
            (x1.x - mu) * (x1.x - mu) + (x1.y - mu) * (x1.y - mu) +
            (x1.z - mu) * (x1.z - mu) + (x1.w - mu) * (x1.w - mu);
  for (int o = 32; o; o >>= 1) q += __shfl_xor(q, o);
  float rs = rsqrtf(q * (1.f / 512.f) + 1e-5f);
  float4 g0 = *(const float4*)(gam + lane * 4);
  float4 g1 = *(const float4*)(gam + 256 + lane * 4);
  float4 b0 = *(const float4*)(bet + lane * 4);
  float4 b1 = *(const float4*)(bet + 256 + lane * 4);
  float4 o0, o1;
  o0.x = (x0.x - mu) * rs * g0.x + b0.x;
  o0.y = (x0.y - mu) * rs * g0.y + b0.y;
  o0.z = (x0.z - mu) * rs * g0.z + b0.z;
  o0.w = (x0.w - mu) * rs * g0.w + b0.w;
  o1.x = (x1.x - mu) * rs * g1.x + b1.x;
  o1.y = (x1.y - mu) * rs * g1.y + b1.y;
  o1.z = (x1.z - mu) * rs * g1.z + b1.z;
  o1.w = (x1.w - mu) * rs * g1.w + b1.w;
  size_t ro = ((size_t)b * NPAD + PADF + i) * DD;
  *(uint2*)(xph + ro + lane * 4) = make_uint2(pk_f16(o0.x, o0.y), pk_f16(o0.z, o0.w));
  *(uint2*)(xph + ro + 256 + lane * 4) =
      make_uint2(pk_f16(o1.x, o1.y), pk_f16(o1.z, o1.w));
}

__global__ void k_zero_pad(unsigned short* __restrict__ xph) {
  int r = blockIdx.x;
  int b = r / PADF, j = r - b * PADF;
  size_t ro = ((size_t)b * NPAD + j) * DD;
  ((unsigned*)(xph + ro))[threadIdx.x] = 0u;
}

// ---------------------------------------------------------------- landmarks (f16 qkv)
__global__ __launch_bounds__(256) void k_landmarks(
    float* __restrict__ ql, float* __restrict__ kl,
    const unsigned short* __restrict__ qkv) {
  int t = threadIdx.x;
  int mi = t >> 6, d = t & 63;
  int blk = blockIdx.x;
  int bh = blk >> 6, mg = blk & 63;
  int b = bh >> 3, h = bh & 7;
  int m = mg * 4 + mi;
  const unsigned short* base = qkv + (size_t)b * NPAD * 1536 + h * 64 + d;
  float sq = 0.f, sk = 0.f;
  int t0 = m * 65;
  for (int j = 0; j < 65; ++j) {
    const unsigned short* p = base + (size_t)(t0 + j) * 1536;
    sq += f16f(p[0]);
    sk += f16f(p[512]);
  }
  ql[((size_t)bh * 256 + m) * 64 + d] = sq * (0.125f / 65.f);
  kl[((size_t)bh * 256 + m) * 64 + d] = sk * (1.f / 65.f);
}

// ---------------------------------------------------------------- sim2 = ql @ kl^T
__global__ __launch_bounds__(256) void k_sim2(
    float* __restrict__ sim, const float* __restrict__ ql, const float* __restrict__ kl) {
  __shared__ __align__(16) float Aq[64][68];
  __shared__ __align__(16) float Bk[64][68];
  int t = threadIdx.x;
  int tj = blockIdx.x, ti = blockIdx.y, bh = blockIdx.z;
  int r = t >> 2, cc = (t & 3) * 16;
  const float* ap = ql + ((size_t)bh * 256 + ti * 64 + r) * 64 + cc;
  const float* bp = kl + ((size_t)bh * 256 + tj * 64 + r) * 64 + cc;
#pragma unroll
  for (int i = 0; i < 16; i += 4) {
    *(float4*)&Aq[r][cc + i] = *(const float4*)(ap + i);
    *(float4*)&Bk[r][cc + i] = *(const float4*)(bp + i);
  }
  __syncthreads();
  int tx = t & 15, ty = t >> 4;
  float acc[4][4];
#pragma unroll
  for (int i = 0; i < 4; ++i)
#pragma unroll
    for (int j = 0; j < 4; ++j) acc[i][j] = 0.f;
  for (int d = 0; d < 64; d += 4) {
    float4 a4[4], b4[4];
#pragma unroll
    for (int ii = 0; ii < 4; ++ii) a4[ii] = *(float4*)&Aq[ty * 4 + ii][d];
#pragma unroll
    for (int jj = 0; jj < 4; ++jj) b4[jj] = *(float4*)&Bk[tx * 4 + jj][d];
#pragma unroll
    for (int ii = 0; ii < 4; ++ii)
#pragma unroll
      for (int jj = 0; jj < 4; ++jj)
        acc[ii][jj] += a4[ii].x * b4[jj].x + a4[ii].y * b4[jj].y + a4[ii].z * b4[jj].z +
                       a4[ii].w * b4[jj].w;
  }
#pragma unroll
  for (int ii = 0; ii < 4; ++ii)
#pragma unroll
    for (int jj = 0; jj < 4; ++jj)
      sim[((size_t)bh * 256 + ti * 64 + ty * 4 + ii) * 256 + tj * 64 + tx * 4 + jj] =
          acc[ii][jj];
}

// ---------------------------------------------------------------- row softmax (len 256)
__global__ __launch_bounds__(256) void k_softmax256(float* __restrict__ a) {
  int w = threadIdx.x >> 6, lane = threadIdx.x & 63;
  size_t row = (size_t)blockIdx.x * 4 + w;
  float* p = a + row * 256 + lane * 4;
  float4 v = *(float4*)p;
  float m = fmaxf(fmaxf(v.x, v.y), fmaxf(v.z, v.w));
  for (int o = 32; o; o >>= 1) m = fmaxf(m, __shfl_xor(m, o));
  v.x = expf(v.x - m); v.y = expf(v.y - m);
  v.z = expf(v.z - m); v.w = expf(v.w - m);
  float s = v.x + v.y + v.z + v.w;
  for (int o = 32; o; o >>= 1) s += __shfl_xor(s, o);
  float inv = 1.f / s;
  v.x *= inv; v.y *= inv; v.z *= inv; v.w *= inv;
  *(float4*)p = v;
}

// ---------------------------------------------------------------- pinv helpers
__global__ void k_pinv_sums(float* __restrict__ red, const float* __restrict__ a2) {
  int bh = blockIdx.x, t = threadIdx.x;
  const float* Ab = a2 + (size_t)bh * 65536;
  float s = 0.f;
  for (int i = 0; i < 256; ++i) s += fabsf(Ab[(size_t)i * 256 + t]);
  red[bh * 256 + t] = s;
  float c = 0.f;
  const float* rp = Ab + (size_t)t * 256;
  for (int j = 0; j < 256; j += 4) {
    float4 v = *(const float4*)(rp + j);
    c += fabsf(v.x) + fabsf(v.y) + fabsf(v.z) + fabsf(v.w);
  }
  red[4096 + bh * 256 + t] = c;
}

__global__ void k_pinv_scale(float* __restrict__ red) {
  __shared__ float sm[8];
  int t = threadIdx.x;
  float m1 = 0.f, m2 = 0.f;
  for (int k = t; k < 4096; k += 256) {
    m1 = fmaxf(m1, red[k]);
    m2 = fmaxf(m2, red[4096 + k]);
  }
  for (int o = 32; o; o >>= 1) {
    m1 = fmaxf(m1, __shfl_xor(m1, o));
    m2 = fmaxf(m2, __shfl_xor(m2, o));
  }
  int w = t >> 6;
  if ((t & 63) == 0) { sm[w] = m1; sm[4 + w] = m2; }
  __syncthreads();
  if (t == 0) {
    float a = fmaxf(fmaxf(sm[0], sm[1]), fmaxf(sm[2], sm[3]));
    float b = fmaxf(fmaxf(sm[4], sm[5]), fmaxf(sm[6], sm[7]));
    red[8192] = 1.0f / (a * b);
  }
}

__global__ void k_zinit(float* __restrict__ z, const float* __restrict__ a2,
                        const float* __restrict__ red) {
  float s = red[8192];
  int i = blockIdx.x, bh = blockIdx.y, j = threadIdx.x;
  z[((size_t)bh * 256 + i) * 256 + j] = a2[((size_t)bh * 256 + j) * 256 + i] * s;
}

// ---- shared BK=128 f16 3-term matmul core: acc += A[i0..i0+64) @ B (256xN)
__device__ __forceinline__ void bmm_core(
    short (*Ash)[136], short (*Asl)[136], short (*Bsh)[136], short (*Bsl)[136],
    const float* __restrict__ Ab, const float* __restrict__ Bb, int i0, int j0, int N,
    int t, f32x4 (&acc)[4]) {
  const int lane = t & 63, w = t >> 6;
  const int fr = lane & 15, kg = lane >> 4;
  const int ar = t >> 2, akseg = (t & 3) * 32;  // A: 32 floats / thread
  for (int k0 = 0; k0 < 256; k0 += 128) {
    __syncthreads();
    {  // stage A rows (f16 split): 64 rows x 128 k
      const float* p = Ab + (size_t)(i0 + ar) * 256 + k0 + akseg;
#pragma unroll
      for (int q = 0; q < 4; ++q) {
        float4 f0 = *(const float4*)(p + q * 8);
        float4 f1 = *(const float4*)(p + q * 8 + 4);
        unsigned h0, h1, h2, h3, l0, l1, l2, l3;
        split2h(f0.x, f0.y, h0, l0);
        split2h(f0.z, f0.w, h1, l1);
        split2h(f1.x, f1.y, h2, l2);
        split2h(f1.z, f1.w, h3, l3);
        *(uint4*)&Ash[ar][akseg + q * 8] = make_uint4(h0, h1, h2, h3);
        *(uint4*)&Asl[ar][akseg + q * 8] = make_uint4(l0, l1, l2, l3);
      }
    }
    {  // stage B transposed (f16 split): Bsh[j_local][k_local], 128 k-rows x 64 j
#pragma unroll
      for (int pass = 0; pass < 8; ++pass) {
        int kr = pass * 16 + (t >> 4);
        int jseg = (t & 15) * 4;
        const float* p = Bb + (size_t)(k0 + kr) * N + j0 + jseg;
        float4 f = *(const float4*)p;
        float fv[4] = {f.x, f.y, f.z, f.w};
#pragma unroll
        for (int c = 0; c < 4; ++c) {
          _Float16 hh = (_Float16)fv[c];
          float lo = fv[c] - (float)hh;
          Bsh[jseg + c][kr] = (short)__builtin_bit_cast(unsigned short, hh);
          Bsl[jseg + c][kr] = (short)f16_1(lo);
        }
      }
    }
    __syncthreads();
#pragma unroll
    for (int kw = 0; kw < 4; ++kw) {
      f16x8 bhf = *(const f16x8*)&Bsh[w * 16 + fr][kw * 32 + kg * 8];
      f16x8 blf = *(const f16x8*)&Bsl[w * 16 + fr][kw * 32 + kg * 8];
#pragma unroll
      for (int mf = 0; mf < 4; ++mf) {
        f16x8 ah = *(const f16x8*)&Ash[mf * 16 + fr][kw * 32 + kg * 8];
        f16x8 al = *(const f16x8*)&Asl[mf * 16 + fr][kw * 32 + kg * 8];
        acc[mf] = __builtin_amdgcn_mfma_f32_16x16x32_f16(ah, bhf, acc[mf], 0, 0, 0);
        acc[mf] = __builtin_amdgcn_mfma_f32_16x16x32_f16(al, bhf, acc[mf], 0, 0, 0);
        acc[mf] = __builtin_amdgcn_mfma_f32_16x16x32_f16(ah, blf, acc[mf], 0, 0, 0);
      }
    }
  }
}

// ------- batched 256x256 @ 256xN; C = a1*(A@B) + d1*I + e1*E (E optional)
__global__ __launch_bounds__(256) void k_bmm_poly(
    const float* __restrict__ A, const float* __restrict__ Bm,
    const float* __restrict__ E, float* __restrict__ C, float a1, float d1, float e1,
    int N) {
  __shared__ short Ash[64][136];
  __shared__ short Asl[64][136];
  __shared__ short Bsh[64][136];
  __shared__ short Bsl[64][136];
  const int t = threadIdx.x;
  const int bh = blockIdx.z;
  const int i0 = blockIdx.y * 64, j0 = blockIdx.x * 64;
  const int lane = t & 63, w = t >> 6;
  const int fr = lane & 15, kg = lane >> 4;
  f32x4 acc[4];
  f32x4 zero4 = {0.f, 0.f, 0.f, 0.f};
#pragma unroll
  for (int i = 0; i < 4; ++i) acc[i] = zero4;
  bmm_core(Ash, Asl, Bsh, Bsl, A + (size_t)bh * 65536, Bm + (size_t)bh * 256 * N, i0,
           j0, N, t, acc);
  int j = j0 + w * 16 + fr;
#pragma unroll
  for (int mf = 0; mf < 4; ++mf) {
#pragma unroll
    for (int rr = 0; rr < 4; ++rr) {
      int i = i0 + mf * 16 + kg * 4 + rr;
      float v = acc[mf][rr];
      size_t off = (size_t)bh * 256 * N + (size_t)i * N + j;
      float out = a1 * v + ((i == j) ? d1 : 0.f);
      if (E) out += e1 * E[off];
      C[off] = out;
    }
  }
}

// ------- dual batched: z<16: C0 = s*(A0@B); z>=16: C1 = s*(A1@B)   (N=256)
__global__ __launch_bounds__(256) void k_bmm_dual(
    const float* __restrict__ A0, const float* __restrict__ A1,
    const float* __restrict__ Bm, float* __restrict__ C0, float* __restrict__ C1,
    float s) {
  __shared__ short Ash[64][136];
  __shared__ short Asl[64][136];
  __shared__ short Bsh[64][136];
  __shared__ short Bsl[64][136];
  const int t = threadIdx.x;
  const int z = blockIdx.z;
  const int bh = z & 15;
  const int sel = z >> 4;
  const float* A = sel ? A1 : A0;
  float* C = sel ? C1 : C0;
  const int i0 = blockIdx.y * 64, j0 = blockIdx.x * 64;
  const int lane = t & 63, w = t >> 6;
  const int fr = lane & 15, kg = lane >> 4;
  f32x4 acc[4];
  f32x4 zero4 = {0.f, 0.f, 0.f, 0.f};
#pragma unroll
  for (int i = 0; i < 4; ++i) acc[i] = zero4;
  bmm_core(Ash, Asl, Bsh, Bsl, A + (size_t)bh * 65536, Bm + (size_t)bh * 65536, i0, j0,
           256, t, acc);
  int j = j0 + w * 16 + fr;
#pragma unroll
  for (int mf = 0; mf < 4; ++mf) {
#pragma unroll
    for (int rr = 0; rr < 4; ++rr) {
      int i = i0 + mf * 16 + kg * 4 + rr;
      size_t off = (size_t)bh * 65536 + (size_t)i * 256 + j;
      C[off] = s * acc[mf][rr];
    }
  }
}

// -------------------------- a3 @ v : MFMA flash (f16 qkv, no-max, split-K chunks)
__global__ __launch_bounds__(256, 2) void k_a3v_mfma(
    float* __restrict__ pacc, float* __restrict__ pL,
    const float* __restrict__ ql, const unsigned short* __restrict__ qkv) {
  __shared__ short Ks[64][72];
  __shared__ short Vt[64][72];
  __shared__ short Ps[4][64][72];
  const int t = threadIdx.x;
  const int bh = blockIdx.x;
  const int kc = blockIdx.y;
  const int b = bh >> 3, h = bh & 7;
  const int lane = t & 63, w = t >> 6;
  const int fr = lane & 15, kg = lane >> 4;

  f16x8 qf[4][2];
#pragma unroll
  for (int nf = 0; nf < 4; ++nf) {
    const float* qp = ql + ((size_t)bh * 256 + w * 64 + nf * 16 + fr) * 64 + kg * 8;
#pragma unroll
    for (int kw = 0; kw < 2; ++kw) {
      float4 a = *(const float4*)(qp + kw * 32);
      float4 c = *(const float4*)(qp + kw * 32 + 4);
      uint4 uu = make_uint4(pk_f16(a.x, a.y), pk_f16(a.z, a.w), pk_f16(c.x, c.y),
                            pk_f16(c.z, c.w));
      qf[nf][kw] = *(f16x8*)&uu;
    }
  }
  f32x4 oacc[4][4];
  f32x4 zero4 = {0.f, 0.f, 0.f, 0.f};
#pragma unroll
  for (int i = 0; i < 4; ++i)
#pragma unroll
    for (int j = 0; j < 4; ++j) oacc[i][j] = zero4;
  float Lp[4] = {0.f, 0.f, 0.f, 0.f};

  const int skey = t >> 2, sd = (t & 3) * 16;
  const unsigned short* kbase = qkv + (size_t)b * NPAD * 1536 + 512 + h * 64 + sd;

  for (int it = 0; it < A3CH / 64; ++it) {
    int nt = kc * A3CH + it * 64;
    __syncthreads();
    {
      const unsigned short* kp = kbase + (size_t)(nt + skey) * 1536;
      *(uint4*)&Ks[skey][sd] = *(const uint4*)kp;
      *(uint4*)&Ks[skey][sd + 8] = *(const uint4*)(kp + 8);
      const unsigned short* vp = kp + 512;
      uint4 v01 = *(const uint4*)vp;
      uint4 v23 = *(const uint4*)(vp + 8);
      Vt[sd + 0][skey] = (short)v01.x;
      Vt[sd + 1][skey] = (short)(v01.x >> 16);
      Vt[sd + 2][skey] = (short)v01.y;
      Vt[sd + 3][skey] = (short)(v01.y >> 16);
      Vt[sd + 4][skey] = (short)v01.z;
      Vt[sd + 5][skey] = (short)(v01.z >> 16);
      Vt[sd + 6][skey] = (short)v01.w;
      Vt[sd + 7][skey] = (short)(v01.w >> 16);
      Vt[sd + 8][skey] = (short)v23.x;
      Vt[sd + 9][skey] = (short)(v23.x >> 16);
      Vt[sd + 10][skey] = (short)v23.y;
      Vt[sd + 11][skey] = (short)(v23.y >> 16);
      Vt[sd + 12][skey] = (short)v23.z;
      Vt[sd + 13][skey] = (short)(v23.z >> 16);
      Vt[sd + 14][skey] = (short)v23.w;
      Vt[sd + 15][skey] = (short)(v23.w >> 16);
    }
    __syncthreads();
    f32x4 sacc[4][4];
#pragma unroll
    for (int i = 0; i < 4; ++i)
#pragma unroll
      for (int j = 0; j < 4; ++j) sacc[i][j] = zero4;
#pragma unroll
    for (int kw = 0; kw < 2; ++kw) {
      f16x8 kf[4];
#pragma unroll
      for (int mf = 0; mf < 4; ++mf)
        kf[mf] = *(const f16x8*)&Ks[mf * 16 + fr][kw * 32 + kg * 8];
#pragma unroll
      for (int mf = 0; mf < 4; ++mf)
#pragma unroll
        for (int nf = 0; nf < 4; ++nf)
          sacc[mf][nf] = __builtin_amdgcn_mfma_f32_16x16x32_f16(kf[mf], qf[nf][kw],
                                                                sacc[mf][nf], 0, 0, 0);
    }
#pragma unroll
    for (int mf = 0; mf < 4; ++mf)
#pragma unroll
      for (int nf = 0; nf < 4; ++nf) {
        f32x4 s = sacc[mf][nf];
        float p0 = __expf(s[0]);
        float p1 = __expf(s[1]);
        float p2 = __expf(s[2]);
        float p3 = __expf(s[3]);
        Lp[nf] += (p0 + p1) + (p2 + p3);
        uint2 pw = make_uint2(pk_f16(p0, p1), pk_f16(p2, p3));
        *(uint2*)&Ps[w][nf * 16 + fr][mf * 16 + kg * 4] = pw;
      }
    __syncthreads();
#pragma unroll
    for (int kw = 0; kw < 2; ++kw) {
      f16x8 vf[4], pf[4];
#pragma unroll
      for (int mf = 0; mf < 4; ++mf)
        vf[mf] = *(const f16x8*)&Vt[mf * 16 + fr][kw * 32 + kg * 8];
#pragma unroll
      for (int nf = 0; nf < 4; ++nf)
        pf[nf] = *(const f16x8*)&Ps[w][nf * 16 + fr][kw * 32 + kg * 8];
#pragma unroll
      for (int mf = 0; mf < 4; ++mf)
#pragma unroll
        for (int nf = 0; nf < 4; ++nf)
          oacc[mf][nf] = __builtin_amdgcn_mfma_f32_16x16x32_f16(vf[mf], pf[nf],
                                                                oacc[mf][nf], 0, 0, 0);
    }
  }
  size_t obase = ((size_t)kc * 16 + bh) * 256;
#pragma unroll
  for (int mf = 0; mf < 4; ++mf)
#pragma unroll
    for (int nf = 0; nf < 4; ++nf) {
      int lm = w * 64 + nf * 16 + fr;
      *(f32x4*)(pacc + (obase + lm) * 64 + mf * 16 + kg * 4) = oacc[mf][nf];
    }
#pragma unroll
  for (int nf = 0; nf < 4; ++nf) {
    Lp[nf] += __shfl_xor(Lp[nf], 16);
    Lp[nf] += __shfl_xor(Lp[nf], 32);
  }
  if (lane < 16) {
#pragma unroll
    for (int nf = 0; nf < 4; ++nf)
      pL[obase + w * 64 + nf * 16 + lane] = Lp[nf];
  }
}

__global__ __launch_bounds__(64) void k_a3v_red(
    float* __restrict__ bv, const float* __restrict__ pacc,
    const float* __restrict__ pL) {
  int row = blockIdx.x;
  int d = threadIdx.x;
  float A = 0.f, L = 0.f;
#pragma unroll
  for (int c = 0; c < A3KC; ++c) {
    size_t pr = (size_t)c * 4096 + row;
    A += pacc[pr * 64 + d];
    L += pL[pr];
  }
  bv[(size_t)row * 64 + d] = A / L;
}

// ------------- fused sim1: softmax(q @ (0.125*kl)^T) @ w2 -> single f16 attout
__global__ __launch_bounds__(256, 2) void k_att1(
    unsigned short* __restrict__ attf, const unsigned short* __restrict__ qkv,
    const float* __restrict__ kl, const float* __restrict__ w2) {
  __shared__ short KLs[64][72];
  __shared__ short W2t[64][72];
  __shared__ short Ps[4][64][72];
  const int t = threadIdx.x;
  const int tile = blockIdx.x, bh = blockIdx.y;
  const int b = bh >> 3, h = bh & 7;
  const int lane = t & 63, w = t >> 6;
  const int fr = lane & 15, kg = lane >> 4;
  const int n0 = tile * 256;

  f16x8 qf[4][2];
#pragma unroll
  for (int nf = 0; nf < 4; ++nf) {
    const unsigned short* qp =
        qkv + ((size_t)b * NPAD + n0 + w * 64 + nf * 16 + fr) * 1536 + h * 64 + kg * 8;
    qf[nf][0] = *(const f16x8*)qp;
    qf[nf][1] = *(const f16x8*)(qp + 32);
  }
  f32x4 oacc[4][4];
  f32x4 zero4 = {0.f, 0.f, 0.f, 0.f};
#pragma unroll
  for (int i = 0; i < 4; ++i)
#pragma unroll
    for (int j = 0; j < 4; ++j) oacc[i][j] = zero4;
  float Lp[4] = {0.f, 0.f, 0.f, 0.f};

  const int sr = t >> 2, sc = (t & 3) * 16;
  for (int cb = 0; cb < 4; ++cb) {
    __syncthreads();
    {
      const float* kp = kl + ((size_t)bh * 256 + cb * 64 + sr) * 64 + sc;
      float4 k0 = *(const float4*)kp;
      float4 k1 = *(const float4*)(kp + 4);
      float4 k2 = *(const float4*)(kp + 8);
      float4 k3 = *(const float4*)(kp + 12);
      *(uint4*)&KLs[sr][sc] =
          make_uint4(pk_f16(k0.x * 0.125f, k0.y * 0.125f),
                     pk_f16(k0.z * 0.125f, k0.w * 0.125f),
                     pk_f16(k1.x * 0.125f, k1.y * 0.125f),
                     pk_f16(k1.z * 0.125f, k1.w * 0.125f));
      *(uint4*)&KLs[sr][sc + 8] =
          make_uint4(pk_f16(k2.x * 0.125f, k2.y * 0.125f),
                     pk_f16(k2.z * 0.125f, k2.w * 0.125f),
                     pk_f16(k3.x * 0.125f, k3.y * 0.125f),
                     pk_f16(k3.z * 0.125f, k3.w * 0.125f));
      const float* wp = w2 + ((size_t)bh * 256 + cb * 64 + sr) * 64 + sc;
      float4 v0 = *(const float4*)wp;
      float4 v1 = *(const float4*)(wp + 4);
      float4 v2 = *(const float4*)(wp + 8);
      float4 v3 = *(const float4*)(wp + 12);
      W2t[sc + 0][sr] = (short)f16_1(v0.x);
      W2t[sc + 1][sr] = (short)f16_1(v0.y);
      W2t[sc + 2][sr] = (short)f16_1(v0.z);
      W2t[sc + 3][sr] = (short)f16_1(v0.w);
      W2t[sc + 4][sr] = (short)f16_1(v1.x);
      W2t[sc + 5][sr] = (short)f16_1(v1.y);
      W2t[sc + 6][sr] = (short)f16_1(v1.z);
      W2t[sc + 7][sr] = (short)f16_1(v1.w);
      W2t[sc + 8][sr] = (short)f16_1(v2.x);
      W2t[sc + 9][sr] = (short)f16_1(v2.y);
      W2t[sc + 10][sr] = (short)f16_1(v2.z);
      W2t[sc + 11][sr] = (short)f16_1(v2.w);
      W2t[sc + 12][sr] = (short)f16_1(v3.x);
      W2t[sc + 13][sr] = (short)f16_1(v3.y);
      W2t[sc + 14][sr] = (short)f16_1(v3.z);
      W2t[sc + 15][sr] = (short)f16_1(v3.w);
    }
    __syncthreads();
    f32x4 sacc[4][4];
#pragma unroll
    for (int i = 0; i < 4; ++i)
#pragma unroll
      for (int j = 0; j < 4; ++j) sacc[i][j] = zero4;
#pragma unroll
    for (int kw = 0; kw < 2; ++kw) {
      f16x8 kf[4];
#pragma unroll
      for (int mf = 0; mf < 4; ++mf)
        kf[mf] = *(const f16x8*)&KLs[mf * 16 + fr][kw * 32 + kg * 8];
#pragma unroll
      for (int mf = 0; mf < 4; ++mf)
#pragma unroll
        for (int nf = 0; nf < 4; ++nf)
          sacc[mf][nf] = __builtin_amdgcn_mfma_f32_16x16x32_f16(kf[mf], qf[nf][kw],
                                                                sacc[mf][nf], 0, 0, 0);
    }
#pragma unroll
    for (int mf = 0; mf < 4; ++mf)
#pragma unroll
      for (int nf = 0; nf < 4; ++nf) {
        f32x4 s = sacc[mf][nf];
        float p0 = __expf(s[0]);
        float p1 = __expf(s[1]);
        float p2 = __expf(s[2]);
        float p3 = __expf(s[3]);
        Lp[nf] += (p0 + p1) + (p2 + p3);
        uint2 pw = make_uint2(pk_f16(p0, p1), pk_f16(p2, p3));
        *(uint2*)&Ps[w][nf * 16 + fr][mf * 16 + kg * 4] = pw;
      }
    __syncthreads();
#pragma unroll
    for (int kw = 0; kw < 2; ++kw) {
      f16x8 vf[4], pf[4];
#pragma unroll
      for (int mf = 0; mf < 4; ++mf)
        vf[mf] = *(const f16x8*)&W2t[mf * 16 + fr][kw * 32 + kg * 8];
#pragma unroll
      for (int nf = 0; nf < 4; ++nf)
        pf[nf] = *(const f16x8*)&Ps[w][nf * 16 + fr][kw * 32 + kg * 8];
#pragma unroll
      for (int mf = 0; mf < 4; ++mf)
#pragma unroll
        for (int nf = 0; nf < 4; ++nf)
          oacc[mf][nf] = __builtin_amdgcn_mfma_f32_16x16x32_f16(vf[mf], pf[nf],
                                                                oacc[mf][nf], 0, 0, 0);
    }
  }
#pragma unroll
  for (int nf = 0; nf < 4; ++nf) {
    Lp[nf] += __shfl_xor(Lp[nf], 16);
    Lp[nf] += __shfl_xor(Lp[nf], 32);
  }
#pragma unroll
  for (int nf = 0; nf < 4; ++nf) {
    float inv = 1.0f / Lp[nf];
    int tok = n0 + w * 64 + nf * 16 + fr;
#pragma unroll
    for (int mf = 0; mf < 4; ++mf) {
      f32x4 o = oacc[mf][nf];
      ushort4 hs;
      hs.x = f16_1(o[0] * inv);
      hs.y = f16_1(o[1] * inv);
      hs.z = f16_1(o[2] * inv);
      hs.w = f16_1(o[3] * inv);
      *(ushort4*)(attf + ((size_t)b * NPAD + tok) * DD + h * 64 + mf * 16 + kg * 4) = hs;
    }
  }
}

// ---------------- attf += depthwise33(v); sliding-window (40 LDS loads/thread)
__global__ __launch_bounds__(256) void k_convres(
    unsigned short* __restrict__ attf, const unsigned short* __restrict__ qkv,
    const float* __restrict__ resw) {
  __shared__ float vS[96][68];
  __shared__ float w33[33];
  int t = threadIdx.x;
  int tb = blockIdx.x, bh = blockIdx.y;
  int b = bh >> 3, h = bh & 7;
  int n0 = tb * 64;
  if (t < 33) w33[t] = resw[h * 33 + t];
  int sc = (t & 3) * 16;
#pragma unroll
  for (int pass = 0; pass < 2; ++pass) {
    int r = (t >> 2) + pass * 64;
    if (r < 96) {
      int seq = n0 - 16 + r;
      if (seq >= 0 && seq < NPAD) {
        const unsigned short* p =
            qkv + ((size_t)b * NPAD + seq) * 1536 + 1024 + h * 64 + sc;
        uint4 u0 = *(const uint4*)p;
        uint4 u1 = *(const uint4*)(p + 8);
        float4 f0 = make_float4(f16f(u0.x), f16f(u0.x >> 16), f16f(u0.y),
                                f16f(u0.y >> 16));
        float4 f1 = make_float4(f16f(u0.z), f16f(u0.z >> 16), f16f(u0.w),
                                f16f(u0.w >> 16));
        float4 f2 = make_float4(f16f(u1.x), f16f(u1.x >> 16), f16f(u1.y),
                                f16f(u1.y >> 16));
        float4 f3 = make_float4(f16f(u1.z), f16f(u1.z >> 16), f16f(u1.w),
                                f16f(u1.w >> 16));
        *(float4*)&vS[r][sc + 0] = f0;
        *(float4*)&vS[r][sc + 4] = f1;
        *(float4*)&vS[r][sc + 8] = f2;
        *(float4*)&vS[r][sc + 12] = f3;
      } else {
        float4 z = make_float4(0.f, 0.f, 0.f, 0.f);
        *(float4*)&vS[r][sc + 0] = z;
        *(float4*)&vS[r][sc + 4] = z;
        *(float4*)&vS[r][sc + 8] = z;
        *(float4*)&vS[r][sc + 12] = z;
      }
    }
  }
  __syncthreads();
  int tg = t >> 5;
  int d2 = (t & 31) * 2;
  float ax[8], ay[8];
#pragma unroll
  for (int j = 0; j < 8; ++j) { ax[j] = 0.f; ay[j] = 0.f; }
  // rows tg*8 .. tg*8+39 cover taps k=0..32 for the 8 tokens tg*8+j
#pragma unroll
  for (int rr = 0; rr < 40; ++rr) {
    float2 v = *(float2*)&vS[tg * 8 + rr][d2];
#pragma unroll
    for (int j = 0; j < 8; ++j) {
      int k = rr - j;
      if (k >= 0 && k < 33) {
        ax[j] += w33[k] * v.x;
        ay[j] += w33[k] * v.y;
      }
    }
  }
#pragma unroll
  for (int j = 0; j < 8; ++j) {
    size_t off = ((size_t)b * NPAD + n0 + tg * 8 + j) * DD + h * 64 + d2;
    unsigned u = *(unsigned*)(attf + off);
    float x0 = f16f(u) + ax[j];
    float x1 = f16f(u >> 16) + ay[j];
    *(unsigned*)(attf + off) = pk_f16(x0, x1);
  }
}

// -------------- PPEG (combined 7x7), 4 output rows per block (window reuse)
// grid (32 rowgrp x 4 colgrp, 4 cg, 2 b), 128 thr (channels)
__global__ __launch_bounds__(128) void k_ppeg(
    float* __restrict__ hB, const float* __restrict__ hA,
    const float* __restrict__ w7, const float* __restrict__ b7,
    const float* __restrict__ w5, const float* __restrict__ b5,
    const float* __restrict__ w3, const float* __restrict__ b3) {
  __shared__ float cw[49][128];
  int t = threadIdx.x;
  int i0 = (blockIdx.x >> 2) * 4;
  int j0 = (blockIdx.x & 3) * 32;
  int cg = blockIdx.y, b = blockIdx.z;
  int c = cg * 128 + t;
#pragma unroll
  for (int k = 0; k < 49; ++k) cw[k][t] = w7[c * 49 + k];
#pragma unroll
  for (int di = 0; di < 5; ++di)
#pragma unroll
    for (int dj = 0; dj < 5; ++dj)
      cw[(di + 1) * 7 + dj + 1][t] += w5[c * 25 + di * 5 + dj];
#pragma unroll
  for (int di = 0; di < 3; ++di)
#pragma unroll
    for (int dj = 0; dj < 3; ++dj)
      cw[(di + 2) * 7 + dj + 2][t] += w3[c * 9 + di * 3 + dj];
  cw[24][t] += 1.0f;
  float bias = b7[c] + b5[c] + b3[c];
  const float* base = hA + (size_t)b * TT * DD + DD + c;
  float* obase = hB + (size_t)b * TT * DD + DD + c;
  float acc[4][32];
#pragma unroll
  for (int r = 0; r < 4; ++r)
#pragma unroll
    for (int j = 0; j < 32; ++j) acc[r][j] = bias;
  // window rows ii = i0-3 .. i0+6; output row i0+r uses di = wi - r in [0,7)
  for (int wi = 0; wi < 10; ++wi) {
    int ii = i0 + wi - 3;
    if ((unsigned)ii >= 128u) continue;
    float win[38];
#pragma unroll
    for (int w = 0; w < 38; ++w) {
      int col = j0 - 3 + w;
      win[w] = ((unsigned)col < 128u) ? base[(size_t)(ii * 128 + col) * DD] : 0.f;
    }
#pragma unroll
    for (int r = 0; r < 4; ++r) {
      int di = wi - r;
      if (di < 0 || di > 6) continue;
#pragma unroll
      for (int dj = 0; dj < 7; ++dj) {
        float wv = cw[di * 7 + dj][t];
#pragma unroll
        for (int j = 0; j < 32; ++j) acc[r][j] += win[j + dj] * wv;
      }
    }
  }
#pragma unroll
  for (int r = 0; r < 4; ++r)
#pragma unroll
    for (int j = 0; j < 32; ++j)
      obase[(size_t)((i0 + r) * 128 + j0 + j) * DD] = acc[r][j];
}

// ---------------------------------------------------------------- final head
__global__ __launch_bounds__(512) void k_final(
    float* __restrict__ out, const float* __restrict__ h,
    const float* __restrict__ g, const float* __restrict__ be,
    const float* __restrict__ cw, const float* __restrict__ cbias) {
  __shared__ float sm[16];
  int t = threadIdx.x;
  for (int b = 0; b < 2; ++b) {
    const float* row = h + (size_t)b * TT * DD;
    float x = row[t];
    float s = x;
    for (int o = 32; o; o >>= 1) s += __shfl_xor(s, o);
    if ((t & 63) == 0) sm[t >> 6] = s;
    __syncthreads();
    float mu = 0.f;
    for (int i = 0; i < 8; ++i) mu += sm[i];
    mu *= (1.f / 512.f);
    __syncthreads();
    float d = x - mu;
    s = d * d;
    for (int o = 32; o; o >>= 1) s += __shfl_xor(s, o);
    if ((t & 63) == 0) sm[t >> 6] = s;
    __syncthreads();
    float var = 0.f;
    for (int i = 0; i < 8; ++i) var += sm[i];
    var *= (1.f / 512.f);
    float rs = rsqrtf(var + 1e-5f);
    __syncthreads();
    float f = d * rs * g[t] + be[t];
    float p0 = f * cw[2 * t], p1 = f * cw[2 * t + 1];
    for (int o = 32; o; o >>= 1) {
      p0 += __shfl_xor(p0, o);
      p1 += __shfl_xor(p1, o);
    }
    if ((t & 63) == 0) {
      sm[t >> 6] = p0;
      sm[8 + (t >> 6)] = p1;
    }
    __syncthreads();
    if (t == 0) {
      float q0 = 0.f, q1 = 0.f;
      for (int i = 0; i < 8; ++i) {
        q0 += sm[i];
        q1 += sm[8 + i];
      }
      out[b * 2 + 0] = q0 + cbias[0];
      out[b * 2 + 1] = q1 + cbias[1];
    }
    __syncthreads();
  }
}

// ---------------------------------------------------------------- host side
static void run_attn(float* h, const float* lng, const float* lnb,
                     const float* wqkv, const float* wout, const float* bout,
                     const float* resw, float* xp, unsigned short* qkvh, float* ql,
                     float* kl, float* a2, float* z0, float* z1, float* xz, float* xz2,
                     float* yB, float* yC, float* bv, float* w2, float* red,
                     float* Sbuf, unsigned short* wth, hipStream_t stream) {
  // xp region: [single f16 plane: LN output, later attention output]
  unsigned short* xph = (unsigned short*)xp;
  k_zero_pad<<<BB * PADF, 256, 0, stream>>>(xph);
  k_ln_pad<<<(BB * TT + 3) / 4, 256, 0, stream>>>(xph, h, lng, lnb);
  k_cvt_wt<<<dim3(DD / 32, 1536 / 32), 256, 0, stream>>>(wqkv, wth, DD, 1536);
  k_gemm_qkv8<<<dim3(BB * NPAD / 128, 1536 / 256), 512, 0, stream>>>(xph, wth, qkvh);
  k_landmarks<<<1024, 256, 0, stream>>>(ql, kl, qkvh);
  float* pacc = Sbuf;
  float* pL = Sbuf + (size_t)A3KC * 4096 * 64;
  k_a3v_mfma<<<dim3(16, A3KC), 256, 0, stream>>>(pacc, pL, ql, qkvh);
  k_a3v_red<<<4096, 64, 0, stream>>>(bv, pacc, pL);
  k_sim2<<<dim3(4, 4, 16), 256, 0, stream>>>(a2, ql, kl);
  k_softmax256<<<1024, 256, 0, stream>>>(a2);
  k_pinv_sums<<<16, 256, 0, stream>>>(red, a2);
  k_pinv_scale<<<1, 256, 0, stream>>>(red);
  k_zinit<<<dim3(256, 16), 256, 0, stream>>>(z0, a2, red);
  // Newton-Schulz: 3 matmuls/iter via P = a2@z carried forward
  float* zc = z0;
  float* zn = z1;
  float* P = xz;
  float* Pn = xz2;
  // P0 = a2 @ z0
  k_bmm_poly<<<dim3(4, 4, 16), 256, 0, stream>>>(a2, zc, nullptr, P, 1.f, 0.f, 0.f, 256);
  for (int it = 0; it < 6; ++it) {
    // yB = P@P + 15I - 7P   (== 15I - P@(7I - P))
    k_bmm_poly<<<dim3(4, 4, 16), 256, 0, stream>>>(P, P, P, yB, 1.f, 15.f, -7.f, 256);
    // yC = 13I - P@yB
    k_bmm_poly<<<dim3(4, 4, 16), 256, 0, stream>>>(P, yB, nullptr, yC, -1.f, 13.f, 0.f, 256);
    // zn = 0.25 zc@yC ; Pn = 0.25 P@yC  (batched)
    k_bmm_dual<<<dim3(4, 4, 32), 256, 0, stream>>>(zc, P, yC, zn, Pn, 0.25f);
    float* tmp = zc; zc = zn; zn = tmp;
    tmp = P; P = Pn; Pn = tmp;
  }
  k_bmm_poly<<<dim3(1, 4, 16), 256, 0, stream>>>(zc, bv, nullptr, w2, 1.f, 0.f, 0.f, 64);
  // attention output as single f16 in xph (LN plane is dead after qkv GEMM)
  k_att1<<<dim3(NPAD / 256, 16), 256, 0, stream>>>(xph, qkvh, kl, w2);
  k_convres<<<dim3(NPAD / 64, 16), 256, 0, stream>>>(xph, qkvh, resw);
  k_cvt_wt<<<dim3(DD / 32, DD / 32), 256, 0, stream>>>(wout, wth, DD, DD);
  k_gemm_proj<<<dim3(129, 2, BB), 512, 0, stream>>>(xph, wth, h, bout);
}

extern "C" void kernel_launch(void* const* d_in, const int* in_sizes, int n_in,
                              void* d_out, int out_size, void* d_ws, size_t ws_size,
                              hipStream_t stream) {
  const float* x        = (const float*)d_in[0];
  const float* w_feat   = (const float*)d_in[1];
  const float* b_feat   = (const float*)d_in[2];
  const float* cls_tok  = (const float*)d_in[3];
  const float* ln1_g    = (const float*)d_in[4];
  const float* ln1_b    = (const float*)d_in[5];
  const float* qkv1     = (const float*)d_in[6];
  const float* out1_w   = (const float*)d_in[7];
  const float* out1_b   = (const float*)d_in[8];
  const float* res1_w   = (const float*)d_in[9];
  const float* ppeg_w7  = (const float*)d_in[10];
  const float* ppeg_b7  = (const float*)d_in[11];
  const float* ppeg_w5  = (const float*)d_in[12];
  const float* ppeg_b5  = (const float*)d_in[13];
  const float* ppeg_w3  = (const float*)d_in[14];
  const float* ppeg_b3  = (const float*)d_in[15];
  const float* ln2_g    = (const float*)d_in[16];
  const float* ln2_b    = (const float*)d_in[17];
  const float* qkv2     = (const float*)d_in[18];
  const float* out2_w   = (const float*)d_in[19];
  const float* out2_b   = (const float*)d_in[20];
  const float* res2_w   = (const float*)d_in[21];
  const float* lnf_g    = (const float*)d_in[22];
  const float* lnf_b    = (const float*)d_in[23];
  const float* cls_w    = (const float*)d_in[24];
  const float* cls_b    = (const float*)d_in[25];

  float* ws = (float*)d_ws;
  size_t off = 0;
  float* hA  = ws + off; off += (size_t)BB * TT * DD;
  float* hB  = ws + off; off += (size_t)BB * TT * DD;
  float* xp  = ws + off; off += (size_t)BB * NPAD * DD;
  float* qkvf = ws + off; off += (size_t)BB * NPAD * 3 * DD;  // used as f16 (half)
  unsigned short* qkvh = (unsigned short*)qkvf;
  float* ql  = ws + off; off += (size_t)BB * HH * 256 * 64;
  float* kl  = ws + off; off += (size_t)BB * HH * 256 * 64;
  float* a2  = ws + off; off += (size_t)16 * 65536;
  float* z0  = ws + off; off += (size_t)16 * 65536;
  float* z1  = ws + off; off += (size_t)16 * 65536;
  float* xz  = ws + off; off += (size_t)16 * 65536;
  float* xz2 = ws + off; off += (size_t)16 * 65536;
  float* yB  = ws + off; off += (size_t)16 * 65536;
  float* yC  = ws + off; off += (size_t)16 * 65536;
  float* bv  = ws + off; off += (size_t)BB * HH * 256 * 64;
  float* w2  = ws + off; off += (size_t)BB * HH * 256 * 64;
  float* red = ws + off; off += 8448;
  unsigned short* wth = (unsigned short*)(ws + off); off += 393216;

  // Stage 1: h = gelu(x @ w_feat + b_feat), prepend cls token
  // (x pre-rounded to f16 in the then-dead qkvh buffer; pipelined GEMM)
  k_set_cls<<<2, 512, 0, stream>>>(hA, cls_tok);
  k_cvt_wt<<<dim3(1024 / 32, DD / 32), 256, 0, stream>>>(w_feat, wth, 1024, DD);
  k_cvt_x<<<16384, 256, 0, stream>>>(qkvh, x);
  k_gemm_feat<<<dim3(256, 2), 512, 0, stream>>>(qkvh, wth, hA, b_feat);
  // Attention 1 (residual in-place on hA; hB is dead -> scratch)
  run_attn(hA, ln1_g, ln1_b, qkv1, out1_w, out1_b, res1_w, xp, qkvh, ql, kl, a2, z0, z1,
           xz, xz2, yB, yC, bv, w2, red, hB, wth, stream);
  // PPEG: hB = ppeg(hA)
  k_copy_cls<<<2, 512, 0, stream>>>(hB, hA);
  k_ppeg<<<dim3(128, 4, 2), 128, 0, stream>>>(hB, hA, ppeg_w7, ppeg_b7, ppeg_w5, ppeg_b5,
                                              ppeg_w3, ppeg_b3);
  // Attention 2 (residual in-place on hB; hA is dead -> scratch)
  run_attn(hB, ln2_g, ln2_b, qkv2, out2_w, out2_b, res2_w, xp, qkvh, ql, kl, a2, z0, z1,
           xz, xz2, yB, yC, bv, w2, red, hA, wth, stream);
  // Final: LN(cls) @ cls_w + cls_b
  k_final<<<1, 512, 0, stream>>>((float*)d_out, hB, lnf_g, lnf_b, cls_w, cls_b);
}